// Round 3
// baseline (1770.366 us; speedup 1.0000x reference)
//
#include <hip/hip_runtime.h>

typedef unsigned short u16;
typedef __attribute__((ext_vector_type(8))) short short8;
typedef __attribute__((ext_vector_type(4))) float f4;
typedef __attribute__((ext_vector_type(4))) unsigned short u16x4;

__device__ __forceinline__ float b2f(u16 u) {
    unsigned int x = ((unsigned int)u) << 16;
    return __builtin_bit_cast(float, x);
}
__device__ __forceinline__ u16 f2b(float f) {
    unsigned int u = __builtin_bit_cast(unsigned int, f);
    u += 0x7FFFu + ((u >> 16) & 1u);   // round-to-nearest-even
    return (u16)(u >> 16);
}

__device__ __forceinline__ void gl16(const void* g, void* l) {
    __builtin_amdgcn_global_load_lds(
        (const __attribute__((address_space(1))) void*)g,
        (__attribute__((address_space(3))) void*)l, 16, 0, 0);
}

// ---------------------------------------------------------------------------
// bf16 MFMA GEMM with global_load_lds staging (m97 structure):
//   C[M,N] = A[M,K] @ Bt[N,K]^T  (+bias, +relu)
// Tile 128x128, BK=32, 4 waves (2x2), each wave 64x64 (4x4 fragments 16x16).
// CBF: 0 f32-out, 1 bf16-out. EPI: 0 none, 1 +bias, 2 +bias+relu.
// SHIFT (CBF=1 only): 0 none, 1 self rel-shift write, 2 cross rel-shift write.
// ---------------------------------------------------------------------------
template<int FM, int FN, int CBF, int EPI, int SHIFT>
__global__ __launch_bounds__(256, 3)
void gemm_bt(const u16* __restrict__ Ap, const u16* __restrict__ Bp,
             void* __restrict__ Cp, const float* __restrict__ bias,
             int M, int N, int K, int lda, int ldb, int ldc,
             long long sAh, long long sAb, long long sBh, long long sBb,
             long long sCh, long long sCb, int batchH)
{
    constexpr int BM = FM * 32;
    constexpr int BN = FN * 32;
    __shared__ __align__(16) u16 As[BM * 32];
    __shared__ __align__(16) u16 Bs[BN * 32];

    const int tid  = threadIdx.x;
    const int z    = blockIdx.z;
    const int bb   = z / batchH;
    const int hh   = z - bb * batchH;
    const int m0   = blockIdx.y * BM;
    const int n0   = blockIdx.x * BN;
    const int w    = tid >> 6;
    const int lane = tid & 63;
    const int wr   = w >> 1;
    const int wc   = w & 1;
    const int lrow = lane & 15;
    const int lk   = (lane >> 4) << 3;
    const int lrow4 = lane >> 2;
    const int lch   = lane & 3;

    const u16* Ag = Ap + sAb * bb + sAh * hh;
    const u16* Bg = Bp + sBb * bb + sBh * hh;

    f4 acc[FM][FN] = {};

    const int nKt = K >> 5;
    for (int kt = 0; kt < nKt; ++kt) {
        const int kb = kt << 5;
        __syncthreads();
        #pragma unroll
        for (int i = 0; i < BM / 64; ++i) {
            const int row0 = (w + i * 4) << 4;
            gl16(Ag + (long long)(m0 + row0 + lrow4) * lda + kb + (lch << 3),
                 &As[row0 * 32]);
        }
        #pragma unroll
        for (int i = 0; i < BN / 64; ++i) {
            const int row0 = (w + i * 4) << 4;
            gl16(Bg + (long long)(n0 + row0 + lrow4) * ldb + kb + (lch << 3),
                 &Bs[row0 * 32]);
        }
        __syncthreads();

        short8 af[FM], bv[FN];
        #pragma unroll
        for (int m = 0; m < FM; ++m)
            af[m] = *(const short8*)(&As[(wr * FM * 16 + m * 16 + lrow) * 32 + lk]);
        #pragma unroll
        for (int n = 0; n < FN; ++n)
            bv[n] = *(const short8*)(&Bs[(wc * FN * 16 + n * 16 + lrow) * 32 + lk]);
        #pragma unroll
        for (int m = 0; m < FM; ++m)
            #pragma unroll
            for (int n = 0; n < FN; ++n)
                acc[m][n] = __builtin_amdgcn_mfma_f32_16x16x32_bf16(af[m], bv[n], acc[m][n], 0, 0, 0);
    }

    const int crow0 = m0 + wr * FM * 16 + ((lane >> 4) << 2);
    const int ccol0 = n0 + wc * FN * 16 + lrow;
    if (CBF == 0) {
        float* Cg = (float*)Cp + sCb * bb + sCh * hh;
        #pragma unroll
        for (int m = 0; m < FM; ++m) {
            #pragma unroll
            for (int n = 0; n < FN; ++n) {
                const int col = ccol0 + n * 16;
                float bvv = (EPI >= 1) ? bias[col] : 0.f;
                #pragma unroll
                for (int r = 0; r < 4; ++r) {
                    float vv = acc[m][n][r] + bvv;
                    if (EPI == 2) vv = fmaxf(vv, 0.f);
                    Cg[(long long)(crow0 + m * 16 + r) * ldc + col] = vv;
                }
            }
        }
    } else {
        u16* Cg = (u16*)Cp + sCb * bb + sCh * hh;
        #pragma unroll
        for (int m = 0; m < FM; ++m) {
            #pragma unroll
            for (int n = 0; n < FN; ++n) {
                const int col = ccol0 + n * 16;
                float bvv = (EPI >= 1) ? bias[col] : 0.f;
                #pragma unroll
                for (int r = 0; r < 4; ++r) {
                    float vv = acc[m][n][r] + bvv;
                    if (EPI == 2) vv = fmaxf(vv, 0.f);
                    const int t = crow0 + m * 16 + r;
                    if (SHIFT == 0) {
                        Cg[(long long)t * ldc + col] = f2b(vv);
                    } else if (SHIFT == 1) {
                        const int j = col + t - 1023;
                        if (j >= 0 && j < 2048) Cg[(long long)t * ldc + j] = f2b(vv);
                    } else {
                        const int j1 = col + t - 1023;
                        if (j1 >= 0) Cg[(long long)t * ldc + j1] = f2b(vv);
                        const int j2 = col + t + 1;
                        if (t >= 1 && j2 < 1024) Cg[(long long)(t - 1) * ldc + j2] = f2b(vv);
                    }
                }
            }
        }
    }
}

// ---------------------------------------------------------------------------
// Fused attention: inline AC scores (MFMA vs K from global) + BD add +
// softmax + probs write + PV.  Block = (b,h) x 32 q-rows, 512 threads (8 waves).
// MODE 0: self (causal mask at +1024, skip fully-masked tiles), KK=2048.
// MODE 1: cross (no mask, BD zero-col at j==t+1), KK=1024.
// qw: q + r_w_bias [b*1024+t][h*64+d]; kb: K [b*KK+j][h*64+d];
// bds: shifted BD~ bf16 [bh*1024+t][KK]; vt: V^T [(bh*64+d)][KK].
// ---------------------------------------------------------------------------
template<int KK, int MODE>
__global__ __launch_bounds__(512)
void fattn(const u16* __restrict__ qw, const u16* __restrict__ kb,
           const u16* __restrict__ bds, const u16* __restrict__ vt,
           float* __restrict__ probs, u16* __restrict__ ob)
{
    constexpr int LE = KK + 8;
    __shared__ __align__(16) u16 e[32 * LE];
    __shared__ __align__(16) u16 qs[32 * 72];
    __shared__ float pmax[32][4];
    __shared__ float rinv[32];

    const int tid = threadIdx.x;
    const int bh  = blockIdx.y;
    const int b   = bh >> 4, h = bh & 15;
    const int t0  = blockIdx.x << 5;

    // stage Q(+bias) tile: 32 rows x 64 cols bf16
    if (tid < 256) {
        const int row = tid >> 3, ch = tid & 7;
        *(short8*)&qs[row * 72 + ch * 8] =
            *(const short8*)(qw + ((long long)(b * 1024 + t0 + row)) * 1024 + h * 64 + ch * 8);
    }
    __syncthreads();

    const int w = tid >> 6, lane = tid & 63;
    const int wr = w & 1, cf = w >> 1;           // row-half, col-frag group
    const int lc = lane & 15, lk = (lane >> 4) << 3;
    const int rloc0 = wr * 16 + ((lane >> 4) << 2);

    const short8 af0 = *(const short8*)&qs[(wr * 16 + lc) * 72 + lk];
    const short8 af1 = *(const short8*)&qs[(wr * 16 + lc) * 72 + 32 + lk];

    float m4[4] = {-3e38f, -3e38f, -3e38f, -3e38f};
    const long long bdrow = (long long)bh * 1024 + t0;

    const int nt = KK >> 7;
    for (int jt = 0; jt < nt; ++jt) {
        const int j0 = jt << 7;
        if (MODE == 0 && j0 > t0 + 1055) {       // fully masked tile
            #pragma unroll
            for (int s = 0; s < 2; ++s)
                #pragma unroll
                for (int r = 0; r < 4; ++r)
                    e[(rloc0 + r) * LE + j0 + cf * 32 + s * 16 + lc] = 0xFF80u;
            continue;
        }
        #pragma unroll
        for (int s = 0; s < 2; ++s) {
            const int jcol = j0 + cf * 32 + s * 16 + lc;
            const u16* kg = kb + ((long long)(b * KK + jcol)) * 1024 + h * 64;
            short8 bv0 = *(const short8*)(kg + lk);
            short8 bv1 = *(const short8*)(kg + 32 + lk);
            f4 acc = {};
            acc = __builtin_amdgcn_mfma_f32_16x16x32_bf16(af0, bv0, acc, 0, 0, 0);
            acc = __builtin_amdgcn_mfma_f32_16x16x32_bf16(af1, bv1, acc, 0, 0, 0);
            #pragma unroll
            for (int r = 0; r < 4; ++r) {
                const int tloc = rloc0 + r;
                const int tg = t0 + tloc;
                u16 st;
                if (MODE == 0) {
                    if (jcol <= tg + 1024) {
                        float bd = b2f(bds[((long long)bh * 1024 + tg) * KK + jcol]);
                        float sv = (acc[r] + bd) * 0.125f;
                        st = f2b(sv);
                        m4[r] = fmaxf(m4[r], sv);
                    } else st = 0xFF80u;
                } else {
                    float bd = (jcol == tg + 1) ? 0.f
                             : b2f(bds[((long long)bh * 1024 + tg) * KK + jcol]);
                    float sv = (acc[r] + bd) * 0.125f;
                    st = f2b(sv);
                    m4[r] = fmaxf(m4[r], sv);
                }
                e[tloc * LE + jcol] = st;
            }
        }
    }
    // combine per-row max across the 16 lanes of each row group
    #pragma unroll
    for (int o = 1; o < 16; o <<= 1)
        #pragma unroll
        for (int r = 0; r < 4; ++r)
            m4[r] = fmaxf(m4[r], __shfl_xor(m4[r], o));
    if (lc == 0)
        #pragma unroll
        for (int r = 0; r < 4; ++r) pmax[rloc0 + r][cf] = m4[r];
    __syncthreads();

    // exp + row-sum + normalized probs write
    const int r = tid >> 4, q = tid & 15;
    const float rmax = fmaxf(fmaxf(pmax[r][0], pmax[r][1]), fmaxf(pmax[r][2], pmax[r][3]));
    float* pr = probs + ((long long)bh * 1024 + t0 + r) * KK;
    float sum = 0.f;
    #pragma unroll 4
    for (int i = 0; i < KK / 128; ++i) {
        const int j0 = q * 8 + i * 128;
        short8 s8 = *(const short8*)&e[r * LE + j0];
        short8 st;
        #pragma unroll
        for (int k2 = 0; k2 < 8; ++k2) {
            float ev = __expf(b2f((u16)s8[k2]) - rmax);   // masked: exp(-inf)=0
            sum += ev;
            st[k2] = (short)f2b(ev);
        }
        *(short8*)&e[r * LE + j0] = st;
    }
    #pragma unroll
    for (int o = 1; o < 16; o <<= 1) sum += __shfl_xor(sum, o);
    const float inv = 1.f / sum;
    if (q == 0) rinv[r] = inv;
    #pragma unroll 4
    for (int i = 0; i < KK / 128; ++i) {
        const int j0 = q * 8 + i * 128;
        short8 e8 = *(const short8*)&e[r * LE + j0];
        f4 p0, p1;
        p0.x = b2f((u16)e8[0]) * inv; p0.y = b2f((u16)e8[1]) * inv;
        p0.z = b2f((u16)e8[2]) * inv; p0.w = b2f((u16)e8[3]) * inv;
        p1.x = b2f((u16)e8[4]) * inv; p1.y = b2f((u16)e8[5]) * inv;
        p1.z = b2f((u16)e8[6]) * inv; p1.w = b2f((u16)e8[7]) * inv;
        *(f4*)(pr + j0) = p0;
        *(f4*)(pr + j0 + 4) = p1;
    }
    __syncthreads();

    // PV: 8 waves = 2 row-blocks x 4 d-blocks of 16x16 output
    const int rb = w >> 2, db = (w & 3) << 4;
    const u16* vrow = vt + ((long long)bh * 64 + db + lc) * KK + lk;
    f4 acc = {};
    #pragma unroll 8
    for (int kc = 0; kc < KK / 32; ++kc) {
        short8 a = *(const short8*)&e[(rb * 16 + lc) * LE + kc * 32 + lk];
        short8 bvv = *(const short8*)(vrow + kc * 32);
        acc = __builtin_amdgcn_mfma_f32_16x16x32_bf16(a, bvv, acc, 0, 0, 0);
    }
    const int orow = (lane >> 4) << 2;
    u16* obase = ob + ((long long)(b * 1024 + t0 + rb * 16 + orow)) * 1024 + h * 64 + db + lc;
    #pragma unroll
    for (int rr = 0; rr < 4; ++rr) {
        float val = acc[rr] * rinv[rb * 16 + orow + rr];
        obase[(long long)rr * 1024] = f2b(val);
    }
}

// ---------------------------------------------------------------------------
// Elementwise / layout kernels
// ---------------------------------------------------------------------------
__global__ void conv_f2b(const float* __restrict__ in, u16* __restrict__ out, long long n4)
{
    long long i = (long long)blockIdx.x * 256 + threadIdx.x;
    if (i >= n4) return;
    f4 v = *(const f4*)(in + i * 4);
    u16x4 o; o.x = f2b(v.x); o.y = f2b(v.y); o.z = f2b(v.z); o.w = f2b(v.w);
    *(u16x4*)(out + i * 4) = o;
}

__global__ void concat_mem(const float* __restrict__ mem, const float* __restrict__ tgt,
                           float* __restrict__ nm, u16* __restrict__ cat)
{
    long long i = (long long)blockIdx.x * 256 + threadIdx.x;
    long long b = i >> 19;
    int rem = (int)(i & 524287);
    int r = rem >> 8, c4 = rem & 255;
    const float* sp = (r < 1024) ? (mem + ((b << 10) + r) * 1024 + c4 * 4)
                                 : (tgt + ((b << 10) + (r - 1024)) * 1024 + c4 * 4);
    f4 v = *(const f4*)sp;
    *(f4*)(nm + i * 4) = v;
    u16x4 o; o.x = f2b(v.x); o.y = f2b(v.y); o.z = f2b(v.z); o.w = f2b(v.w);
    *(u16x4*)(cat + i * 4) = o;
}

__global__ void transpose_w(const float* __restrict__ W, u16* __restrict__ Wt, int R, int C)
{
    __shared__ float tile[32][33];
    int c0 = blockIdx.x * 32, r0 = blockIdx.y * 32;
    int tx = threadIdx.x, ty = threadIdx.y;
    tile[ty][tx] = W[(long long)(r0 + ty) * C + c0 + tx];
    __syncthreads();
    Wt[(long long)(c0 + ty) * R + r0 + tx] = f2b(tile[tx][ty]);
}

__global__ void transpose_v(const u16* __restrict__ v, u16* __restrict__ vt, int K)
{
    __shared__ u16 tile[32][33];
    int z = blockIdx.z; int b = z >> 4, hh = z & 15;
    int j0 = blockIdx.x * 32, d0 = blockIdx.y * 32;
    int tx = threadIdx.x, ty = threadIdx.y;
    tile[ty][tx] = v[((long long)b * K + j0 + ty) * 1024 + hh * 64 + d0 + tx];
    __syncthreads();
    vt[((long long)((b * 16 + hh) * 64 + d0 + ty)) * K + j0 + tx] = tile[tx][ty];
}

__global__ void add_qbias(const u16* __restrict__ q, const float* __restrict__ rwb,
                          const float* __restrict__ rrb, u16* __restrict__ qw, u16* __restrict__ qr)
{
    long long i = (long long)blockIdx.x * 256 + threadIdx.x;
    int hd = (int)((i * 4) & 1023);
    u16x4 qq = *(const u16x4*)(q + i * 4);
    f4 wv = *(const f4*)(rwb + hd);
    f4 rv = *(const f4*)(rrb + hd);
    u16x4 a, c;
    a.x = f2b(b2f(qq.x) + wv.x); a.y = f2b(b2f(qq.y) + wv.y);
    a.z = f2b(b2f(qq.z) + wv.z); a.w = f2b(b2f(qq.w) + wv.w);
    c.x = f2b(b2f(qq.x) + rv.x); c.y = f2b(b2f(qq.y) + rv.y);
    c.z = f2b(b2f(qq.z) + rv.z); c.w = f2b(b2f(qq.w) + rv.w);
    *(u16x4*)(qw + i * 4) = a;
    *(u16x4*)(qr + i * 4) = c;
}

__global__ __launch_bounds__(256) void ln_res(const float* __restrict__ x, const float* __restrict__ h,
                                              const float* __restrict__ g, const float* __restrict__ bl,
                                              float* __restrict__ o32, u16* __restrict__ obf)
{
    const long long row = blockIdx.x;
    const int tid = threadIdx.x;
    const long long base = row * 1024 + tid * 4;
    f4 xa = *(const f4*)(x + base);
    f4 ha = *(const f4*)(h + base);
    float v0 = xa.x + ha.x, v1 = xa.y + ha.y, v2 = xa.z + ha.z, v3 = xa.w + ha.w;
    float lsum = v0 + v1 + v2 + v3;
    float lsq = v0 * v0 + v1 * v1 + v2 * v2 + v3 * v3;
    #pragma unroll
    for (int o2 = 32; o2; o2 >>= 1) { lsum += __shfl_xor(lsum, o2); lsq += __shfl_xor(lsq, o2); }
    __shared__ float r1[4], r2[4];
    int w = tid >> 6, lane = tid & 63;
    if (lane == 0) { r1[w] = lsum; r2[w] = lsq; }
    __syncthreads();
    lsum = r1[0] + r1[1] + r1[2] + r1[3];
    lsq  = r2[0] + r2[1] + r2[2] + r2[3];
    const float mu = lsum * 0.0009765625f;
    const float var = lsq * 0.0009765625f - mu * mu;
    const float rsd = rsqrtf(var + 1e-5f);
    const int c = tid * 4;
    f4 gv = *(const f4*)(g + c);
    f4 bv = *(const f4*)(bl + c);
    f4 y;
    y.x = (v0 - mu) * rsd * gv.x + bv.x;
    y.y = (v1 - mu) * rsd * gv.y + bv.y;
    y.z = (v2 - mu) * rsd * gv.z + bv.z;
    y.w = (v3 - mu) * rsd * gv.w + bv.w;
    *(f4*)(o32 + base) = y;
    if (obf) {
        u16x4 u; u.x = f2b(y.x); u.y = f2b(y.y); u.z = f2b(y.z); u.w = f2b(y.w);
        *(u16x4*)(obf + base) = u;
    }
}

// ---------------------------------------------------------------------------
extern "C" void kernel_launch(void* const* d_in, const int* in_sizes, int n_in,
                              void* d_out, int out_size, void* d_ws, size_t ws_size,
                              hipStream_t stream)
{
    (void)in_sizes; (void)n_in; (void)out_size;
    const float* src  = (const float*)d_in[0];
    const float* tgt  = (const float*)d_in[1];
    const float* mem  = (const float*)d_in[2];
    const float* pos  = (const float*)d_in[3];
    const float* rwb  = (const float*)d_in[4];
    const float* rrb  = (const float*)d_in[5];
    const float* Wq1  = (const float*)d_in[6];
    const float* Wk1  = (const float*)d_in[7];
    const float* Wv1  = (const float*)d_in[8];
    const float* Wr1  = (const float*)d_in[9];
    const float* Wo1  = (const float*)d_in[10];
    const float* ln1g = (const float*)d_in[11];
    const float* ln1b = (const float*)d_in[12];
    const float* Wq2  = (const float*)d_in[13];
    const float* Wk2  = (const float*)d_in[14];
    const float* Wv2  = (const float*)d_in[15];
    const float* Wr2  = (const float*)d_in[16];
    const float* Wo2  = (const float*)d_in[17];
    const float* ln2g = (const float*)d_in[18];
    const float* ln2b = (const float*)d_in[19];
    const float* Wf1  = (const float*)d_in[20];
    const float* bf1  = (const float*)d_in[21];
    const float* Wf2  = (const float*)d_in[22];
    const float* bf2  = (const float*)d_in[23];
    const float* ln3g = (const float*)d_in[24];
    const float* ln3b = (const float*)d_in[25];

    float* outp   = (float*)d_out;            // [4,1024,1024]
    float* newmem = outp + 4194304;           // [4,2048,1024]
    float* selfP  = outp + 12582912;          // [4,16,1024,2048]
    float* interP = outp + 146800640;         // [4,16,1024,1024]

    char* ws = (char*)d_ws;
    size_t off = 0;
    auto alloc = [&](size_t bytes) -> void* {
        void* p = ws + off;
        off = (off + bytes + 255) & ~(size_t)255;
        return p;
    };
    u16*   tgt_bf  = (u16*)alloc(8u << 20);
    u16*   src_bf  = (u16*)alloc(8u << 20);
    u16*   cat_bf  = (u16*)alloc(16u << 20);
    u16*   pos_bf  = (u16*)alloc(4u << 20);
    u16*   Wq1t = (u16*)alloc(2u << 20);
    u16*   Wk1t = (u16*)alloc(2u << 20);
    u16*   Wv1t = (u16*)alloc(2u << 20);
    u16*   Wr1t = (u16*)alloc(2u << 20);
    u16*   Wo1t = (u16*)alloc(2u << 20);
    u16*   Wq2t = (u16*)alloc(2u << 20);
    u16*   Wk2t = (u16*)alloc(2u << 20);
    u16*   Wv2t = (u16*)alloc(2u << 20);
    u16*   Wr2t = (u16*)alloc(2u << 20);
    u16*   Wo2t = (u16*)alloc(2u << 20);
    u16*   Wf1t = (u16*)alloc(8u << 20);
    u16*   Wf2t = (u16*)alloc(8u << 20);
    u16*   qb   = (u16*)alloc(8u << 20);
    u16*   qwb  = (u16*)alloc(8u << 20);
    u16*   qrb  = (u16*)alloc(8u << 20);
    u16*   kb   = (u16*)alloc(16u << 20);
    u16*   vb   = (u16*)alloc(16u << 20);
    u16*   vtb  = (u16*)alloc(16u << 20);
    u16*   ob   = (u16*)alloc(8u << 20);
    float* projb = (float*)alloc(16u << 20);
    u16*   r1b  = (u16*)alloc(4u << 20);
    u16*   r2b  = (u16*)alloc(2u << 20);
    float* out1_32 = (float*)alloc(16u << 20);
    u16*   out1_bf = (u16*)alloc(8u << 20);
    float* out2_32 = (float*)alloc(16u << 20);
    u16*   out2_bf = (u16*)alloc(8u << 20);
    u16*   hb   = (u16*)alloc(32u << 20);
    u16*   bdt2 = (u16*)alloc(128u << 20);    // [b*16+h][1024][1024] bf16
    if (off > ws_size) return;

    dim3 tb(32, 32);

    // ---- phase 0: conversions / transposes / new_mem
    concat_mem<<<8192, 256, 0, stream>>>(mem, tgt, newmem, cat_bf);
    conv_f2b<<<4096, 256, 0, stream>>>(tgt, tgt_bf, 1048576);
    conv_f2b<<<4096, 256, 0, stream>>>(src, src_bf, 1048576);
    conv_f2b<<<2048, 256, 0, stream>>>(pos, pos_bf, 524288);
    transpose_w<<<dim3(32, 32), tb, 0, stream>>>(Wq1, Wq1t, 1024, 1024);
    transpose_w<<<dim3(32, 32), tb, 0, stream>>>(Wk1, Wk1t, 1024, 1024);
    transpose_w<<<dim3(32, 32), tb, 0, stream>>>(Wv1, Wv1t, 1024, 1024);
    transpose_w<<<dim3(32, 32), tb, 0, stream>>>(Wr1, Wr1t, 1024, 1024);
    transpose_w<<<dim3(32, 32), tb, 0, stream>>>(Wo1, Wo1t, 1024, 1024);
    transpose_w<<<dim3(32, 32), tb, 0, stream>>>(Wq2, Wq2t, 1024, 1024);
    transpose_w<<<dim3(32, 32), tb, 0, stream>>>(Wk2, Wk2t, 1024, 1024);
    transpose_w<<<dim3(32, 32), tb, 0, stream>>>(Wv2, Wv2t, 1024, 1024);
    transpose_w<<<dim3(32, 32), tb, 0, stream>>>(Wr2, Wr2t, 1024, 1024);
    transpose_w<<<dim3(32, 32), tb, 0, stream>>>(Wo2, Wo2t, 1024, 1024);
    transpose_w<<<dim3(128, 32), tb, 0, stream>>>(Wf1, Wf1t, 1024, 4096);
    transpose_w<<<dim3(32, 128), tb, 0, stream>>>(Wf2, Wf2t, 4096, 1024);

    // ---- layer 1: self relative attention (K=2048)
    gemm_bt<4,4,1,0,0><<<dim3(8,32,1), 256, 0, stream>>>(tgt_bf, Wq1t, qb, nullptr,
        4096,1024,1024, 1024,1024,1024, 0,0,0,0,0,0, 1);
    gemm_bt<4,4,1,0,0><<<dim3(8,64,1), 256, 0, stream>>>(cat_bf, Wk1t, kb, nullptr,
        8192,1024,1024, 1024,1024,1024, 0,0,0,0,0,0, 1);
    gemm_bt<4,4,1,0,0><<<dim3(8,64,1), 256, 0, stream>>>(cat_bf, Wv1t, vb, nullptr,
        8192,1024,1024, 1024,1024,1024, 0,0,0,0,0,0, 1);
    gemm_bt<4,4,1,0,0><<<dim3(8,16,1), 256, 0, stream>>>(pos_bf, Wr1t, r1b, nullptr,
        2048,1024,1024, 1024,1024,1024, 0,0,0,0,0,0, 1);
    add_qbias<<<4096, 256, 0, stream>>>(qb, rwb, rrb, qwb, qrb);
    // BD~ rel-shifted -> interP region (bf16 scratch, exact fit)
    gemm_bt<4,4,1,0,1><<<dim3(16,8,64), 256, 0, stream>>>(qrb, r1b, (void*)interP, nullptr,
        1024,2048,64, 1024,1024,2048,
        64LL,1048576LL, 64LL,0LL, 2097152LL,33554432LL, 16);
    transpose_v<<<dim3(64,2,64), tb, 0, stream>>>(vb, vtb, 2048);
    fattn<2048,0><<<dim3(32,64), 512, 0, stream>>>(qwb, kb, (const u16*)interP, vtb, selfP, ob);
    gemm_bt<4,4,0,0,0><<<dim3(8,32,1), 256, 0, stream>>>(ob, Wo1t, projb, nullptr,
        4096,1024,1024, 1024,1024,1024, 0,0,0,0,0,0, 1);
    ln_res<<<4096, 256, 0, stream>>>(tgt, projb, ln1g, ln1b, out1_32, out1_bf);

    // ---- layer 2: cross relative attention (K=1024, no mask)
    gemm_bt<4,4,1,0,0><<<dim3(8,32,1), 256, 0, stream>>>(out1_bf, Wq2t, qb, nullptr,
        4096,1024,1024, 1024,1024,1024, 0,0,0,0,0,0, 1);
    gemm_bt<4,4,1,0,0><<<dim3(8,32,1), 256, 0, stream>>>(src_bf, Wk2t, kb, nullptr,
        4096,1024,1024, 1024,1024,1024, 0,0,0,0,0,0, 1);
    gemm_bt<4,4,1,0,0><<<dim3(8,32,1), 256, 0, stream>>>(src_bf, Wv2t, vb, nullptr,
        4096,1024,1024, 1024,1024,1024, 0,0,0,0,0,0, 1);
    gemm_bt<4,4,1,0,0><<<dim3(8,8,1), 256, 0, stream>>>(pos_bf + 1048576, Wr2t, r2b, nullptr,
        1024,1024,1024, 1024,1024,1024, 0,0,0,0,0,0, 1);
    add_qbias<<<4096, 256, 0, stream>>>(qb, rwb, rrb, qwb, qrb);
    // BD~2 rel-shifted (dual-write), batched over all (b,h)
    gemm_bt<4,4,1,0,2><<<dim3(8,8,64), 256, 0, stream>>>(qrb, r2b, bdt2, nullptr,
        1024,1024,64, 1024,1024,1024,
        64LL,1048576LL, 64LL,0LL, 1048576LL,16777216LL, 16);
    transpose_v<<<dim3(32,2,64), tb, 0, stream>>>(vb, vtb, 1024);
    fattn<1024,1><<<dim3(32,64), 512, 0, stream>>>(qwb, kb, bdt2, vtb, interP, ob);
    gemm_bt<4,4,0,0,0><<<dim3(8,32,1), 256, 0, stream>>>(ob, Wo2t, projb, nullptr,
        4096,1024,1024, 1024,1024,1024, 0,0,0,0,0,0, 1);
    ln_res<<<4096, 256, 0, stream>>>(out1_32, projb, ln2g, ln2b, out2_32, out2_bf);

    // ---- layer 3: FF
    gemm_bt<4,4,1,2,0><<<dim3(32,32,1), 256, 0, stream>>>(out2_bf, Wf1t, hb, bf1,
        4096,4096,1024, 1024,1024,4096, 0,0,0,0,0,0, 1);
    gemm_bt<4,4,0,1,0><<<dim3(8,32,1), 256, 0, stream>>>(hb, Wf2t, projb, bf2,
        4096,1024,4096, 4096,4096,1024, 0,0,0,0,0,0, 1);
    ln_res<<<4096, 256, 0, stream>>>(out2_32, projb, ln3g, ln3b, outp, nullptr);
}

// Round 4
// 1418.103 us; speedup vs baseline: 1.2484x; 1.2484x over previous
//
#include <hip/hip_runtime.h>

typedef unsigned short u16;
typedef __attribute__((ext_vector_type(8))) short short8;
typedef __attribute__((ext_vector_type(4))) float f4;
typedef __attribute__((ext_vector_type(4))) unsigned short u16x4;

__device__ __forceinline__ float b2f(u16 u) {
    unsigned int x = ((unsigned int)u) << 16;
    return __builtin_bit_cast(float, x);
}
__device__ __forceinline__ u16 f2b(float f) {
    unsigned int u = __builtin_bit_cast(unsigned int, f);
    u += 0x7FFFu + ((u >> 16) & 1u);   // round-to-nearest-even
    return (u16)(u >> 16);
}

__device__ __forceinline__ void gl16(const void* g, void* l) {
    __builtin_amdgcn_global_load_lds(
        (const __attribute__((address_space(1))) void*)g,
        (__attribute__((address_space(3))) void*)l, 16, 0, 0);
}

// ---------------------------------------------------------------------------
// bf16 MFMA GEMM with global_load_lds staging (m97 structure):
//   C[M,N] = A[M,K] @ Bt[N,K]^T  (+bias, +relu)
// Tile 128x128, BK=32, 4 waves (2x2), each wave 64x64 (4x4 fragments 16x16).
// CBF: 0 f32-out, 1 bf16-out. EPI: 0 none, 1 +bias, 2 +bias+relu.
// SHIFT (CBF=1 only): 0 none, 1 self rel-shift write, 2 cross rel-shift write.
// ---------------------------------------------------------------------------
template<int FM, int FN, int CBF, int EPI, int SHIFT>
__global__ __launch_bounds__(256, 3)
void gemm_bt(const u16* __restrict__ Ap, const u16* __restrict__ Bp,
             void* __restrict__ Cp, const float* __restrict__ bias,
             int M, int N, int K, int lda, int ldb, int ldc,
             long long sAh, long long sAb, long long sBh, long long sBb,
             long long sCh, long long sCb, int batchH)
{
    constexpr int BM = FM * 32;
    constexpr int BN = FN * 32;
    __shared__ __align__(16) u16 As[BM * 32];
    __shared__ __align__(16) u16 Bs[BN * 32];

    const int tid  = threadIdx.x;
    const int z    = blockIdx.z;
    const int bb   = z / batchH;
    const int hh   = z - bb * batchH;
    const int m0   = blockIdx.y * BM;
    const int n0   = blockIdx.x * BN;
    const int w    = tid >> 6;
    const int lane = tid & 63;
    const int wr   = w >> 1;
    const int wc   = w & 1;
    const int lrow = lane & 15;
    const int lk   = (lane >> 4) << 3;
    const int lrow4 = lane >> 2;
    const int lch   = lane & 3;

    const u16* Ag = Ap + sAb * bb + sAh * hh;
    const u16* Bg = Bp + sBb * bb + sBh * hh;

    f4 acc[FM][FN] = {};

    const int nKt = K >> 5;
    for (int kt = 0; kt < nKt; ++kt) {
        const int kb = kt << 5;
        __syncthreads();
        #pragma unroll
        for (int i = 0; i < BM / 64; ++i) {
            const int row0 = (w + i * 4) << 4;
            gl16(Ag + (long long)(m0 + row0 + lrow4) * lda + kb + (lch << 3),
                 &As[row0 * 32]);
        }
        #pragma unroll
        for (int i = 0; i < BN / 64; ++i) {
            const int row0 = (w + i * 4) << 4;
            gl16(Bg + (long long)(n0 + row0 + lrow4) * ldb + kb + (lch << 3),
                 &Bs[row0 * 32]);
        }
        __syncthreads();

        short8 af[FM], bv[FN];
        #pragma unroll
        for (int m = 0; m < FM; ++m)
            af[m] = *(const short8*)(&As[(wr * FM * 16 + m * 16 + lrow) * 32 + lk]);
        #pragma unroll
        for (int n = 0; n < FN; ++n)
            bv[n] = *(const short8*)(&Bs[(wc * FN * 16 + n * 16 + lrow) * 32 + lk]);
        #pragma unroll
        for (int m = 0; m < FM; ++m)
            #pragma unroll
            for (int n = 0; n < FN; ++n)
                acc[m][n] = __builtin_amdgcn_mfma_f32_16x16x32_bf16(af[m], bv[n], acc[m][n], 0, 0, 0);
    }

    const int crow0 = m0 + wr * FM * 16 + ((lane >> 4) << 2);
    const int ccol0 = n0 + wc * FN * 16 + lrow;
    if (CBF == 0) {
        float* Cg = (float*)Cp + sCb * bb + sCh * hh;
        #pragma unroll
        for (int m = 0; m < FM; ++m) {
            #pragma unroll
            for (int n = 0; n < FN; ++n) {
                const int col = ccol0 + n * 16;
                float bvv = (EPI >= 1) ? bias[col] : 0.f;
                #pragma unroll
                for (int r = 0; r < 4; ++r) {
                    float vv = acc[m][n][r] + bvv;
                    if (EPI == 2) vv = fmaxf(vv, 0.f);
                    Cg[(long long)(crow0 + m * 16 + r) * ldc + col] = vv;
                }
            }
        }
    } else {
        u16* Cg = (u16*)Cp + sCb * bb + sCh * hh;
        #pragma unroll
        for (int m = 0; m < FM; ++m) {
            #pragma unroll
            for (int n = 0; n < FN; ++n) {
                const int col = ccol0 + n * 16;
                float bvv = (EPI >= 1) ? bias[col] : 0.f;
                #pragma unroll
                for (int r = 0; r < 4; ++r) {
                    float vv = acc[m][n][r] + bvv;
                    if (EPI == 2) vv = fmaxf(vv, 0.f);
                    const int t = crow0 + m * 16 + r;
                    if (SHIFT == 0) {
                        Cg[(long long)t * ldc + col] = f2b(vv);
                    } else if (SHIFT == 1) {
                        const int j = col + t - 1023;
                        if (j >= 0 && j < 2048) Cg[(long long)t * ldc + j] = f2b(vv);
                    } else {
                        const int j1 = col + t - 1023;
                        if (j1 >= 0) Cg[(long long)t * ldc + j1] = f2b(vv);
                        const int j2 = col + t + 1;
                        if (t >= 1 && j2 < 1024) Cg[(long long)(t - 1) * ldc + j2] = f2b(vv);
                    }
                }
            }
        }
    }
}

// ---------------------------------------------------------------------------
// Fused attention v2: 16 q-rows per block, 256 threads (4 waves).
// Phase A: AC scores via MFMA (K gathers from L2) -> LDS bf16 (no global dep).
// Phase B: row-parallel streaming: AC + BD (coalesced short8), exp (no max-sub),
//          unnormalized exp -> LDS, normalized f32 probs -> HBM.
// Phase C: PV MFMA from LDS exp + V^T gathers; scale by 1/sum at the end.
// Scores are pre-scaled by 0.125 (folded into qw and bds).
// MODE 0: self causal (limit=t+1024, skip masked tiles), KK=2048.
// MODE 1: cross (zero-BD col at j==t+1), KK=1024.
// ---------------------------------------------------------------------------
template<int KK, int MODE>
__global__ __launch_bounds__(256)
void fattn(const u16* __restrict__ qw, const u16* __restrict__ kb,
           const u16* __restrict__ bds, const u16* __restrict__ vt,
           float* __restrict__ probs, u16* __restrict__ ob)
{
    constexpr int LE = KK + 8;
    __shared__ __align__(16) u16 e[16 * LE];
    __shared__ __align__(16) u16 qs[16 * 72];
    __shared__ float rinv[16];

    const int tid = threadIdx.x;
    const int bh  = blockIdx.y;
    const int b   = bh >> 4, h = bh & 15;
    const int t0  = blockIdx.x << 4;

    // stage Q tile (16 x 64 bf16, already scaled by 0.125)
    if (tid < 128) {
        const int row = tid >> 3, ch = tid & 7;
        *(short8*)&qs[row * 72 + ch * 8] =
            *(const short8*)(qw + ((long long)(b * 1024 + t0 + row)) * 1024 + h * 64 + ch * 8);
    }
    __syncthreads();

    const int w = tid >> 6, lane = tid & 63;
    const int lc = lane & 15, g = lane >> 4;
    const int lk = g << 3;

    const short8 af0 = *(const short8*)&qs[lc * 72 + lk];
    const short8 af1 = *(const short8*)&qs[lc * 72 + 32 + lk];

    // ---- Phase A: AC -> e (bf16)
    constexpr int STRIP = KK / 4;
    const int c0 = w * STRIP;
    const int jmaxv = t0 + 15 + 1024;          // last possibly-valid col (self)
    for (int jt = 0; jt < STRIP / 32; ++jt) {
        const int jb = c0 + jt * 32;
        if (MODE == 0 && jb > jmaxv) break;     // ascending strip: rest masked
        #pragma unroll
        for (int s = 0; s < 2; ++s) {
            const int jcol = jb + s * 16 + lc;
            const u16* kg = kb + ((long long)(b * KK + jcol)) * 1024 + h * 64;
            short8 bv0 = *(const short8*)(kg + lk);
            short8 bv1 = *(const short8*)(kg + 32 + lk);
            f4 acc = {};
            acc = __builtin_amdgcn_mfma_f32_16x16x32_bf16(af0, bv0, acc, 0, 0, 0);
            acc = __builtin_amdgcn_mfma_f32_16x16x32_bf16(af1, bv1, acc, 0, 0, 0);
            #pragma unroll
            for (int r = 0; r < 4; ++r)
                e[(g * 4 + r) * LE + jcol] = f2b(acc[r]);
        }
    }
    __syncthreads();

    // ---- Phase B: row-parallel BD add + exp + sums + probs write
    {
        const int r = tid >> 4, q = tid & 15;
        const int t = t0 + r;
        const int limit = t + 1024;             // self only
        const u16* bd = bds + ((long long)bh * 1024 + t) * KK;
        float* pr = probs + ((long long)bh * 1024 + t) * KK;
        float sum = 0.f;
        for (int i = 0; i < KK / 128; ++i) {
            const int j0 = q * 8 + i * 128;
            short8 st;
            if (MODE == 0 && j0 > limit) {
                #pragma unroll
                for (int k2 = 0; k2 < 8; ++k2) st[k2] = 0;
                *(short8*)&e[r * LE + j0] = st;
                continue;
            }
            short8 a8 = *(const short8*)&e[r * LE + j0];
            short8 b8 = *(const short8*)(bd + j0);
            #pragma unroll
            for (int k2 = 0; k2 < 8; ++k2) {
                const int j = j0 + k2;
                float bdv = b2f((u16)b8[k2]);
                if (MODE == 1 && j == t + 1) bdv = 0.f;
                float sv = b2f((u16)a8[k2]) + bdv;
                float ev = __expf(sv);
                if (MODE == 0 && j > limit) ev = 0.f;
                sum += ev;
                st[k2] = (short)f2b(ev);
            }
            *(short8*)&e[r * LE + j0] = st;
        }
        #pragma unroll
        for (int o = 1; o < 16; o <<= 1) sum += __shfl_xor(sum, o);
        const float inv = 1.f / sum;
        if (q == 0) rinv[r] = inv;
        for (int i = 0; i < KK / 128; ++i) {
            const int j0 = q * 8 + i * 128;
            short8 e8 = *(const short8*)&e[r * LE + j0];
            f4 p0, p1;
            p0.x = b2f((u16)e8[0]) * inv; p0.y = b2f((u16)e8[1]) * inv;
            p0.z = b2f((u16)e8[2]) * inv; p0.w = b2f((u16)e8[3]) * inv;
            p1.x = b2f((u16)e8[4]) * inv; p1.y = b2f((u16)e8[5]) * inv;
            p1.z = b2f((u16)e8[6]) * inv; p1.w = b2f((u16)e8[7]) * inv;
            *(f4*)(pr + j0) = p0;
            *(f4*)(pr + j0 + 4) = p1;
        }
    }
    __syncthreads();

    // ---- Phase C: PV (4 waves x 16 d-cols), causal k-bound for self
    const int db = w << 4;
    const u16* vrow = vt + ((long long)bh * 64 + db + lc) * KK + lk;
    const int kcend = (MODE == 0) ? ((t0 + 1040 + 31) >> 5) : (KK / 32);
    f4 acc = {};
    for (int kc = 0; kc < kcend; ++kc) {
        short8 a = *(const short8*)&e[lc * LE + kc * 32 + lk];
        short8 bvv = *(const short8*)(vrow + kc * 32);
        acc = __builtin_amdgcn_mfma_f32_16x16x32_bf16(a, bvv, acc, 0, 0, 0);
    }
    const int orow = g << 2;
    u16* obase = ob + ((long long)(b * 1024 + t0 + orow)) * 1024 + h * 64 + db + lc;
    #pragma unroll
    for (int rr = 0; rr < 4; ++rr)
        obase[(long long)rr * 1024] = f2b(acc[rr] * rinv[orow + rr]);
}

// ---------------------------------------------------------------------------
// Elementwise / layout kernels
// ---------------------------------------------------------------------------
__global__ void conv_f2b(const float* __restrict__ in, u16* __restrict__ out, long long n4)
{
    long long i = (long long)blockIdx.x * 256 + threadIdx.x;
    if (i >= n4) return;
    f4 v = *(const f4*)(in + i * 4);
    u16x4 o; o.x = f2b(v.x); o.y = f2b(v.y); o.z = f2b(v.z); o.w = f2b(v.w);
    *(u16x4*)(out + i * 4) = o;
}

__global__ void concat_mem(const float* __restrict__ mem, const float* __restrict__ tgt,
                           float* __restrict__ nm, u16* __restrict__ cat)
{
    long long i = (long long)blockIdx.x * 256 + threadIdx.x;
    long long b = i >> 19;
    int rem = (int)(i & 524287);
    int r = rem >> 8, c4 = rem & 255;
    const float* sp = (r < 1024) ? (mem + ((b << 10) + r) * 1024 + c4 * 4)
                                 : (tgt + ((b << 10) + (r - 1024)) * 1024 + c4 * 4);
    f4 v = *(const f4*)sp;
    *(f4*)(nm + i * 4) = v;
    u16x4 o; o.x = f2b(v.x); o.y = f2b(v.y); o.z = f2b(v.z); o.w = f2b(v.w);
    *(u16x4*)(cat + i * 4) = o;
}

__global__ void transpose_w(const float* __restrict__ W, u16* __restrict__ Wt, int R, int C)
{
    __shared__ float tile[32][33];
    int c0 = blockIdx.x * 32, r0 = blockIdx.y * 32;
    int tx = threadIdx.x, ty = threadIdx.y;
    tile[ty][tx] = W[(long long)(r0 + ty) * C + c0 + tx];
    __syncthreads();
    Wt[(long long)(c0 + ty) * R + r0 + tx] = f2b(tile[tx][ty]);
}

__global__ void transpose_v(const u16* __restrict__ v, u16* __restrict__ vt, int K)
{
    __shared__ u16 tile[32][33];
    int z = blockIdx.z; int b = z >> 4, hh = z & 15;
    int j0 = blockIdx.x * 32, d0 = blockIdx.y * 32;
    int tx = threadIdx.x, ty = threadIdx.y;
    tile[ty][tx] = v[((long long)b * K + j0 + ty) * 1024 + hh * 64 + d0 + tx];
    __syncthreads();
    vt[((long long)((b * 16 + hh) * 64 + d0 + ty)) * K + j0 + tx] = tile[tx][ty];
}

// qw = (q + r_w_bias)*0.125, qr = (q + r_r_bias)*0.125  (score scale folded in)
__global__ void add_qbias(const u16* __restrict__ q, const float* __restrict__ rwb,
                          const float* __restrict__ rrb, u16* __restrict__ qw, u16* __restrict__ qr)
{
    long long i = (long long)blockIdx.x * 256 + threadIdx.x;
    int hd = (int)((i * 4) & 1023);
    u16x4 qq = *(const u16x4*)(q + i * 4);
    f4 wv = *(const f4*)(rwb + hd);
    f4 rv = *(const f4*)(rrb + hd);
    u16x4 a, c;
    a.x = f2b((b2f(qq.x) + wv.x) * 0.125f); a.y = f2b((b2f(qq.y) + wv.y) * 0.125f);
    a.z = f2b((b2f(qq.z) + wv.z) * 0.125f); a.w = f2b((b2f(qq.w) + wv.w) * 0.125f);
    c.x = f2b((b2f(qq.x) + rv.x) * 0.125f); c.y = f2b((b2f(qq.y) + rv.y) * 0.125f);
    c.z = f2b((b2f(qq.z) + rv.z) * 0.125f); c.w = f2b((b2f(qq.w) + rv.w) * 0.125f);
    *(u16x4*)(qw + i * 4) = a;
    *(u16x4*)(qr + i * 4) = c;
}

__global__ __launch_bounds__(256) void ln_res(const float* __restrict__ x, const float* __restrict__ h,
                                              const float* __restrict__ g, const float* __restrict__ bl,
                                              float* __restrict__ o32, u16* __restrict__ obf)
{
    const long long row = blockIdx.x;
    const int tid = threadIdx.x;
    const long long base = row * 1024 + tid * 4;
    f4 xa = *(const f4*)(x + base);
    f4 ha = *(const f4*)(h + base);
    float v0 = xa.x + ha.x, v1 = xa.y + ha.y, v2 = xa.z + ha.z, v3 = xa.w + ha.w;
    float lsum = v0 + v1 + v2 + v3;
    float lsq = v0 * v0 + v1 * v1 + v2 * v2 + v3 * v3;
    #pragma unroll
    for (int o2 = 32; o2; o2 >>= 1) { lsum += __shfl_xor(lsum, o2); lsq += __shfl_xor(lsq, o2); }
    __shared__ float r1[4], r2[4];
    int w = tid >> 6, lane = tid & 63;
    if (lane == 0) { r1[w] = lsum; r2[w] = lsq; }
    __syncthreads();
    lsum = r1[0] + r1[1] + r1[2] + r1[3];
    lsq  = r2[0] + r2[1] + r2[2] + r2[3];
    const float mu = lsum * 0.0009765625f;
    const float var = lsq * 0.0009765625f - mu * mu;
    const float rsd = rsqrtf(var + 1e-5f);
    const int c = tid * 4;
    f4 gv = *(const f4*)(g + c);
    f4 bv = *(const f4*)(bl + c);
    f4 y;
    y.x = (v0 - mu) * rsd * gv.x + bv.x;
    y.y = (v1 - mu) * rsd * gv.y + bv.y;
    y.z = (v2 - mu) * rsd * gv.z + bv.z;
    y.w = (v3 - mu) * rsd * gv.w + bv.w;
    *(f4*)(o32 + base) = y;
    if (obf) {
        u16x4 u; u.x = f2b(y.x); u.y = f2b(y.y); u.z = f2b(y.z); u.w = f2b(y.w);
        *(u16x4*)(obf + base) = u;
    }
}

// ---------------------------------------------------------------------------
extern "C" void kernel_launch(void* const* d_in, const int* in_sizes, int n_in,
                              void* d_out, int out_size, void* d_ws, size_t ws_size,
                              hipStream_t stream)
{
    (void)in_sizes; (void)n_in; (void)out_size;
    const float* src  = (const float*)d_in[0];
    const float* tgt  = (const float*)d_in[1];
    const float* mem  = (const float*)d_in[2];
    const float* pos  = (const float*)d_in[3];
    const float* rwb  = (const float*)d_in[4];
    const float* rrb  = (const float*)d_in[5];
    const float* Wq1  = (const float*)d_in[6];
    const float* Wk1  = (const float*)d_in[7];
    const float* Wv1  = (const float*)d_in[8];
    const float* Wr1  = (const float*)d_in[9];
    const float* Wo1  = (const float*)d_in[10];
    const float* ln1g = (const float*)d_in[11];
    const float* ln1b = (const float*)d_in[12];
    const float* Wq2  = (const float*)d_in[13];
    const float* Wk2  = (const float*)d_in[14];
    const float* Wv2  = (const float*)d_in[15];
    const float* Wr2  = (const float*)d_in[16];
    const float* Wo2  = (const float*)d_in[17];
    const float* ln2g = (const float*)d_in[18];
    const float* ln2b = (const float*)d_in[19];
    const float* Wf1  = (const float*)d_in[20];
    const float* bf1  = (const float*)d_in[21];
    const float* Wf2  = (const float*)d_in[22];
    const float* bf2  = (const float*)d_in[23];
    const float* ln3g = (const float*)d_in[24];
    const float* ln3b = (const float*)d_in[25];

    float* outp   = (float*)d_out;            // [4,1024,1024]
    float* newmem = outp + 4194304;           // [4,2048,1024]
    float* selfP  = outp + 12582912;          // [4,16,1024,2048]
    float* interP = outp + 146800640;         // [4,16,1024,1024]

    char* ws = (char*)d_ws;
    size_t off = 0;
    auto alloc = [&](size_t bytes) -> void* {
        void* p = ws + off;
        off = (off + bytes + 255) & ~(size_t)255;
        return p;
    };
    u16*   tgt_bf  = (u16*)alloc(8u << 20);
    u16*   src_bf  = (u16*)alloc(8u << 20);
    u16*   cat_bf  = (u16*)alloc(16u << 20);
    u16*   pos_bf  = (u16*)alloc(4u << 20);
    u16*   Wq1t = (u16*)alloc(2u << 20);
    u16*   Wk1t = (u16*)alloc(2u << 20);
    u16*   Wv1t = (u16*)alloc(2u << 20);
    u16*   Wr1t = (u16*)alloc(2u << 20);
    u16*   Wo1t = (u16*)alloc(2u << 20);
    u16*   Wq2t = (u16*)alloc(2u << 20);
    u16*   Wk2t = (u16*)alloc(2u << 20);
    u16*   Wv2t = (u16*)alloc(2u << 20);
    u16*   Wr2t = (u16*)alloc(2u << 20);
    u16*   Wo2t = (u16*)alloc(2u << 20);
    u16*   Wf1t = (u16*)alloc(8u << 20);
    u16*   Wf2t = (u16*)alloc(8u << 20);
    u16*   qb   = (u16*)alloc(8u << 20);
    u16*   qwb  = (u16*)alloc(8u << 20);
    u16*   qrb  = (u16*)alloc(8u << 20);
    u16*   kb   = (u16*)alloc(16u << 20);
    u16*   vb   = (u16*)alloc(16u << 20);
    u16*   vtb  = (u16*)alloc(16u << 20);
    u16*   ob   = (u16*)alloc(8u << 20);
    float* projb = (float*)alloc(16u << 20);
    u16*   r1b  = (u16*)alloc(4u << 20);
    u16*   r2b  = (u16*)alloc(2u << 20);
    float* out1_32 = (float*)alloc(16u << 20);
    u16*   out1_bf = (u16*)alloc(8u << 20);
    float* out2_32 = (float*)alloc(16u << 20);
    u16*   out2_bf = (u16*)alloc(8u << 20);
    u16*   hb   = (u16*)alloc(32u << 20);
    u16*   bdt2 = (u16*)alloc(128u << 20);    // [b*16+h][1024][1024] bf16
    if (off > ws_size) return;

    dim3 tb(32, 32);

    // ---- phase 0: conversions / transposes / new_mem
    concat_mem<<<8192, 256, 0, stream>>>(mem, tgt, newmem, cat_bf);
    conv_f2b<<<4096, 256, 0, stream>>>(tgt, tgt_bf, 1048576);
    conv_f2b<<<4096, 256, 0, stream>>>(src, src_bf, 1048576);
    conv_f2b<<<2048, 256, 0, stream>>>(pos, pos_bf, 524288);
    transpose_w<<<dim3(32, 32), tb, 0, stream>>>(Wq1, Wq1t, 1024, 1024);
    transpose_w<<<dim3(32, 32), tb, 0, stream>>>(Wk1, Wk1t, 1024, 1024);
    transpose_w<<<dim3(32, 32), tb, 0, stream>>>(Wv1, Wv1t, 1024, 1024);
    transpose_w<<<dim3(32, 32), tb, 0, stream>>>(Wr1, Wr1t, 1024, 1024);
    transpose_w<<<dim3(32, 32), tb, 0, stream>>>(Wo1, Wo1t, 1024, 1024);
    transpose_w<<<dim3(32, 32), tb, 0, stream>>>(Wq2, Wq2t, 1024, 1024);
    transpose_w<<<dim3(32, 32), tb, 0, stream>>>(Wk2, Wk2t, 1024, 1024);
    transpose_w<<<dim3(32, 32), tb, 0, stream>>>(Wv2, Wv2t, 1024, 1024);
    transpose_w<<<dim3(32, 32), tb, 0, stream>>>(Wr2, Wr2t, 1024, 1024);
    transpose_w<<<dim3(32, 32), tb, 0, stream>>>(Wo2, Wo2t, 1024, 1024);
    transpose_w<<<dim3(128, 32), tb, 0, stream>>>(Wf1, Wf1t, 1024, 4096);
    transpose_w<<<dim3(32, 128), tb, 0, stream>>>(Wf2, Wf2t, 4096, 1024);

    // ---- layer 1: self relative attention (K=2048)
    gemm_bt<4,4,1,0,0><<<dim3(8,32,1), 256, 0, stream>>>(tgt_bf, Wq1t, qb, nullptr,
        4096,1024,1024, 1024,1024,1024, 0,0,0,0,0,0, 1);
    gemm_bt<4,4,1,0,0><<<dim3(8,64,1), 256, 0, stream>>>(cat_bf, Wk1t, kb, nullptr,
        8192,1024,1024, 1024,1024,1024, 0,0,0,0,0,0, 1);
    gemm_bt<4,4,1,0,0><<<dim3(8,64,1), 256, 0, stream>>>(cat_bf, Wv1t, vb, nullptr,
        8192,1024,1024, 1024,1024,1024, 0,0,0,0,0,0, 1);
    gemm_bt<4,4,1,0,0><<<dim3(8,16,1), 256, 0, stream>>>(pos_bf, Wr1t, r1b, nullptr,
        2048,1024,1024, 1024,1024,1024, 0,0,0,0,0,0, 1);
    add_qbias<<<4096, 256, 0, stream>>>(qb, rwb, rrb, qwb, qrb);
    // BD~ rel-shifted (pre-scaled) -> interP region (bf16 scratch, exact fit)
    gemm_bt<4,4,1,0,1><<<dim3(16,8,64), 256, 0, stream>>>(qrb, r1b, (void*)interP, nullptr,
        1024,2048,64, 1024,1024,2048,
        64LL,1048576LL, 64LL,0LL, 2097152LL,33554432LL, 16);
    transpose_v<<<dim3(64,2,64), tb, 0, stream>>>(vb, vtb, 2048);
    fattn<2048,0><<<dim3(64,64), 256, 0, stream>>>(qwb, kb, (const u16*)interP, vtb, selfP, ob);
    gemm_bt<4,4,0,0,0><<<dim3(8,32,1), 256, 0, stream>>>(ob, Wo1t, projb, nullptr,
        4096,1024,1024, 1024,1024,1024, 0,0,0,0,0,0, 1);
    ln_res<<<4096, 256, 0, stream>>>(tgt, projb, ln1g, ln1b, out1_32, out1_bf);

    // ---- layer 2: cross relative attention (K=1024, no mask)
    gemm_bt<4,4,1,0,0><<<dim3(8,32,1), 256, 0, stream>>>(out1_bf, Wq2t, qb, nullptr,
        4096,1024,1024, 1024,1024,1024, 0,0,0,0,0,0, 1);
    gemm_bt<4,4,1,0,0><<<dim3(8,32,1), 256, 0, stream>>>(src_bf, Wk2t, kb, nullptr,
        4096,1024,1024, 1024,1024,1024, 0,0,0,0,0,0, 1);
    gemm_bt<4,4,1,0,0><<<dim3(8,32,1), 256, 0, stream>>>(src_bf, Wv2t, vb, nullptr,
        4096,1024,1024, 1024,1024,1024, 0,0,0,0,0,0, 1);
    gemm_bt<4,4,1,0,0><<<dim3(8,8,1), 256, 0, stream>>>(pos_bf + 1048576, Wr2t, r2b, nullptr,
        1024,1024,1024, 1024,1024,1024, 0,0,0,0,0,0, 1);
    add_qbias<<<4096, 256, 0, stream>>>(qb, rwb, rrb, qwb, qrb);
    // BD~2 rel-shifted (dual-write, pre-scaled), batched over all (b,h)
    gemm_bt<4,4,1,0,2><<<dim3(8,8,64), 256, 0, stream>>>(qrb, r2b, bdt2, nullptr,
        1024,1024,64, 1024,1024,1024,
        64LL,1048576LL, 64LL,0LL, 1048576LL,16777216LL, 16);
    transpose_v<<<dim3(32,2,64), tb, 0, stream>>>(vb, vtb, 1024);
    fattn<1024,1><<<dim3(64,64), 256, 0, stream>>>(qwb, kb, bdt2, vtb, interP, ob);
    gemm_bt<4,4,0,0,0><<<dim3(8,32,1), 256, 0, stream>>>(ob, Wo2t, projb, nullptr,
        4096,1024,1024, 1024,1024,1024, 0,0,0,0,0,0, 1);
    ln_res<<<4096, 256, 0, stream>>>(out1_32, projb, ln2g, ln2b, out2_32, out2_bf);

    // ---- layer 3: FF
    gemm_bt<4,4,1,2,0><<<dim3(32,32,1), 256, 0, stream>>>(out2_bf, Wf1t, hb, bf1,
        4096,4096,1024, 1024,1024,4096, 0,0,0,0,0,0, 1);
    gemm_bt<4,4,0,1,0><<<dim3(8,32,1), 256, 0, stream>>>(hb, Wf2t, projb, bf2,
        4096,1024,4096, 4096,4096,1024, 0,0,0,0,0,0, 1);
    ln_res<<<4096, 256, 0, stream>>>(out2_32, projb, ln3g, ln3b, outp, nullptr);
}

// Round 5
// 1295.600 us; speedup vs baseline: 1.3664x; 1.0946x over previous
//
#include <hip/hip_runtime.h>

typedef unsigned short u16;
typedef __attribute__((ext_vector_type(8))) short short8;
typedef __attribute__((ext_vector_type(4))) float f4;
typedef __attribute__((ext_vector_type(4))) unsigned short u16x4;

__device__ __forceinline__ float b2f(u16 u) {
    unsigned int x = ((unsigned int)u) << 16;
    return __builtin_bit_cast(float, x);
}
__device__ __forceinline__ u16 f2b(float f) {
    unsigned int u = __builtin_bit_cast(unsigned int, f);
    u += 0x7FFFu + ((u >> 16) & 1u);   // round-to-nearest-even
    return (u16)(u >> 16);
}

__device__ __forceinline__ void gl16(const void* g, void* l) {
    __builtin_amdgcn_global_load_lds(
        (const __attribute__((address_space(1))) void*)g,
        (__attribute__((address_space(3))) void*)l, 16, 0, 0);
}

// ---------------------------------------------------------------------------
// bf16 MFMA GEMM, global_load_lds staging (m97 structure):
//   C[M,N] = A[M,K] @ Bt[N,K]^T  (+bias, +relu)
// Tile 128x128, BK=32, 4 waves (2x2). CBF: 0 f32-out, 1 bf16-out.
// EPI: 0 none, 1 +bias, 2 +bias+relu. Split-K by offsetting Ap/Bp and halving K.
// ---------------------------------------------------------------------------
template<int FM, int FN, int CBF, int EPI>
__global__ __launch_bounds__(256, 3)
void gemm_bt(const u16* __restrict__ Ap, const u16* __restrict__ Bp,
             void* __restrict__ Cp, const float* __restrict__ bias,
             int M, int N, int K, int lda, int ldb, int ldc,
             long long sAh, long long sAb, long long sBh, long long sBb,
             long long sCh, long long sCb, int batchH)
{
    constexpr int BM = FM * 32;
    constexpr int BN = FN * 32;
    __shared__ __align__(16) u16 As[BM * 32];
    __shared__ __align__(16) u16 Bs[BN * 32];

    const int tid  = threadIdx.x;
    const int z    = blockIdx.z;
    const int bb   = z / batchH;
    const int hh   = z - bb * batchH;
    const int m0   = blockIdx.y * BM;
    const int n0   = blockIdx.x * BN;
    const int w    = tid >> 6;
    const int lane = tid & 63;
    const int wr   = w >> 1;
    const int wc   = w & 1;
    const int lrow = lane & 15;
    const int lk   = (lane >> 4) << 3;
    const int lrow4 = lane >> 2;
    const int lch   = lane & 3;

    const u16* Ag = Ap + sAb * bb + sAh * hh;
    const u16* Bg = Bp + sBb * bb + sBh * hh;

    f4 acc[FM][FN] = {};

    const int nKt = K >> 5;
    for (int kt = 0; kt < nKt; ++kt) {
        const int kb = kt << 5;
        __syncthreads();
        #pragma unroll
        for (int i = 0; i < BM / 64; ++i) {
            const int row0 = (w + i * 4) << 4;
            gl16(Ag + (long long)(m0 + row0 + lrow4) * lda + kb + (lch << 3),
                 &As[row0 * 32]);
        }
        #pragma unroll
        for (int i = 0; i < BN / 64; ++i) {
            const int row0 = (w + i * 4) << 4;
            gl16(Bg + (long long)(n0 + row0 + lrow4) * ldb + kb + (lch << 3),
                 &Bs[row0 * 32]);
        }
        __syncthreads();

        short8 af[FM], bv[FN];
        #pragma unroll
        for (int m = 0; m < FM; ++m)
            af[m] = *(const short8*)(&As[(wr * FM * 16 + m * 16 + lrow) * 32 + lk]);
        #pragma unroll
        for (int n = 0; n < FN; ++n)
            bv[n] = *(const short8*)(&Bs[(wc * FN * 16 + n * 16 + lrow) * 32 + lk]);
        #pragma unroll
        for (int m = 0; m < FM; ++m)
            #pragma unroll
            for (int n = 0; n < FN; ++n)
                acc[m][n] = __builtin_amdgcn_mfma_f32_16x16x32_bf16(af[m], bv[n], acc[m][n], 0, 0, 0);
    }

    const int crow0 = m0 + wr * FM * 16 + ((lane >> 4) << 2);
    const int ccol0 = n0 + wc * FN * 16 + lrow;
    if (CBF == 0) {
        float* Cg = (float*)Cp + sCb * bb + sCh * hh;
        #pragma unroll
        for (int m = 0; m < FM; ++m) {
            #pragma unroll
            for (int n = 0; n < FN; ++n) {
                const int col = ccol0 + n * 16;
                float bvv = (EPI >= 1) ? bias[col] : 0.f;
                #pragma unroll
                for (int r = 0; r < 4; ++r) {
                    float vv = acc[m][n][r] + bvv;
                    if (EPI == 2) vv = fmaxf(vv, 0.f);
                    Cg[(long long)(crow0 + m * 16 + r) * ldc + col] = vv;
                }
            }
        }
    } else {
        u16* Cg = (u16*)Cp + sCb * bb + sCh * hh;
        #pragma unroll
        for (int m = 0; m < FM; ++m) {
            #pragma unroll
            for (int n = 0; n < FN; ++n) {
                const int col = ccol0 + n * 16;
                float bvv = (EPI >= 1) ? bias[col] : 0.f;
                #pragma unroll
                for (int r = 0; r < 4; ++r) {
                    float vv = acc[m][n][r] + bvv;
                    if (EPI == 2) vv = fmaxf(vv, 0.f);
                    Cg[(long long)(crow0 + m * 16 + r) * ldc + col] = f2b(vv);
                }
            }
        }
    }
}

// ---------------------------------------------------------------------------
// Fused attention v3: inline AC AND inline rel-shifted BD (no BD GEMM, no BD
// HBM traffic). 16 q-rows / 256 threads / 4 waves per block.
// A1: AC = qw·K^T via MFMA (K gathers from L2) -> e (bf16 LDS).
// A2: BD~ = qr·r^T via MFMA (r gathers from L2), rel-shift RMW add into e:
//     MODE 0 (self):  e[t][u+t-1023] += bd~[t][u]   (j>=0; j<=t+1024 auto)
//     MODE 1 (cross): e[t][u+t-1023] += bd~[t][u] (j>=0, covers j<=t)
//                     e[t][u+t+2]    += bd~[t+1][u] (j<KK, covers j>=t+2)
//                     (j==t+1: BD=0 -> untouched AC, matches reference)
// B: exp (no max-sub; scores pre-scaled by 0.125, O(few)), causal zeros for
//    self, unnormalized exp bf16 -> LDS, normalized f32 probs -> HBM.
// C: PV via MFMA from LDS exp + V^T gathers; final scale by 1/sum.
// ---------------------------------------------------------------------------
template<int KK, int MODE>
__global__ __launch_bounds__(256)
void fattn(const u16* __restrict__ qw, const u16* __restrict__ qr,
           const u16* __restrict__ kb, const u16* __restrict__ rr,
           const u16* __restrict__ vt,
           float* __restrict__ probs, u16* __restrict__ ob, int kld)
{
    constexpr int LE = KK + 8;
    __shared__ __align__(16) u16 e[16 * LE];
    __shared__ __align__(16) u16 qws[16 * 72];
    __shared__ __align__(16) u16 qrs[17 * 72];
    __shared__ float rinv[16];

    const int tid = threadIdx.x;
    const int bh  = blockIdx.y;
    const int b   = bh >> 4, h = bh & 15;
    const int t0  = blockIdx.x << 4;

    // stage qw rows t0..t0+15 and qr rows t0..t0+15 (+16 for cross wrap)
    {
        const int row = tid >> 3, ch = tid & 7;
        if (tid < 128) {
            *(short8*)&qws[row * 72 + ch * 8] =
                *(const short8*)(qw + ((long long)(b * 1024 + t0 + row)) * 1024 + h * 64 + ch * 8);
        } else {
            const int r2 = row - 16;
            *(short8*)&qrs[r2 * 72 + ch * 8] =
                *(const short8*)(qr + ((long long)(b * 1024 + t0 + r2)) * 1024 + h * 64 + ch * 8);
        }
        if (MODE == 1 && tid < 8) {
            const int trow = (t0 + 16 > 1023) ? 1023 : (t0 + 16);  // clamped; unused values predicated off
            *(short8*)&qrs[16 * 72 + tid * 8] =
                *(const short8*)(qr + ((long long)(b * 1024 + trow)) * 1024 + h * 64 + tid * 8);
        }
    }
    __syncthreads();

    const int w = tid >> 6, lane = tid & 63;
    const int lc = lane & 15, g = lane >> 4;
    const int lk = g << 3;
    constexpr int STRIP = KK / 4;
    const int c0 = w * STRIP;

    // ---- Phase A1: AC
    {
        const short8 aw0 = *(const short8*)&qws[lc * 72 + lk];
        const short8 aw1 = *(const short8*)&qws[lc * 72 + 32 + lk];
        const int jmaxv = t0 + 15 + 1024;
        for (int jt = 0; jt < STRIP / 32; ++jt) {
            const int jb = c0 + jt * 32;
            if (MODE == 0 && jb > jmaxv) break;
            #pragma unroll
            for (int s = 0; s < 2; ++s) {
                const int jcol = jb + s * 16 + lc;
                const u16* kg = kb + (long long)(b * KK + jcol) * kld + h * 64;
                short8 bv0 = *(const short8*)(kg + lk);
                short8 bv1 = *(const short8*)(kg + 32 + lk);
                f4 acc = {};
                acc = __builtin_amdgcn_mfma_f32_16x16x32_bf16(aw0, bv0, acc, 0, 0, 0);
                acc = __builtin_amdgcn_mfma_f32_16x16x32_bf16(aw1, bv1, acc, 0, 0, 0);
                #pragma unroll
                for (int r = 0; r < 4; ++r)
                    e[(g * 4 + r) * LE + jcol] = f2b(acc[r]);
            }
        }
    }
    __syncthreads();

    // ---- Phase A2: BD~ + shifted RMW add into e
    {
        const short8 ar0 = *(const short8*)&qrs[lc * 72 + lk];
        const short8 ar1 = *(const short8*)&qrs[lc * 72 + 32 + lk];
        short8 as0 = {}, as1 = {};
        if (MODE == 1) {
            as0 = *(const short8*)&qrs[(lc + 1) * 72 + lk];
            as1 = *(const short8*)&qrs[(lc + 1) * 72 + 32 + lk];
        }
        const u16* rbase = rr + h * 64;
        for (int jt = 0; jt < STRIP / 32; ++jt) {
            const int jb = c0 + jt * 32;
            const bool p1ok = (jb + 31 + t0 + 15) >= 1023;          // some j>=0 in tile
            const bool p2ok = (MODE == 1) && (jb + t0 + 2 <= 1023); // some j<KK in tile
            if (!p1ok && !p2ok) continue;
            #pragma unroll
            for (int s = 0; s < 2; ++s) {
                const int ucol = jb + s * 16 + lc;
                const u16* rg = rbase + (long long)ucol * 2048;
                short8 rv0 = *(const short8*)(rg + lk);
                short8 rv1 = *(const short8*)(rg + 32 + lk);
                if (p1ok) {
                    f4 a1 = {};
                    a1 = __builtin_amdgcn_mfma_f32_16x16x32_bf16(ar0, rv0, a1, 0, 0, 0);
                    a1 = __builtin_amdgcn_mfma_f32_16x16x32_bf16(ar1, rv1, a1, 0, 0, 0);
                    #pragma unroll
                    for (int r = 0; r < 4; ++r) {
                        const int tl = g * 4 + r;
                        const int j = ucol + t0 + tl - 1023;
                        if (j >= 0) {
                            const int idx = tl * LE + j;
                            e[idx] = f2b(b2f(e[idx]) + a1[r]);
                        }
                    }
                }
                if (p2ok) {
                    f4 a2 = {};
                    a2 = __builtin_amdgcn_mfma_f32_16x16x32_bf16(as0, rv0, a2, 0, 0, 0);
                    a2 = __builtin_amdgcn_mfma_f32_16x16x32_bf16(as1, rv1, a2, 0, 0, 0);
                    #pragma unroll
                    for (int r = 0; r < 4; ++r) {
                        const int tl = g * 4 + r;
                        const int j = ucol + t0 + tl + 2;
                        if (j < KK) {
                            const int idx = tl * LE + j;
                            e[idx] = f2b(b2f(e[idx]) + a2[r]);
                        }
                    }
                }
            }
        }
    }
    __syncthreads();

    // ---- Phase B: exp + row-sum + normalized probs write
    {
        const int r = tid >> 4, q = tid & 15;
        const int t = t0 + r;
        const int limit = t + 1024;
        float* pr = probs + ((long long)bh * 1024 + t) * KK;
        float sum = 0.f;
        for (int i = 0; i < KK / 128; ++i) {
            const int j0 = q * 8 + i * 128;
            short8 st;
            if (MODE == 0 && j0 > limit) {
                #pragma unroll
                for (int k2 = 0; k2 < 8; ++k2) st[k2] = 0;
                *(short8*)&e[r * LE + j0] = st;
                continue;
            }
            short8 a8 = *(const short8*)&e[r * LE + j0];
            #pragma unroll
            for (int k2 = 0; k2 < 8; ++k2) {
                float ev = __expf(b2f((u16)a8[k2]));
                if (MODE == 0 && j0 + k2 > limit) ev = 0.f;
                sum += ev;
                st[k2] = (short)f2b(ev);
            }
            *(short8*)&e[r * LE + j0] = st;
        }
        #pragma unroll
        for (int o = 1; o < 16; o <<= 1) sum += __shfl_xor(sum, o);
        const float inv = 1.f / sum;
        if (q == 0) rinv[r] = inv;
        for (int i = 0; i < KK / 128; ++i) {
            const int j0 = q * 8 + i * 128;
            short8 e8 = *(const short8*)&e[r * LE + j0];
            f4 p0, p1;
            p0.x = b2f((u16)e8[0]) * inv; p0.y = b2f((u16)e8[1]) * inv;
            p0.z = b2f((u16)e8[2]) * inv; p0.w = b2f((u16)e8[3]) * inv;
            p1.x = b2f((u16)e8[4]) * inv; p1.y = b2f((u16)e8[5]) * inv;
            p1.z = b2f((u16)e8[6]) * inv; p1.w = b2f((u16)e8[7]) * inv;
            *(f4*)(pr + j0) = p0;
            *(f4*)(pr + j0 + 4) = p1;
        }
    }
    __syncthreads();

    // ---- Phase C: PV (4 waves x 16 d-cols), causal k-bound for self
    const int db = w << 4;
    const u16* vrow = vt + ((long long)bh * 64 + db + lc) * KK + lk;
    const int kcend = (MODE == 0) ? ((t0 + 1040 + 31) >> 5) : (KK / 32);
    f4 acc = {};
    for (int kc = 0; kc < kcend; ++kc) {
        short8 a = *(const short8*)&e[lc * LE + kc * 32 + lk];
        short8 bvv = *(const short8*)(vrow + kc * 32);
        acc = __builtin_amdgcn_mfma_f32_16x16x32_bf16(a, bvv, acc, 0, 0, 0);
    }
    const int orow = g << 2;
    u16* obase = ob + ((long long)(b * 1024 + t0 + orow)) * 1024 + h * 64 + db + lc;
    #pragma unroll
    for (int rr2 = 0; rr2 < 4; ++rr2)
        obase[(long long)rr2 * 1024] = f2b(acc[rr2] * rinv[orow + rr2]);
}

// ---------------------------------------------------------------------------
// Elementwise / layout kernels
// ---------------------------------------------------------------------------
__global__ void conv_f2b(const float* __restrict__ in, u16* __restrict__ out, long long n4)
{
    long long i = (long long)blockIdx.x * 256 + threadIdx.x;
    if (i >= n4) return;
    f4 v = *(const f4*)(in + i * 4);
    u16x4 o; o.x = f2b(v.x); o.y = f2b(v.y); o.z = f2b(v.z); o.w = f2b(v.w);
    *(u16x4*)(out + i * 4) = o;
}

__global__ void concat_mem(const float* __restrict__ mem, const float* __restrict__ tgt,
                           float* __restrict__ nm, u16* __restrict__ cat)
{
    long long i = (long long)blockIdx.x * 256 + threadIdx.x;
    long long b = i >> 19;
    int rem = (int)(i & 524287);
    int r = rem >> 8, c4 = rem & 255;
    const float* sp = (r < 1024) ? (mem + ((b << 10) + r) * 1024 + c4 * 4)
                                 : (tgt + ((b << 10) + (r - 1024)) * 1024 + c4 * 4);
    f4 v = *(const f4*)sp;
    *(f4*)(nm + i * 4) = v;
    u16x4 o; o.x = f2b(v.x); o.y = f2b(v.y); o.z = f2b(v.z); o.w = f2b(v.w);
    *(u16x4*)(cat + i * 4) = o;
}

__global__ void transpose_w(const float* __restrict__ W, u16* __restrict__ Wt, int R, int C)
{
    __shared__ float tile[32][33];
    int c0 = blockIdx.x * 32, r0 = blockIdx.y * 32;
    int tx = threadIdx.x, ty = threadIdx.y;
    tile[ty][tx] = W[(long long)(r0 + ty) * C + c0 + tx];
    __syncthreads();
    Wt[(long long)(c0 + ty) * R + r0 + tx] = f2b(tile[tx][ty]);
}

// v rows from P-buffer: v(b,j,d) = src[(b*KK + j)*ld + coff + h*64 + d]
__global__ void transpose_v(const u16* __restrict__ v, u16* __restrict__ vt,
                            int KK, int ld, int coff)
{
    __shared__ u16 tile[32][33];
    int z = blockIdx.z; int b = z >> 4, hh = z & 15;
    int j0 = blockIdx.x * 32, d0 = blockIdx.y * 32;
    int tx = threadIdx.x, ty = threadIdx.y;
    tile[ty][tx] = v[((long long)(b * KK + j0 + ty)) * ld + coff + hh * 64 + d0 + tx];
    __syncthreads();
    vt[((long long)((b * 16 + hh) * 64 + d0 + ty)) * KK + j0 + tx] = tile[tx][ty];
}

// qw = (q + r_w_bias)*0.125, qr = (q + r_r_bias)*0.125 ; q read strided from src
__global__ void add_qbias(const u16* __restrict__ src, long long ld, long long sb,
                          const float* __restrict__ rwb, const float* __restrict__ rrb,
                          u16* __restrict__ qwo, u16* __restrict__ qro)
{
    long long i = (long long)blockIdx.x * 256 + threadIdx.x;   // 4-elem groups, 1M total
    const int col = (int)((i * 4) & 1023);
    const long long trow = (i * 4) >> 10;
    const long long b = trow >> 10;
    const long long tr = trow & 1023;
    u16x4 qq = *(const u16x4*)(src + b * sb + tr * ld + col);
    f4 wv = *(const f4*)(rwb + col);
    f4 rv = *(const f4*)(rrb + col);
    u16x4 a, c;
    a.x = f2b((b2f(qq.x) + wv.x) * 0.125f); a.y = f2b((b2f(qq.y) + wv.y) * 0.125f);
    a.z = f2b((b2f(qq.z) + wv.z) * 0.125f); a.w = f2b((b2f(qq.w) + wv.w) * 0.125f);
    c.x = f2b((b2f(qq.x) + rv.x) * 0.125f); c.y = f2b((b2f(qq.y) + rv.y) * 0.125f);
    c.z = f2b((b2f(qq.z) + rv.z) * 0.125f); c.w = f2b((b2f(qq.w) + rv.w) * 0.125f);
    *(u16x4*)(qwo + i * 4) = a;
    *(u16x4*)(qro + i * 4) = c;
}

// out = LN(x + h1 + h2) * g + bl ; optional bf16 copy.
__global__ __launch_bounds__(256) void ln_res(const float* __restrict__ x,
                                              const float* __restrict__ h1,
                                              const float* __restrict__ h2,
                                              const float* __restrict__ g, const float* __restrict__ bl,
                                              float* __restrict__ o32, u16* __restrict__ obf)
{
    const long long row = blockIdx.x;
    const int tid = threadIdx.x;
    const long long base = row * 1024 + tid * 4;
    f4 xa = *(const f4*)(x + base);
    f4 ha = *(const f4*)(h1 + base);
    f4 hb = *(const f4*)(h2 + base);
    float v0 = xa.x + ha.x + hb.x, v1 = xa.y + ha.y + hb.y;
    float v2 = xa.z + ha.z + hb.z, v3 = xa.w + ha.w + hb.w;
    float lsum = v0 + v1 + v2 + v3;
    float lsq = v0 * v0 + v1 * v1 + v2 * v2 + v3 * v3;
    #pragma unroll
    for (int o2 = 32; o2; o2 >>= 1) { lsum += __shfl_xor(lsum, o2); lsq += __shfl_xor(lsq, o2); }
    __shared__ float r1[4], r2[4];
    int w = tid >> 6, lane = tid & 63;
    if (lane == 0) { r1[w] = lsum; r2[w] = lsq; }
    __syncthreads();
    lsum = r1[0] + r1[1] + r1[2] + r1[3];
    lsq  = r2[0] + r2[1] + r2[2] + r2[3];
    const float mu = lsum * 0.0009765625f;
    const float var = lsq * 0.0009765625f - mu * mu;
    const float rsd = rsqrtf(var + 1e-5f);
    const int c = tid * 4;
    f4 gv = *(const f4*)(g + c);
    f4 bv = *(const f4*)(bl + c);
    f4 y;
    y.x = (v0 - mu) * rsd * gv.x + bv.x;
    y.y = (v1 - mu) * rsd * gv.y + bv.y;
    y.z = (v2 - mu) * rsd * gv.z + bv.z;
    y.w = (v3 - mu) * rsd * gv.w + bv.w;
    *(f4*)(o32 + base) = y;
    if (obf) {
        u16x4 u; u.x = f2b(y.x); u.y = f2b(y.y); u.z = f2b(y.z); u.w = f2b(y.w);
        *(u16x4*)(obf + base) = u;
    }
}

// ---------------------------------------------------------------------------
extern "C" void kernel_launch(void* const* d_in, const int* in_sizes, int n_in,
                              void* d_out, int out_size, void* d_ws, size_t ws_size,
                              hipStream_t stream)
{
    (void)in_sizes; (void)n_in; (void)out_size;
    const float* src  = (const float*)d_in[0];
    const float* tgt  = (const float*)d_in[1];
    const float* mem  = (const float*)d_in[2];
    const float* pos  = (const float*)d_in[3];
    const float* rwb  = (const float*)d_in[4];
    const float* rrb  = (const float*)d_in[5];
    const float* Wq1  = (const float*)d_in[6];
    const float* Wk1  = (const float*)d_in[7];
    const float* Wv1  = (const float*)d_in[8];
    const float* Wr1  = (const float*)d_in[9];
    const float* Wo1  = (const float*)d_in[10];
    const float* ln1g = (const float*)d_in[11];
    const float* ln1b = (const float*)d_in[12];
    const float* Wq2  = (const float*)d_in[13];
    const float* Wk2  = (const float*)d_in[14];
    const float* Wv2  = (const float*)d_in[15];
    const float* Wr2  = (const float*)d_in[16];
    const float* Wo2  = (const float*)d_in[17];
    const float* ln2g = (const float*)d_in[18];
    const float* ln2b = (const float*)d_in[19];
    const float* Wf1  = (const float*)d_in[20];
    const float* bf1  = (const float*)d_in[21];
    const float* Wf2  = (const float*)d_in[22];
    const float* bf2  = (const float*)d_in[23];
    const float* ln3g = (const float*)d_in[24];
    const float* ln3b = (const float*)d_in[25];

    float* outp   = (float*)d_out;            // [4,1024,1024]
    float* newmem = outp + 4194304;           // [4,2048,1024]
    float* selfP  = outp + 12582912;          // [4,16,1024,2048]
    float* interP = outp + 146800640;         // [4,16,1024,1024]

    char* ws = (char*)d_ws;
    size_t off = 0;
    auto alloc = [&](size_t bytes) -> void* {
        void* p = ws + off;
        off = (off + bytes + 255) & ~(size_t)255;
        return p;
    };
    u16*   src_bf  = (u16*)alloc(8u << 20);       // [4096][1024]
    u16*   cat_bf  = (u16*)alloc(16u << 20);      // [8192][1024]
    u16*   pos_bf  = (u16*)alloc(4u << 20);       // [2048][1024]
    u16*   W1t    = (u16*)alloc(6u << 20);        // [3072][1024]  Wq1|Wk1|Wv1 ^T
    u16*   Wr12t  = (u16*)alloc(4u << 20);        // [2048][1024]  Wr1|Wr2 ^T
    u16*   W2t    = (u16*)alloc(4u << 20);        // [2048][1024]  Wk2|Wv2 ^T
    u16*   Wq2t   = (u16*)alloc(2u << 20);
    u16*   Wo1t   = (u16*)alloc(2u << 20);
    u16*   Wo2t   = (u16*)alloc(2u << 20);
    u16*   Wf1t   = (u16*)alloc(8u << 20);
    u16*   Wf2t   = (u16*)alloc(8u << 20);
    u16*   P1     = (u16*)alloc(48u << 20);       // [8192][3072]  Q|K|V self
    u16*   P2     = (u16*)alloc(16u << 20);       // [4096][2048]  K|V cross
    u16*   R12    = (u16*)alloc(8u << 20);        // [2048][2048]  r1 | r2
    u16*   qwb    = (u16*)alloc(8u << 20);        // [4096][1024]
    u16*   qrb    = (u16*)alloc(8u << 20);
    u16*   qb2    = (u16*)alloc(8u << 20);
    u16*   vtb    = (u16*)alloc(16u << 20);       // V^T (reused both layers)
    u16*   ob     = (u16*)alloc(8u << 20);
    float* projb  = (float*)alloc(16u << 20);
    float* projb2 = (float*)alloc(16u << 20);
    float* out1_32 = (float*)alloc(16u << 20);
    u16*   out1_bf = (u16*)alloc(8u << 20);
    float* out2_32 = (float*)alloc(16u << 20);
    u16*   out2_bf = (u16*)alloc(8u << 20);
    u16*   hb     = (u16*)alloc(32u << 20);       // [4096][4096]
    if (off > ws_size) return;

    dim3 tb(32, 32);

    // ---- phase 0: conversions / transposes / new_mem
    concat_mem<<<8192, 256, 0, stream>>>(mem, tgt, newmem, cat_bf);
    conv_f2b<<<4096, 256, 0, stream>>>(src, src_bf, 1048576);
    conv_f2b<<<2048, 256, 0, stream>>>(pos, pos_bf, 524288);
    transpose_w<<<dim3(32, 32), tb, 0, stream>>>(Wq1, W1t, 1024, 1024);
    transpose_w<<<dim3(32, 32), tb, 0, stream>>>(Wk1, W1t + 1048576, 1024, 1024);
    transpose_w<<<dim3(32, 32), tb, 0, stream>>>(Wv1, W1t + 2097152, 1024, 1024);
    transpose_w<<<dim3(32, 32), tb, 0, stream>>>(Wr1, Wr12t, 1024, 1024);
    transpose_w<<<dim3(32, 32), tb, 0, stream>>>(Wr2, Wr12t + 1048576, 1024, 1024);
    transpose_w<<<dim3(32, 32), tb, 0, stream>>>(Wk2, W2t, 1024, 1024);
    transpose_w<<<dim3(32, 32), tb, 0, stream>>>(Wv2, W2t + 1048576, 1024, 1024);
    transpose_w<<<dim3(32, 32), tb, 0, stream>>>(Wq2, Wq2t, 1024, 1024);
    transpose_w<<<dim3(32, 32), tb, 0, stream>>>(Wo1, Wo1t, 1024, 1024);
    transpose_w<<<dim3(32, 32), tb, 0, stream>>>(Wo2, Wo2t, 1024, 1024);
    transpose_w<<<dim3(128, 32), tb, 0, stream>>>(Wf1, Wf1t, 1024, 4096);
    transpose_w<<<dim3(32, 128), tb, 0, stream>>>(Wf2, Wf2t, 4096, 1024);

    // ---- layer 1: self relative attention (K=2048)
    // P1 = cat @ [Wq1|Wk1|Wv1]  (Q part valid only for tgt rows; harmless extra)
    gemm_bt<4,4,1,0><<<dim3(24,64,1), 256, 0, stream>>>(cat_bf, W1t, P1, nullptr,
        8192,3072,1024, 1024,1024,3072, 0,0,0,0,0,0, 1);
    // R12 = pos @ [Wr1|Wr2]
    gemm_bt<4,4,1,0><<<dim3(16,16,1), 256, 0, stream>>>(pos_bf, Wr12t, R12, nullptr,
        2048,2048,1024, 1024,1024,2048, 0,0,0,0,0,0, 1);
    // Q rows live at P1[(b*2048+1024+t)][0:1024]
    add_qbias<<<4096, 256, 0, stream>>>(P1 + 1024LL * 3072, 3072LL, 2048LL * 3072,
                                        rwb, rrb, qwb, qrb);
    transpose_v<<<dim3(64,2,64), tb, 0, stream>>>(P1, vtb, 2048, 3072, 2048);
    fattn<2048,0><<<dim3(64,64), 256, 0, stream>>>(qwb, qrb, P1 + 1024, R12, vtb,
                                                   selfP, ob, 3072);
    // Wo1 (split-K x2)
    gemm_bt<4,4,0,0><<<dim3(8,32,1), 256, 0, stream>>>(ob, Wo1t, projb, nullptr,
        4096,1024,512, 1024,1024,1024, 0,0,0,0,0,0, 1);
    gemm_bt<4,4,0,0><<<dim3(8,32,1), 256, 0, stream>>>(ob + 512, Wo1t + 512, projb2, nullptr,
        4096,1024,512, 1024,1024,1024, 0,0,0,0,0,0, 1);
    ln_res<<<4096, 256, 0, stream>>>(tgt, projb, projb2, ln1g, ln1b, out1_32, out1_bf);

    // ---- layer 2: cross relative attention (K=1024)
    gemm_bt<4,4,1,0><<<dim3(8,32,1), 256, 0, stream>>>(out1_bf, Wq2t, qb2, nullptr,
        4096,1024,1024, 1024,1024,1024, 0,0,0,0,0,0, 1);
    gemm_bt<4,4,1,0><<<dim3(16,32,1), 256, 0, stream>>>(src_bf, W2t, P2, nullptr,
        4096,2048,1024, 1024,1024,2048, 0,0,0,0,0,0, 1);
    add_qbias<<<4096, 256, 0, stream>>>(qb2, 1024LL, 1048576LL, rwb, rrb, qwb, qrb);
    transpose_v<<<dim3(32,2,64), tb, 0, stream>>>(P2, vtb, 1024, 2048, 1024);
    fattn<1024,1><<<dim3(64,64), 256, 0, stream>>>(qwb, qrb, P2,
        R12 + 1024LL * 2048 + 1024, vtb, interP, ob, 2048);
    gemm_bt<4,4,0,0><<<dim3(8,32,1), 256, 0, stream>>>(ob, Wo2t, projb, nullptr,
        4096,1024,512, 1024,1024,1024, 0,0,0,0,0,0, 1);
    gemm_bt<4,4,0,0><<<dim3(8,32,1), 256, 0, stream>>>(ob + 512, Wo2t + 512, projb2, nullptr,
        4096,1024,512, 1024,1024,1024, 0,0,0,0,0,0, 1);
    ln_res<<<4096, 256, 0, stream>>>(out1_32, projb, projb2, ln2g, ln2b, out2_32, out2_bf);

    // ---- layer 3: FF
    gemm_bt<4,4,1,2><<<dim3(32,32,1), 256, 0, stream>>>(out2_bf, Wf1t, hb, bf1,
        4096,4096,1024, 1024,1024,4096, 0,0,0,0,0,0, 1);
    // FF2 (split-K x2; bias on first half)
    gemm_bt<4,4,0,1><<<dim3(8,32,1), 256, 0, stream>>>(hb, Wf2t, projb, bf2,
        4096,1024,2048, 4096,4096,1024, 0,0,0,0,0,0, 1);
    gemm_bt<4,4,0,0><<<dim3(8,32,1), 256, 0, stream>>>(hb + 2048, Wf2t + 2048, projb2, nullptr,
        4096,1024,2048, 4096,4096,1024, 0,0,0,0,0,0, 1);
    ln_res<<<4096, 256, 0, stream>>>(out2_32, projb, projb2, ln3g, ln3b, outp, nullptr);
}

// Round 6
// 1165.292 us; speedup vs baseline: 1.5192x; 1.1118x over previous
//
#include <hip/hip_runtime.h>

typedef unsigned short u16;
typedef __attribute__((ext_vector_type(8))) short short8;
typedef __attribute__((ext_vector_type(4))) float f4;
typedef __attribute__((ext_vector_type(4))) unsigned short u16x4;

__device__ __forceinline__ float b2f(u16 u) {
    unsigned int x = ((unsigned int)u) << 16;
    return __builtin_bit_cast(float, x);
}
__device__ __forceinline__ u16 f2b(float f) {
    unsigned int u = __builtin_bit_cast(unsigned int, f);
    u += 0x7FFFu + ((u >> 16) & 1u);   // round-to-nearest-even
    return (u16)(u >> 16);
}

__device__ __forceinline__ void gl16(const void* g, void* l) {
    __builtin_amdgcn_global_load_lds(
        (const __attribute__((address_space(1))) void*)g,
        (__attribute__((address_space(3))) void*)l, 16, 0, 0);
}

// ---------------------------------------------------------------------------
// bf16 MFMA GEMM, global_load_lds staging (m97 structure):
//   C[M,N] = A[M,K] @ Bt[N,K]^T  (+bias, +relu)
// Tile 128x128, BK=32, 4 waves (2x2). CBF: 0 f32-out, 1 bf16-out.
// EPI: 0 none, 1 +bias, 2 +bias+relu. Split-K by offsetting Ap/Bp and halving K.
// ---------------------------------------------------------------------------
template<int FM, int FN, int CBF, int EPI>
__global__ __launch_bounds__(256, 3)
void gemm_bt(const u16* __restrict__ Ap, const u16* __restrict__ Bp,
             void* __restrict__ Cp, const float* __restrict__ bias,
             int M, int N, int K, int lda, int ldb, int ldc,
             long long sAh, long long sAb, long long sBh, long long sBb,
             long long sCh, long long sCb, int batchH)
{
    constexpr int BM = FM * 32;
    constexpr int BN = FN * 32;
    __shared__ __align__(16) u16 As[BM * 32];
    __shared__ __align__(16) u16 Bs[BN * 32];

    const int tid  = threadIdx.x;
    const int z    = blockIdx.z;
    const int bb   = z / batchH;
    const int hh   = z - bb * batchH;
    const int m0   = blockIdx.y * BM;
    const int n0   = blockIdx.x * BN;
    const int w    = tid >> 6;
    const int lane = tid & 63;
    const int wr   = w >> 1;
    const int wc   = w & 1;
    const int lrow = lane & 15;
    const int lk   = (lane >> 4) << 3;
    const int lrow4 = lane >> 2;
    const int lch   = lane & 3;

    const u16* Ag = Ap + sAb * bb + sAh * hh;
    const u16* Bg = Bp + sBb * bb + sBh * hh;

    f4 acc[FM][FN] = {};

    const int nKt = K >> 5;
    for (int kt = 0; kt < nKt; ++kt) {
        const int kb = kt << 5;
        __syncthreads();
        #pragma unroll
        for (int i = 0; i < BM / 64; ++i) {
            const int row0 = (w + i * 4) << 4;
            gl16(Ag + (long long)(m0 + row0 + lrow4) * lda + kb + (lch << 3),
                 &As[row0 * 32]);
        }
        #pragma unroll
        for (int i = 0; i < BN / 64; ++i) {
            const int row0 = (w + i * 4) << 4;
            gl16(Bg + (long long)(n0 + row0 + lrow4) * ldb + kb + (lch << 3),
                 &Bs[row0 * 32]);
        }
        __syncthreads();

        short8 af[FM], bv[FN];
        #pragma unroll
        for (int m = 0; m < FM; ++m)
            af[m] = *(const short8*)(&As[(wr * FM * 16 + m * 16 + lrow) * 32 + lk]);
        #pragma unroll
        for (int n = 0; n < FN; ++n)
            bv[n] = *(const short8*)(&Bs[(wc * FN * 16 + n * 16 + lrow) * 32 + lk]);
        #pragma unroll
        for (int m = 0; m < FM; ++m)
            #pragma unroll
            for (int n = 0; n < FN; ++n)
                acc[m][n] = __builtin_amdgcn_mfma_f32_16x16x32_bf16(af[m], bv[n], acc[m][n], 0, 0, 0);
    }

    const int crow0 = m0 + wr * FM * 16 + ((lane >> 4) << 2);
    const int ccol0 = n0 + wc * FN * 16 + lrow;
    if (CBF == 0) {
        float* Cg = (float*)Cp + sCb * bb + sCh * hh;
        #pragma unroll
        for (int m = 0; m < FM; ++m) {
            #pragma unroll
            for (int n = 0; n < FN; ++n) {
                const int col = ccol0 + n * 16;
                float bvv = (EPI >= 1) ? bias[col] : 0.f;
                #pragma unroll
                for (int r = 0; r < 4; ++r) {
                    float vv = acc[m][n][r] + bvv;
                    if (EPI == 2) vv = fmaxf(vv, 0.f);
                    Cg[(long long)(crow0 + m * 16 + r) * ldc + col] = vv;
                }
            }
        }
    } else {
        u16* Cg = (u16*)Cp + sCb * bb + sCh * hh;
        #pragma unroll
        for (int m = 0; m < FM; ++m) {
            #pragma unroll
            for (int n = 0; n < FN; ++n) {
                const int col = ccol0 + n * 16;
                float bvv = (EPI >= 1) ? bias[col] : 0.f;
                #pragma unroll
                for (int r = 0; r < 4; ++r) {
                    float vv = acc[m][n][r] + bvv;
                    if (EPI == 2) vv = fmaxf(vv, 0.f);
                    Cg[(long long)(crow0 + m * 16 + r) * ldc + col] = f2b(vv);
                }
            }
        }
    }
}

// ---------------------------------------------------------------------------
// Fused attention v4 (swapped-operand): 16 q-rows, 512 threads (8 waves).
// Swapped MFMA mfma(K_frag, Q_frag) -> lane holds 4 consecutive j for one
// q-row t = lane&15. Phases:
//  A0: BD~ = mfma(r, qr) written PRE-SHIFTED into e (write-only scalar u16;
//      no RMW, no zero-init needed).
//  A1: AC = mfma(K, qw); read 4 BD (8B), add, exp in-register, row-sum
//      partial in register, store exp bf16 (8B). shfl_xor(16,32) -> psum.
//  B/C in parallel after barrier: waves 4-7 write normalized f32 probs;
//      waves 0-3 do PV MFMA (+1/sum scale at end).
// Scores pre-scaled by 0.125 (folded into qw/qr).
// MODE 0: self causal (limit=t+1024), KK=2048. MODE 1: cross, KK=1024.
// ---------------------------------------------------------------------------
template<int KK, int MODE>
__global__ __launch_bounds__(512)
void fattn(const u16* __restrict__ qw, const u16* __restrict__ qr,
           const u16* __restrict__ kb, const u16* __restrict__ rr,
           const u16* __restrict__ vt,
           float* __restrict__ probs, u16* __restrict__ ob, int kld)
{
    constexpr int LE = KK + 8;
    __shared__ __align__(16) u16 e[16 * LE];
    __shared__ __align__(16) u16 qws[16 * 72];
    __shared__ __align__(16) u16 qrs[17 * 72];
    __shared__ float psum[8][16];

    const int tid = threadIdx.x;
    const int bh  = blockIdx.y;
    const int b   = bh >> 4, h = bh & 15;
    const int t0  = blockIdx.x << 4;

    if (tid < 128) {
        const int row = tid >> 3, ch = tid & 7;
        *(short8*)&qws[row * 72 + ch * 8] =
            *(const short8*)(qw + ((long long)(b * 1024 + t0 + row)) * 1024 + h * 64 + ch * 8);
    } else if (tid < 256) {
        const int row = (tid - 128) >> 3, ch = tid & 7;
        *(short8*)&qrs[row * 72 + ch * 8] =
            *(const short8*)(qr + ((long long)(b * 1024 + t0 + row)) * 1024 + h * 64 + ch * 8);
    } else if (MODE == 1 && tid < 264) {
        const int ch = tid - 256;
        const int trow = (t0 + 16 > 1023) ? 1023 : (t0 + 16);  // clamped; predicated off
        *(short8*)&qrs[16 * 72 + ch * 8] =
            *(const short8*)(qr + ((long long)(b * 1024 + trow)) * 1024 + h * 64 + ch * 8);
    }
    __syncthreads();

    const int w = tid >> 6, lane = tid & 63;
    const int lc = lane & 15, g = lane >> 4, lk = g << 3;
    constexpr int STRIP = KK / 8;
    const int c0 = w * STRIP;
    const int t = t0 + lc;

    const short8 bq0 = *(const short8*)&qws[lc * 72 + lk];
    const short8 bq1 = *(const short8*)&qws[lc * 72 + 32 + lk];
    const short8 br0 = *(const short8*)&qrs[lc * 72 + lk];
    const short8 br1 = *(const short8*)&qrs[lc * 72 + 32 + lk];
    short8 bs0 = {}, bs1 = {};
    if (MODE == 1) {
        bs0 = *(const short8*)&qrs[(lc + 1) * 72 + lk];
        bs1 = *(const short8*)&qrs[(lc + 1) * 72 + 32 + lk];
    }

    // ---- A0: BD~ pre-shifted write-only
    #pragma unroll 2
    for (int ut = 0; ut < STRIP / 16; ++ut) {
        const int u0 = c0 + ut * 16;
        const bool need1 = (u0 + t0 + 30 >= 1023);
        const bool need2 = (MODE == 1) && (u0 + t0 <= 1021);
        if (!need1 && !need2) continue;
        const u16* rg = rr + (long long)(u0 + lc) * 2048 + h * 64;
        const short8 a0 = *(const short8*)(rg + lk);
        const short8 a1 = *(const short8*)(rg + 32 + lk);
        if (need1) {
            f4 acc = {};
            acc = __builtin_amdgcn_mfma_f32_16x16x32_bf16(a0, br0, acc, 0, 0, 0);
            acc = __builtin_amdgcn_mfma_f32_16x16x32_bf16(a1, br1, acc, 0, 0, 0);
            #pragma unroll
            for (int i = 0; i < 4; ++i) {
                const int j = u0 + 4 * g + i + t - 1023;
                if (j >= 0) e[lc * LE + j] = f2b(acc[i]);
            }
        }
        if (MODE == 1 && need2) {
            f4 acc = {};
            acc = __builtin_amdgcn_mfma_f32_16x16x32_bf16(a0, bs0, acc, 0, 0, 0);
            acc = __builtin_amdgcn_mfma_f32_16x16x32_bf16(a1, bs1, acc, 0, 0, 0);
            #pragma unroll
            for (int i = 0; i < 4; ++i) {
                const int j = u0 + 4 * g + i + t + 2;
                if (j < KK) e[lc * LE + j] = f2b(acc[i]);
            }
        }
    }
    __syncthreads();

    // ---- A1: AC + BD-add + exp + row-sum
    float sum = 0.f;
    const int limit = t + 1024;
    #pragma unroll 2
    for (int jt = 0; jt < STRIP / 16; ++jt) {
        const int j0 = c0 + jt * 16;
        const int jme = j0 + 4 * g;
        if (MODE == 0 && j0 > t0 + 1039) {       // fully masked tile: zero-fill
            u16x4 z = {0, 0, 0, 0};
            *(u16x4*)&e[lc * LE + jme] = z;
            continue;
        }
        const u16* kg = kb + (long long)(b * KK + j0 + lc) * kld + h * 64;
        const short8 a0 = *(const short8*)(kg + lk);
        const short8 a1 = *(const short8*)(kg + 32 + lk);
        f4 acc = {};
        acc = __builtin_amdgcn_mfma_f32_16x16x32_bf16(a0, bq0, acc, 0, 0, 0);
        acc = __builtin_amdgcn_mfma_f32_16x16x32_bf16(a1, bq1, acc, 0, 0, 0);
        u16x4 bd4 = *(const u16x4*)&e[lc * LE + jme];
        u16x4 st;
        #pragma unroll
        for (int i = 0; i < 4; ++i) {
            const int j = jme + i;
            float bd = b2f(bd4[i]);
            if (MODE == 1 && j == t + 1) bd = 0.f;
            float ev = __expf(acc[i] + bd);
            if (MODE == 0 && j > limit) ev = 0.f;
            sum += ev;
            st[i] = f2b(ev);
        }
        *(u16x4*)&e[lc * LE + jme] = st;
    }
    sum += __shfl_xor(sum, 16);
    sum += __shfl_xor(sum, 32);
    if (g == 0) psum[w][lc] = sum;
    __syncthreads();

    if (w >= 4) {
        // ---- B: normalized f32 probs write (waves 4-7)
        const int r = (tid >> 4) & 15;
        const int q = tid & 15;
        float s = 0.f;
        #pragma unroll
        for (int w2 = 0; w2 < 8; ++w2) s += psum[w2][r];
        const float inv = 1.f / s;
        float* pr = probs + ((long long)bh * 1024 + t0 + r) * KK;
        #pragma unroll 4
        for (int i2 = 0; i2 < KK / 128; ++i2) {
            const int j0 = q * 8 + i2 * 128;
            u16x4 e0 = *(const u16x4*)&e[r * LE + j0];
            u16x4 e1 = *(const u16x4*)&e[r * LE + j0 + 4];
            f4 p0, p1;
            p0.x = b2f(e0.x) * inv; p0.y = b2f(e0.y) * inv;
            p0.z = b2f(e0.z) * inv; p0.w = b2f(e0.w) * inv;
            p1.x = b2f(e1.x) * inv; p1.y = b2f(e1.y) * inv;
            p1.z = b2f(e1.z) * inv; p1.w = b2f(e1.w) * inv;
            *(f4*)(pr + j0) = p0;
            *(f4*)(pr + j0 + 4) = p1;
        }
    } else {
        // ---- C: PV (waves 0-3, 16 d-cols each)
        const int db = w << 4;
        const u16* vrow = vt + ((long long)(bh * 64 + db + lc)) * KK + lk;
        int kcend = KK / 32;
        if (MODE == 0) {
            const int ke = (t0 + 1071) >> 5;
            if (ke < kcend) kcend = ke;
        }
        f4 acc = {};
        #pragma unroll 2
        for (int kc = 0; kc < kcend; ++kc) {
            short8 a = *(const short8*)&e[lc * LE + kc * 32 + lk];
            short8 bv = *(const short8*)(vrow + kc * 32);
            acc = __builtin_amdgcn_mfma_f32_16x16x32_bf16(a, bv, acc, 0, 0, 0);
        }
        #pragma unroll
        for (int i = 0; i < 4; ++i) {
            const int trow = g * 4 + i;
            float s = 0.f;
            #pragma unroll
            for (int w2 = 0; w2 < 8; ++w2) s += psum[w2][trow];
            ob[((long long)(b * 1024 + t0 + trow)) * 1024 + h * 64 + db + lc] = f2b(acc[i] / s);
        }
    }
}

// ---------------------------------------------------------------------------
// Elementwise / layout kernels
// ---------------------------------------------------------------------------
__global__ void conv_f2b(const float* __restrict__ in, u16* __restrict__ out, long long n4)
{
    long long i = (long long)blockIdx.x * 256 + threadIdx.x;
    if (i >= n4) return;
    f4 v = *(const f4*)(in + i * 4);
    u16x4 o; o.x = f2b(v.x); o.y = f2b(v.y); o.z = f2b(v.z); o.w = f2b(v.w);
    *(u16x4*)(out + i * 4) = o;
}

__global__ void concat_mem(const float* __restrict__ mem, const float* __restrict__ tgt,
                           float* __restrict__ nm, u16* __restrict__ cat)
{
    long long i = (long long)blockIdx.x * 256 + threadIdx.x;
    long long b = i >> 19;
    int rem = (int)(i & 524287);
    int r = rem >> 8, c4 = rem & 255;
    const float* sp = (r < 1024) ? (mem + ((b << 10) + r) * 1024 + c4 * 4)
                                 : (tgt + ((b << 10) + (r - 1024)) * 1024 + c4 * 4);
    f4 v = *(const f4*)sp;
    *(f4*)(nm + i * 4) = v;
    u16x4 o; o.x = f2b(v.x); o.y = f2b(v.y); o.z = f2b(v.z); o.w = f2b(v.w);
    *(u16x4*)(cat + i * 4) = o;
}

__global__ void transpose_w(const float* __restrict__ W, u16* __restrict__ Wt, int R, int C)
{
    __shared__ float tile[32][33];
    int c0 = blockIdx.x * 32, r0 = blockIdx.y * 32;
    int tx = threadIdx.x, ty = threadIdx.y;
    tile[ty][tx] = W[(long long)(r0 + ty) * C + c0 + tx];
    __syncthreads();
    Wt[(long long)(c0 + ty) * R + r0 + tx] = f2b(tile[tx][ty]);
}

// v rows from P-buffer: v(b,j,d) = src[(b*KK + j)*ld + coff + h*64 + d]
__global__ void transpose_v(const u16* __restrict__ v, u16* __restrict__ vt,
                            int KK, int ld, int coff)
{
    __shared__ u16 tile[32][33];
    int z = blockIdx.z; int b = z >> 4, hh = z & 15;
    int j0 = blockIdx.x * 32, d0 = blockIdx.y * 32;
    int tx = threadIdx.x, ty = threadIdx.y;
    tile[ty][tx] = v[((long long)(b * KK + j0 + ty)) * ld + coff + hh * 64 + d0 + tx];
    __syncthreads();
    vt[((long long)((b * 16 + hh) * 64 + d0 + ty)) * KK + j0 + tx] = tile[tx][ty];
}

// qw = (q + r_w_bias)*0.125, qr = (q + r_r_bias)*0.125 ; q read strided from src
__global__ void add_qbias(const u16* __restrict__ src, long long ld, long long sb,
                          const float* __restrict__ rwb, const float* __restrict__ rrb,
                          u16* __restrict__ qwo, u16* __restrict__ qro)
{
    long long i = (long long)blockIdx.x * 256 + threadIdx.x;
    const int col = (int)((i * 4) & 1023);
    const long long trow = (i * 4) >> 10;
    const long long b = trow >> 10;
    const long long tr = trow & 1023;
    u16x4 qq = *(const u16x4*)(src + b * sb + tr * ld + col);
    f4 wv = *(const f4*)(rwb + col);
    f4 rv = *(const f4*)(rrb + col);
    u16x4 a, c;
    a.x = f2b((b2f(qq.x) + wv.x) * 0.125f); a.y = f2b((b2f(qq.y) + wv.y) * 0.125f);
    a.z = f2b((b2f(qq.z) + wv.z) * 0.125f); a.w = f2b((b2f(qq.w) + wv.w) * 0.125f);
    c.x = f2b((b2f(qq.x) + rv.x) * 0.125f); c.y = f2b((b2f(qq.y) + rv.y) * 0.125f);
    c.z = f2b((b2f(qq.z) + rv.z) * 0.125f); c.w = f2b((b2f(qq.w) + rv.w) * 0.125f);
    *(u16x4*)(qwo + i * 4) = a;
    *(u16x4*)(qro + i * 4) = c;
}

// out = LN(x + h1 + h2) * g + bl ; optional bf16 copy.
__global__ __launch_bounds__(256) void ln_res(const float* __restrict__ x,
                                              const float* __restrict__ h1,
                                              const float* __restrict__ h2,
                                              const float* __restrict__ g, const float* __restrict__ bl,
                                              float* __restrict__ o32, u16* __restrict__ obf)
{
    const long long row = blockIdx.x;
    const int tid = threadIdx.x;
    const long long base = row * 1024 + tid * 4;
    f4 xa = *(const f4*)(x + base);
    f4 ha = *(const f4*)(h1 + base);
    f4 hb = *(const f4*)(h2 + base);
    float v0 = xa.x + ha.x + hb.x, v1 = xa.y + ha.y + hb.y;
    float v2 = xa.z + ha.z + hb.z, v3 = xa.w + ha.w + hb.w;
    float lsum = v0 + v1 + v2 + v3;
    float lsq = v0 * v0 + v1 * v1 + v2 * v2 + v3 * v3;
    #pragma unroll
    for (int o2 = 32; o2; o2 >>= 1) { lsum += __shfl_xor(lsum, o2); lsq += __shfl_xor(lsq, o2); }
    __shared__ float r1[4], r2[4];
    int w = tid >> 6, lane = tid & 63;
    if (lane == 0) { r1[w] = lsum; r2[w] = lsq; }
    __syncthreads();
    lsum = r1[0] + r1[1] + r1[2] + r1[3];
    lsq  = r2[0] + r2[1] + r2[2] + r2[3];
    const float mu = lsum * 0.0009765625f;
    const float var = lsq * 0.0009765625f - mu * mu;
    const float rsd = rsqrtf(var + 1e-5f);
    const int c = tid * 4;
    f4 gv = *(const f4*)(g + c);
    f4 bv = *(const f4*)(bl + c);
    f4 y;
    y.x = (v0 - mu) * rsd * gv.x + bv.x;
    y.y = (v1 - mu) * rsd * gv.y + bv.y;
    y.z = (v2 - mu) * rsd * gv.z + bv.z;
    y.w = (v3 - mu) * rsd * gv.w + bv.w;
    *(f4*)(o32 + base) = y;
    if (obf) {
        u16x4 u; u.x = f2b(y.x); u.y = f2b(y.y); u.z = f2b(y.z); u.w = f2b(y.w);
        *(u16x4*)(obf + base) = u;
    }
}

// ---------------------------------------------------------------------------
extern "C" void kernel_launch(void* const* d_in, const int* in_sizes, int n_in,
                              void* d_out, int out_size, void* d_ws, size_t ws_size,
                              hipStream_t stream)
{
    (void)in_sizes; (void)n_in; (void)out_size;
    const float* src  = (const float*)d_in[0];
    const float* tgt  = (const float*)d_in[1];
    const float* mem  = (const float*)d_in[2];
    const float* pos  = (const float*)d_in[3];
    const float* rwb  = (const float*)d_in[4];
    const float* rrb  = (const float*)d_in[5];
    const float* Wq1  = (const float*)d_in[6];
    const float* Wk1  = (const float*)d_in[7];
    const float* Wv1  = (const float*)d_in[8];
    const float* Wr1  = (const float*)d_in[9];
    const float* Wo1  = (const float*)d_in[10];
    const float* ln1g = (const float*)d_in[11];
    const float* ln1b = (const float*)d_in[12];
    const float* Wq2  = (const float*)d_in[13];
    const float* Wk2  = (const float*)d_in[14];
    const float* Wv2  = (const float*)d_in[15];
    const float* Wr2  = (const float*)d_in[16];
    const float* Wo2  = (const float*)d_in[17];
    const float* ln2g = (const float*)d_in[18];
    const float* ln2b = (const float*)d_in[19];
    const float* Wf1  = (const float*)d_in[20];
    const float* bf1  = (const float*)d_in[21];
    const float* Wf2  = (const float*)d_in[22];
    const float* bf2  = (const float*)d_in[23];
    const float* ln3g = (const float*)d_in[24];
    const float* ln3b = (const float*)d_in[25];

    float* outp   = (float*)d_out;            // [4,1024,1024]
    float* newmem = outp + 4194304;           // [4,2048,1024]
    float* selfP  = outp + 12582912;          // [4,16,1024,2048]
    float* interP = outp + 146800640;         // [4,16,1024,1024]

    char* ws = (char*)d_ws;
    size_t off = 0;
    auto alloc = [&](size_t bytes) -> void* {
        void* p = ws + off;
        off = (off + bytes + 255) & ~(size_t)255;
        return p;
    };
    u16*   src_bf  = (u16*)alloc(8u << 20);       // [4096][1024]
    u16*   cat_bf  = (u16*)alloc(16u << 20);      // [8192][1024]
    u16*   pos_bf  = (u16*)alloc(4u << 20);       // [2048][1024]
    u16*   W1t    = (u16*)alloc(6u << 20);        // [3072][1024]  Wq1|Wk1|Wv1 ^T
    u16*   Wr12t  = (u16*)alloc(4u << 20);        // [2048][1024]  Wr1|Wr2 ^T
    u16*   W2t    = (u16*)alloc(4u << 20);        // [2048][1024]  Wk2|Wv2 ^T
    u16*   Wq2t   = (u16*)alloc(2u << 20);
    u16*   Wo1t   = (u16*)alloc(2u << 20);
    u16*   Wo2t   = (u16*)alloc(2u << 20);
    u16*   Wf1t   = (u16*)alloc(8u << 20);
    u16*   Wf2t   = (u16*)alloc(8u << 20);
    u16*   P1     = (u16*)alloc(48u << 20);       // [8192][3072]  Q|K|V self
    u16*   P2     = (u16*)alloc(16u << 20);       // [4096][2048]  K|V cross
    u16*   R12    = (u16*)alloc(8u << 20);        // [2048][2048]  r1 | r2
    u16*   qwb    = (u16*)alloc(8u << 20);        // [4096][1024]
    u16*   qrb    = (u16*)alloc(8u << 20);
    u16*   qb2    = (u16*)alloc(8u << 20);
    u16*   vtb    = (u16*)alloc(16u << 20);       // V^T (reused both layers)
    u16*   ob     = (u16*)alloc(8u << 20);
    float* projb  = (float*)alloc(16u << 20);
    float* projb2 = (float*)alloc(16u << 20);
    float* out1_32 = (float*)alloc(16u << 20);
    u16*   out1_bf = (u16*)alloc(8u << 20);
    float* out2_32 = (float*)alloc(16u << 20);
    u16*   out2_bf = (u16*)alloc(8u << 20);
    u16*   hb     = (u16*)alloc(32u << 20);       // [4096][4096]
    if (off > ws_size) return;

    dim3 tb(32, 32);

    // ---- phase 0: conversions / transposes / new_mem
    concat_mem<<<8192, 256, 0, stream>>>(mem, tgt, newmem, cat_bf);
    conv_f2b<<<4096, 256, 0, stream>>>(src, src_bf, 1048576);
    conv_f2b<<<2048, 256, 0, stream>>>(pos, pos_bf, 524288);
    transpose_w<<<dim3(32, 32), tb, 0, stream>>>(Wq1, W1t, 1024, 1024);
    transpose_w<<<dim3(32, 32), tb, 0, stream>>>(Wk1, W1t + 1048576, 1024, 1024);
    transpose_w<<<dim3(32, 32), tb, 0, stream>>>(Wv1, W1t + 2097152, 1024, 1024);
    transpose_w<<<dim3(32, 32), tb, 0, stream>>>(Wr1, Wr12t, 1024, 1024);
    transpose_w<<<dim3(32, 32), tb, 0, stream>>>(Wr2, Wr12t + 1048576, 1024, 1024);
    transpose_w<<<dim3(32, 32), tb, 0, stream>>>(Wk2, W2t, 1024, 1024);
    transpose_w<<<dim3(32, 32), tb, 0, stream>>>(Wv2, W2t + 1048576, 1024, 1024);
    transpose_w<<<dim3(32, 32), tb, 0, stream>>>(Wq2, Wq2t, 1024, 1024);
    transpose_w<<<dim3(32, 32), tb, 0, stream>>>(Wo1, Wo1t, 1024, 1024);
    transpose_w<<<dim3(32, 32), tb, 0, stream>>>(Wo2, Wo2t, 1024, 1024);
    transpose_w<<<dim3(128, 32), tb, 0, stream>>>(Wf1, Wf1t, 1024, 4096);
    transpose_w<<<dim3(32, 128), tb, 0, stream>>>(Wf2, Wf2t, 4096, 1024);

    // ---- layer 1: self relative attention (K=2048)
    gemm_bt<4,4,1,0><<<dim3(24,64,1), 256, 0, stream>>>(cat_bf, W1t, P1, nullptr,
        8192,3072,1024, 1024,1024,3072, 0,0,0,0,0,0, 1);
    gemm_bt<4,4,1,0><<<dim3(16,16,1), 256, 0, stream>>>(pos_bf, Wr12t, R12, nullptr,
        2048,2048,1024, 1024,1024,2048, 0,0,0,0,0,0, 1);
    add_qbias<<<4096, 256, 0, stream>>>(P1 + 1024LL * 3072, 3072LL, 2048LL * 3072,
                                        rwb, rrb, qwb, qrb);
    transpose_v<<<dim3(64,2,64), tb, 0, stream>>>(P1, vtb, 2048, 3072, 2048);
    fattn<2048,0><<<dim3(64,64), 512, 0, stream>>>(qwb, qrb, P1 + 1024, R12, vtb,
                                                   selfP, ob, 3072);
    gemm_bt<4,4,0,0><<<dim3(8,32,1), 256, 0, stream>>>(ob, Wo1t, projb, nullptr,
        4096,1024,512, 1024,1024,1024, 0,0,0,0,0,0, 1);
    gemm_bt<4,4,0,0><<<dim3(8,32,1), 256, 0, stream>>>(ob + 512, Wo1t + 512, projb2, nullptr,
        4096,1024,512, 1024,1024,1024, 0,0,0,0,0,0, 1);
    ln_res<<<4096, 256, 0, stream>>>(tgt, projb, projb2, ln1g, ln1b, out1_32, out1_bf);

    // ---- layer 2: cross relative attention (K=1024)
    gemm_bt<4,4,1,0><<<dim3(8,32,1), 256, 0, stream>>>(out1_bf, Wq2t, qb2, nullptr,
        4096,1024,1024, 1024,1024,1024, 0,0,0,0,0,0, 1);
    gemm_bt<4,4,1,0><<<dim3(16,32,1), 256, 0, stream>>>(src_bf, W2t, P2, nullptr,
        4096,2048,1024, 1024,1024,2048, 0,0,0,0,0,0, 1);
    add_qbias<<<4096, 256, 0, stream>>>(qb2, 1024LL, 1048576LL, rwb, rrb, qwb, qrb);
    transpose_v<<<dim3(32,2,64), tb, 0, stream>>>(P2, vtb, 1024, 2048, 1024);
    fattn<1024,1><<<dim3(64,64), 512, 0, stream>>>(qwb, qrb, P2,
        R12 + 1024LL * 2048 + 1024, vtb, interP, ob, 2048);
    gemm_bt<4,4,0,0><<<dim3(8,32,1), 256, 0, stream>>>(ob, Wo2t, projb, nullptr,
        4096,1024,512, 1024,1024,1024, 0,0,0,0,0,0, 1);
    gemm_bt<4,4,0,0><<<dim3(8,32,1), 256, 0, stream>>>(ob + 512, Wo2t + 512, projb2, nullptr,
        4096,1024,512, 1024,1024,1024, 0,0,0,0,0,0, 1);
    ln_res<<<4096, 256, 0, stream>>>(out1_32, projb, projb2, ln2g, ln2b, out2_32, out2_bf);

    // ---- layer 3: FF
    gemm_bt<4,4,1,2><<<dim3(32,32,1), 256, 0, stream>>>(out2_bf, Wf1t, hb, bf1,
        4096,4096,1024, 1024,1024,4096, 0,0,0,0,0,0, 1);
    gemm_bt<4,4,0,1><<<dim3(8,32,1), 256, 0, stream>>>(hb, Wf2t, projb, bf2,
        4096,1024,2048, 4096,4096,1024, 0,0,0,0,0,0, 1);
    gemm_bt<4,4,0,0><<<dim3(8,32,1), 256, 0, stream>>>(hb + 2048, Wf2t + 2048, projb2, nullptr,
        4096,1024,2048, 4096,4096,1024, 0,0,0,0,0,0, 1);
    ln_res<<<4096, 256, 0, stream>>>(out2_32, projb, projb2, ln3g, ln3b, outp, nullptr);
}

// Round 7
// 1042.900 us; speedup vs baseline: 1.6975x; 1.1174x over previous
//
#include <hip/hip_runtime.h>

typedef unsigned short u16;
typedef __attribute__((ext_vector_type(8))) short short8;
typedef __attribute__((ext_vector_type(4))) float f4;
typedef __attribute__((ext_vector_type(4))) unsigned short u16x4;

__device__ __forceinline__ float b2f(u16 u) {
    unsigned int x = ((unsigned int)u) << 16;
    return __builtin_bit_cast(float, x);
}
__device__ __forceinline__ u16 f2b(float f) {
    unsigned int u = __builtin_bit_cast(unsigned int, f);
    u += 0x7FFFu + ((u >> 16) & 1u);   // round-to-nearest-even
    return (u16)(u >> 16);
}

__device__ __forceinline__ void gl16(const void* g, void* l) {
    __builtin_amdgcn_global_load_lds(
        (const __attribute__((address_space(1))) void*)g,
        (__attribute__((address_space(3))) void*)l, 16, 0, 0);
}

// ---------------------------------------------------------------------------
// bf16 MFMA GEMM, global_load_lds staging (m97 structure):
//   C[M,N] = A[M,K] @ Bt[N,K]^T  (+bias, +relu)
// Tile 128x128, BK=32, 4 waves (2x2). CBF: 0 f32-out, 1 bf16-out.
// EPI: 0 none, 1 +bias, 2 +bias+relu. Split-K via batch strides (z, batchH=1).
// ---------------------------------------------------------------------------
template<int FM, int FN, int CBF, int EPI>
__global__ __launch_bounds__(256, 3)
void gemm_bt(const u16* __restrict__ Ap, const u16* __restrict__ Bp,
             void* __restrict__ Cp, const float* __restrict__ bias,
             int M, int N, int K, int lda, int ldb, int ldc,
             long long sAh, long long sAb, long long sBh, long long sBb,
             long long sCh, long long sCb, int batchH)
{
    constexpr int BM = FM * 32;
    constexpr int BN = FN * 32;
    __shared__ __align__(16) u16 As[BM * 32];
    __shared__ __align__(16) u16 Bs[BN * 32];

    const int tid  = threadIdx.x;
    const int z    = blockIdx.z;
    const int bb   = z / batchH;
    const int hh   = z - bb * batchH;
    const int m0   = blockIdx.y * BM;
    const int n0   = blockIdx.x * BN;
    const int w    = tid >> 6;
    const int lane = tid & 63;
    const int wr   = w >> 1;
    const int wc   = w & 1;
    const int lrow = lane & 15;
    const int lk   = (lane >> 4) << 3;
    const int lrow4 = lane >> 2;
    const int lch   = lane & 3;

    const u16* Ag = Ap + sAb * bb + sAh * hh;
    const u16* Bg = Bp + sBb * bb + sBh * hh;

    f4 acc[FM][FN] = {};

    const int nKt = K >> 5;
    for (int kt = 0; kt < nKt; ++kt) {
        const int kb = kt << 5;
        __syncthreads();
        #pragma unroll
        for (int i = 0; i < BM / 64; ++i) {
            const int row0 = (w + i * 4) << 4;
            gl16(Ag + (long long)(m0 + row0 + lrow4) * lda + kb + (lch << 3),
                 &As[row0 * 32]);
        }
        #pragma unroll
        for (int i = 0; i < BN / 64; ++i) {
            const int row0 = (w + i * 4) << 4;
            gl16(Bg + (long long)(n0 + row0 + lrow4) * ldb + kb + (lch << 3),
                 &Bs[row0 * 32]);
        }
        __syncthreads();

        short8 af[FM], bv[FN];
        #pragma unroll
        for (int m = 0; m < FM; ++m)
            af[m] = *(const short8*)(&As[(wr * FM * 16 + m * 16 + lrow) * 32 + lk]);
        #pragma unroll
        for (int n = 0; n < FN; ++n)
            bv[n] = *(const short8*)(&Bs[(wc * FN * 16 + n * 16 + lrow) * 32 + lk]);
        #pragma unroll
        for (int m = 0; m < FM; ++m)
            #pragma unroll
            for (int n = 0; n < FN; ++n)
                acc[m][n] = __builtin_amdgcn_mfma_f32_16x16x32_bf16(af[m], bv[n], acc[m][n], 0, 0, 0);
    }

    const int crow0 = m0 + wr * FM * 16 + ((lane >> 4) << 2);
    const int ccol0 = n0 + wc * FN * 16 + lrow;
    if (CBF == 0) {
        float* Cg = (float*)Cp + sCb * bb + sCh * hh;
        #pragma unroll
        for (int m = 0; m < FM; ++m) {
            #pragma unroll
            for (int n = 0; n < FN; ++n) {
                const int col = ccol0 + n * 16;
                float bvv = (EPI >= 1) ? bias[col] : 0.f;
                #pragma unroll
                for (int r = 0; r < 4; ++r) {
                    float vv = acc[m][n][r] + bvv;
                    if (EPI == 2) vv = fmaxf(vv, 0.f);
                    Cg[(long long)(crow0 + m * 16 + r) * ldc + col] = vv;
                }
            }
        }
    } else {
        u16* Cg = (u16*)Cp + sCb * bb + sCh * hh;
        #pragma unroll
        for (int m = 0; m < FM; ++m) {
            #pragma unroll
            for (int n = 0; n < FN; ++n) {
                const int col = ccol0 + n * 16;
                float bvv = (EPI >= 1) ? bias[col] : 0.f;
                #pragma unroll
                for (int r = 0; r < 4; ++r) {
                    float vv = acc[m][n][r] + bvv;
                    if (EPI == 2) vv = fmaxf(vv, 0.f);
                    Cg[(long long)(crow0 + m * 16 + r) * ldc + col] = f2b(vv);
                }
            }
        }
    }
}

// ---------------------------------------------------------------------------
// Fused attention v5 (swapped-operand + wave-interleaved tiles).
// 16 q-rows, 512 threads (8 waves). Tiles round-robin across waves (jt%8==w)
// so causal masking doesn't idle high waves.
//  A0: BD~ = mfma(r, qr), written PRE-SHIFTED into e (write-only; no RMW).
//  A1: AC = mfma(K, qw); read 4 BD (8B), add, exp in-register, partial
//      row-sum in register, store exp bf16 (8B). shfl(16,32) -> psum.
//  B/C concurrent: waves 4-7 write normalized f32 probs; waves 0-3 PV MFMA.
// Scores pre-scaled by 0.125 (folded into qw/qr).
// MODE 0: self causal (limit=t+1024), KK=2048. MODE 1: cross, KK=1024.
// ---------------------------------------------------------------------------
template<int KK, int MODE>
__global__ __launch_bounds__(512)
void fattn(const u16* __restrict__ qw, const u16* __restrict__ qr,
           const u16* __restrict__ kb, const u16* __restrict__ rr,
           const u16* __restrict__ vt,
           float* __restrict__ probs, u16* __restrict__ ob, int kld)
{
    constexpr int LE = KK + 8;
    constexpr int NT = KK / 16;
    __shared__ __align__(16) u16 e[16 * LE];
    __shared__ __align__(16) u16 qws[16 * 72];
    __shared__ __align__(16) u16 qrs[17 * 72];
    __shared__ float psum[8][16];

    const int tid = threadIdx.x;
    const int bh  = blockIdx.y;
    const int b   = bh >> 4, h = bh & 15;
    const int t0  = blockIdx.x << 4;

    if (tid < 128) {
        const int row = tid >> 3, ch = tid & 7;
        *(short8*)&qws[row * 72 + ch * 8] =
            *(const short8*)(qw + ((long long)(b * 1024 + t0 + row)) * 1024 + h * 64 + ch * 8);
    } else if (tid < 256) {
        const int row = (tid - 128) >> 3, ch = tid & 7;
        *(short8*)&qrs[row * 72 + ch * 8] =
            *(const short8*)(qr + ((long long)(b * 1024 + t0 + row)) * 1024 + h * 64 + ch * 8);
    } else if (MODE == 1 && tid < 264) {
        const int ch = tid - 256;
        const int trow = (t0 + 16 > 1023) ? 1023 : (t0 + 16);  // clamped; predicated off
        *(short8*)&qrs[16 * 72 + ch * 8] =
            *(const short8*)(qr + ((long long)(b * 1024 + trow)) * 1024 + h * 64 + ch * 8);
    }
    __syncthreads();

    const int w = tid >> 6, lane = tid & 63;
    const int lc = lane & 15, g = lane >> 4, lk = g << 3;
    const int t = t0 + lc;

    const short8 bq0 = *(const short8*)&qws[lc * 72 + lk];
    const short8 bq1 = *(const short8*)&qws[lc * 72 + 32 + lk];
    const short8 br0 = *(const short8*)&qrs[lc * 72 + lk];
    const short8 br1 = *(const short8*)&qrs[lc * 72 + 32 + lk];
    short8 bs0 = {}, bs1 = {};
    if (MODE == 1) {
        bs0 = *(const short8*)&qrs[(lc + 1) * 72 + lk];
        bs1 = *(const short8*)&qrs[(lc + 1) * 72 + 32 + lk];
    }

    // ---- A0: BD~ pre-shifted write-only (interleaved tiles)
    for (int ut = w; ut < NT; ut += 8) {
        const int u0 = ut << 4;
        const bool need1 = (u0 + t0 + 30 >= 1023);
        const bool need2 = (MODE == 1) && (u0 + t0 <= 1021);
        if (!need1 && !need2) continue;
        const u16* rg = rr + (long long)(u0 + lc) * 2048 + h * 64;
        const short8 a0 = *(const short8*)(rg + lk);
        const short8 a1 = *(const short8*)(rg + 32 + lk);
        if (need1) {
            f4 acc = {};
            acc = __builtin_amdgcn_mfma_f32_16x16x32_bf16(a0, br0, acc, 0, 0, 0);
            acc = __builtin_amdgcn_mfma_f32_16x16x32_bf16(a1, br1, acc, 0, 0, 0);
            #pragma unroll
            for (int i = 0; i < 4; ++i) {
                const int j = u0 + 4 * g + i + t - 1023;
                if (j >= 0) e[lc * LE + j] = f2b(acc[i]);
            }
        }
        if (MODE == 1 && need2) {
            f4 acc = {};
            acc = __builtin_amdgcn_mfma_f32_16x16x32_bf16(a0, bs0, acc, 0, 0, 0);
            acc = __builtin_amdgcn_mfma_f32_16x16x32_bf16(a1, bs1, acc, 0, 0, 0);
            #pragma unroll
            for (int i = 0; i < 4; ++i) {
                const int j = u0 + 4 * g + i + t + 2;
                if (j < KK) e[lc * LE + j] = f2b(acc[i]);
            }
        }
    }
    __syncthreads();

    // ---- A1: AC + BD-add + exp + row-sum (interleaved tiles)
    float sum = 0.f;
    const int limit = t + 1024;
    const int jvt = (MODE == 0) ? ((t0 + 1039) >> 4) : (NT - 1);
    #pragma unroll 2
    for (int jt = w; jt < NT; jt += 8) {
        const int j0 = jt << 4;
        const int jme = j0 + 4 * g;
        if (MODE == 0 && jt > jvt) {            // fully masked tile: zero-fill
            u16x4 z = {0, 0, 0, 0};
            *(u16x4*)&e[lc * LE + jme] = z;
            continue;
        }
        const u16* kg = kb + (long long)(b * KK + j0 + lc) * kld + h * 64;
        const short8 a0 = *(const short8*)(kg + lk);
        const short8 a1 = *(const short8*)(kg + 32 + lk);
        f4 acc = {};
        acc = __builtin_amdgcn_mfma_f32_16x16x32_bf16(a0, bq0, acc, 0, 0, 0);
        acc = __builtin_amdgcn_mfma_f32_16x16x32_bf16(a1, bq1, acc, 0, 0, 0);
        u16x4 bd4 = *(const u16x4*)&e[lc * LE + jme];
        u16x4 st;
        #pragma unroll
        for (int i = 0; i < 4; ++i) {
            const int j = jme + i;
            float bd = b2f(bd4[i]);
            if (MODE == 1 && j == t + 1) bd = 0.f;
            float ev = __expf(acc[i] + bd);
            if (MODE == 0 && j > limit) ev = 0.f;
            sum += ev;
            st[i] = f2b(ev);
        }
        *(u16x4*)&e[lc * LE + jme] = st;
    }
    sum += __shfl_xor(sum, 16);
    sum += __shfl_xor(sum, 32);
    if (g == 0) psum[w][lc] = sum;
    __syncthreads();

    if (w >= 4) {
        // ---- B: normalized f32 probs write (waves 4-7)
        const int r = (tid >> 4) & 15;
        const int q = tid & 15;
        float s = 0.f;
        #pragma unroll
        for (int w2 = 0; w2 < 8; ++w2) s += psum[w2][r];
        const float inv = 1.f / s;
        float* pr = probs + ((long long)bh * 1024 + t0 + r) * KK;
        #pragma unroll 4
        for (int i2 = 0; i2 < KK / 128; ++i2) {
            const int j0 = q * 8 + i2 * 128;
            u16x4 e0 = *(const u16x4*)&e[r * LE + j0];
            u16x4 e1 = *(const u16x4*)&e[r * LE + j0 + 4];
            f4 p0, p1;
            p0.x = b2f(e0.x) * inv; p0.y = b2f(e0.y) * inv;
            p0.z = b2f(e0.z) * inv; p0.w = b2f(e0.w) * inv;
            p1.x = b2f(e1.x) * inv; p1.y = b2f(e1.y) * inv;
            p1.z = b2f(e1.z) * inv; p1.w = b2f(e1.w) * inv;
            *(f4*)(pr + j0) = p0;
            *(f4*)(pr + j0 + 4) = p1;
        }
    } else {
        // ---- C: PV (waves 0-3, 16 d-cols each)
        const int db = w << 4;
        const u16* vrow = vt + ((long long)(bh * 64 + db + lc)) * KK + lk;
        int kcend = KK / 32;
        if (MODE == 0) {
            const int ke = (t0 + 1071) >> 5;
            if (ke < kcend) kcend = ke;
        }
        f4 acc = {};
        #pragma unroll 2
        for (int kc = 0; kc < kcend; ++kc) {
            short8 a = *(const short8*)&e[lc * LE + kc * 32 + lk];
            short8 bv = *(const short8*)(vrow + kc * 32);
            acc = __builtin_amdgcn_mfma_f32_16x16x32_bf16(a, bv, acc, 0, 0, 0);
        }
        #pragma unroll
        for (int i = 0; i < 4; ++i) {
            const int trow = g * 4 + i;
            float s = 0.f;
            #pragma unroll
            for (int w2 = 0; w2 < 8; ++w2) s += psum[w2][trow];
            ob[((long long)(b * 1024 + t0 + trow)) * 1024 + h * 64 + db + lc] = f2b(acc[i] / s);
        }
    }
}

// ---------------------------------------------------------------------------
// Elementwise / layout kernels
// ---------------------------------------------------------------------------
__global__ void conv_f2b(const float* __restrict__ in, u16* __restrict__ out, long long n4)
{
    long long i = (long long)blockIdx.x * 256 + threadIdx.x;
    if (i >= n4) return;
    f4 v = *(const f4*)(in + i * 4);
    u16x4 o; o.x = f2b(v.x); o.y = f2b(v.y); o.z = f2b(v.z); o.w = f2b(v.w);
    *(u16x4*)(out + i * 4) = o;
}

__global__ void concat_mem(const float* __restrict__ mem, const float* __restrict__ tgt,
                           float* __restrict__ nm, u16* __restrict__ cat)
{
    long long i = (long long)blockIdx.x * 256 + threadIdx.x;
    long long b = i >> 19;
    int rem = (int)(i & 524287);
    int r = rem >> 8, c4 = rem & 255;
    const float* sp = (r < 1024) ? (mem + ((b << 10) + r) * 1024 + c4 * 4)
                                 : (tgt + ((b << 10) + (r - 1024)) * 1024 + c4 * 4);
    f4 v = *(const f4*)sp;
    *(f4*)(nm + i * 4) = v;
    u16x4 o; o.x = f2b(v.x); o.y = f2b(v.y); o.z = f2b(v.z); o.w = f2b(v.w);
    *(u16x4*)(cat + i * 4) = o;
}

struct TW10 { const float* s[10]; u16* d[10]; };
__global__ void transpose_w10(TW10 p)
{
    __shared__ float tile[32][33];
    const float* W = p.s[blockIdx.z];
    u16* Wt = p.d[blockIdx.z];
    int c0 = blockIdx.x * 32, r0 = blockIdx.y * 32;
    int tx = threadIdx.x, ty = threadIdx.y;
    tile[ty][tx] = W[(long long)(r0 + ty) * 1024 + c0 + tx];
    __syncthreads();
    Wt[(long long)(c0 + ty) * 1024 + r0 + tx] = f2b(tile[tx][ty]);
}

__global__ void transpose_w(const float* __restrict__ W, u16* __restrict__ Wt, int R, int C)
{
    __shared__ float tile[32][33];
    int c0 = blockIdx.x * 32, r0 = blockIdx.y * 32;
    int tx = threadIdx.x, ty = threadIdx.y;
    tile[ty][tx] = W[(long long)(r0 + ty) * C + c0 + tx];
    __syncthreads();
    Wt[(long long)(c0 + ty) * R + r0 + tx] = f2b(tile[tx][ty]);
}

// v rows from P-buffer: v(b,j,d) = src[(b*KK + j)*ld + coff + h*64 + d]
__global__ void transpose_v(const u16* __restrict__ v, u16* __restrict__ vt,
                            int KK, int ld, int coff)
{
    __shared__ u16 tile[32][33];
    int z = blockIdx.z; int b = z >> 4, hh = z & 15;
    int j0 = blockIdx.x * 32, d0 = blockIdx.y * 32;
    int tx = threadIdx.x, ty = threadIdx.y;
    tile[ty][tx] = v[((long long)(b * KK + j0 + ty)) * ld + coff + hh * 64 + d0 + tx];
    __syncthreads();
    vt[((long long)((b * 16 + hh) * 64 + d0 + ty)) * KK + j0 + tx] = tile[tx][ty];
}

// qw = (q + r_w_bias)*0.125, qr = (q + r_r_bias)*0.125 ; q read strided from src
__global__ void add_qbias(const u16* __restrict__ src, long long ld, long long sb,
                          const float* __restrict__ rwb, const float* __restrict__ rrb,
                          u16* __restrict__ qwo, u16* __restrict__ qro)
{
    long long i = (long long)blockIdx.x * 256 + threadIdx.x;
    const int col = (int)((i * 4) & 1023);
    const long long trow = (i * 4) >> 10;
    const long long b = trow >> 10;
    const long long tr = trow & 1023;
    u16x4 qq = *(const u16x4*)(src + b * sb + tr * ld + col);
    f4 wv = *(const f4*)(rwb + col);
    f4 rv = *(const f4*)(rrb + col);
    u16x4 a, c;
    a.x = f2b((b2f(qq.x) + wv.x) * 0.125f); a.y = f2b((b2f(qq.y) + wv.y) * 0.125f);
    a.z = f2b((b2f(qq.z) + wv.z) * 0.125f); a.w = f2b((b2f(qq.w) + wv.w) * 0.125f);
    c.x = f2b((b2f(qq.x) + rv.x) * 0.125f); c.y = f2b((b2f(qq.y) + rv.y) * 0.125f);
    c.z = f2b((b2f(qq.z) + rv.z) * 0.125f); c.w = f2b((b2f(qq.w) + rv.w) * 0.125f);
    *(u16x4*)(qwo + i * 4) = a;
    *(u16x4*)(qro + i * 4) = c;
}

// out = LN(x + h1 + h2 + hbias?) * g + bl ; optional bf16 copy.
__global__ __launch_bounds__(256) void ln_res(const float* __restrict__ x,
                                              const float* __restrict__ h1,
                                              const float* __restrict__ h2,
                                              const float* __restrict__ hbias,
                                              const float* __restrict__ g, const float* __restrict__ bl,
                                              float* __restrict__ o32, u16* __restrict__ obf)
{
    const long long row = blockIdx.x;
    const int tid = threadIdx.x;
    const long long base = row * 1024 + tid * 4;
    f4 xa = *(const f4*)(x + base);
    f4 ha = *(const f4*)(h1 + base);
    f4 hb = *(const f4*)(h2 + base);
    f4 hc = {0.f, 0.f, 0.f, 0.f};
    if (hbias) hc = *(const f4*)(hbias + tid * 4);
    float v0 = xa.x + ha.x + hb.x + hc.x, v1 = xa.y + ha.y + hb.y + hc.y;
    float v2 = xa.z + ha.z + hb.z + hc.z, v3 = xa.w + ha.w + hb.w + hc.w;
    float lsum = v0 + v1 + v2 + v3;
    float lsq = v0 * v0 + v1 * v1 + v2 * v2 + v3 * v3;
    #pragma unroll
    for (int o2 = 32; o2; o2 >>= 1) { lsum += __shfl_xor(lsum, o2); lsq += __shfl_xor(lsq, o2); }
    __shared__ float r1[4], r2[4];
    int w = tid >> 6, lane = tid & 63;
    if (lane == 0) { r1[w] = lsum; r2[w] = lsq; }
    __syncthreads();
    lsum = r1[0] + r1[1] + r1[2] + r1[3];
    lsq  = r2[0] + r2[1] + r2[2] + r2[3];
    const float mu = lsum * 0.0009765625f;
    const float var = lsq * 0.0009765625f - mu * mu;
    const float rsd = rsqrtf(var + 1e-5f);
    const int c = tid * 4;
    f4 gv = *(const f4*)(g + c);
    f4 bv = *(const f4*)(bl + c);
    f4 y;
    y.x = (v0 - mu) * rsd * gv.x + bv.x;
    y.y = (v1 - mu) * rsd * gv.y + bv.y;
    y.z = (v2 - mu) * rsd * gv.z + bv.z;
    y.w = (v3 - mu) * rsd * gv.w + bv.w;
    *(f4*)(o32 + base) = y;
    if (obf) {
        u16x4 u; u.x = f2b(y.x); u.y = f2b(y.y); u.z = f2b(y.z); u.w = f2b(y.w);
        *(u16x4*)(obf + base) = u;
    }
}

// ---------------------------------------------------------------------------
extern "C" void kernel_launch(void* const* d_in, const int* in_sizes, int n_in,
                              void* d_out, int out_size, void* d_ws, size_t ws_size,
                              hipStream_t stream)
{
    (void)in_sizes; (void)n_in; (void)out_size;
    const float* src  = (const float*)d_in[0];
    const float* tgt  = (const float*)d_in[1];
    const float* mem  = (const float*)d_in[2];
    const float* pos  = (const float*)d_in[3];
    const float* rwb  = (const float*)d_in[4];
    const float* rrb  = (const float*)d_in[5];
    const float* Wq1  = (const float*)d_in[6];
    const float* Wk1  = (const float*)d_in[7];
    const float* Wv1  = (const float*)d_in[8];
    const float* Wr1  = (const float*)d_in[9];
    const float* Wo1  = (const float*)d_in[10];
    const float* ln1g = (const float*)d_in[11];
    const float* ln1b = (const float*)d_in[12];
    const float* Wq2  = (const float*)d_in[13];
    const float* Wk2  = (const float*)d_in[14];
    const float* Wv2  = (const float*)d_in[15];
    const float* Wr2  = (const float*)d_in[16];
    const float* Wo2  = (const float*)d_in[17];
    const float* ln2g = (const float*)d_in[18];
    const float* ln2b = (const float*)d_in[19];
    const float* Wf1  = (const float*)d_in[20];
    const float* bf1  = (const float*)d_in[21];
    const float* Wf2  = (const float*)d_in[22];
    const float* bf2  = (const float*)d_in[23];
    const float* ln3g = (const float*)d_in[24];
    const float* ln3b = (const float*)d_in[25];

    float* outp   = (float*)d_out;            // [4,1024,1024]
    float* newmem = outp + 4194304;           // [4,2048,1024]
    float* selfP  = outp + 12582912;          // [4,16,1024,2048]
    float* interP = outp + 146800640;         // [4,16,1024,1024]

    char* ws = (char*)d_ws;
    size_t off = 0;
    auto alloc = [&](size_t bytes) -> void* {
        void* p = ws + off;
        off = (off + bytes + 255) & ~(size_t)255;
        return p;
    };
    u16*   src_bf  = (u16*)alloc(8u << 20);       // [4096][1024]
    u16*   cat_bf  = (u16*)alloc(16u << 20);      // [8192][1024]
    u16*   pos_bf  = (u16*)alloc(4u << 20);       // [2048][1024]
    u16*   W1t    = (u16*)alloc(6u << 20);        // [3072][1024]  Wq1|Wk1|Wv1 ^T
    u16*   Wr12t  = (u16*)alloc(4u << 20);        // [2048][1024]  Wr1|Wr2 ^T
    u16*   W2t    = (u16*)alloc(4u << 20);        // [2048][1024]  Wk2|Wv2 ^T
    u16*   Wq2t   = (u16*)alloc(2u << 20);
    u16*   Wo1t   = (u16*)alloc(2u << 20);
    u16*   Wo2t   = (u16*)alloc(2u << 20);
    u16*   Wf1t   = (u16*)alloc(8u << 20);
    u16*   Wf2t   = (u16*)alloc(8u << 20);
    u16*   P1     = (u16*)alloc(48u << 20);       // [8192][3072]  Q|K|V self
    u16*   P2     = (u16*)alloc(16u << 20);       // [4096][2048]  K|V cross
    u16*   R12    = (u16*)alloc(8u << 20);        // [2048][2048]  r1 | r2
    u16*   qwb    = (u16*)alloc(8u << 20);        // [4096][1024]
    u16*   qrb    = (u16*)alloc(8u << 20);
    u16*   qb2    = (u16*)alloc(8u << 20);
    u16*   vtb    = (u16*)alloc(16u << 20);       // V^T (reused both layers)
    u16*   ob     = (u16*)alloc(8u << 20);
    float* projb  = (float*)alloc(16u << 20);
    float* projb2 = (float*)alloc(16u << 20);     // must stay contiguous after projb
    float* out1_32 = (float*)alloc(16u << 20);
    u16*   out1_bf = (u16*)alloc(8u << 20);
    float* out2_32 = (float*)alloc(16u << 20);
    u16*   out2_bf = (u16*)alloc(8u << 20);
    u16*   hb     = (u16*)alloc(32u << 20);       // [4096][4096]
    if (off > ws_size) return;
    const long long PJ2 = projb2 - projb;         // f32 elems between split-K halves

    dim3 tb(32, 32);

    // ---- phase 0: conversions / transposes / new_mem
    concat_mem<<<8192, 256, 0, stream>>>(mem, tgt, newmem, cat_bf);
    conv_f2b<<<4096, 256, 0, stream>>>(src, src_bf, 1048576);
    conv_f2b<<<2048, 256, 0, stream>>>(pos, pos_bf, 524288);
    TW10 tw;
    tw.s[0] = Wq1; tw.d[0] = W1t;
    tw.s[1] = Wk1; tw.d[1] = W1t + 1048576;
    tw.s[2] = Wv1; tw.d[2] = W1t + 2097152;
    tw.s[3] = Wr1; tw.d[3] = Wr12t;
    tw.s[4] = Wr2; tw.d[4] = Wr12t + 1048576;
    tw.s[5] = Wk2; tw.d[5] = W2t;
    tw.s[6] = Wv2; tw.d[6] = W2t + 1048576;
    tw.s[7] = Wq2; tw.d[7] = Wq2t;
    tw.s[8] = Wo1; tw.d[8] = Wo1t;
    tw.s[9] = Wo2; tw.d[9] = Wo2t;
    transpose_w10<<<dim3(32, 32, 10), tb, 0, stream>>>(tw);
    transpose_w<<<dim3(128, 32), tb, 0, stream>>>(Wf1, Wf1t, 1024, 4096);
    transpose_w<<<dim3(32, 128), tb, 0, stream>>>(Wf2, Wf2t, 4096, 1024);

    // ---- layer 1: self relative attention (K=2048)
    gemm_bt<4,4,1,0><<<dim3(24,64,1), 256, 0, stream>>>(cat_bf, W1t, P1, nullptr,
        8192,3072,1024, 1024,1024,3072, 0,0,0,0,0,0, 1);
    gemm_bt<4,4,1,0><<<dim3(16,16,1), 256, 0, stream>>>(pos_bf, Wr12t, R12, nullptr,
        2048,2048,1024, 1024,1024,2048, 0,0,0,0,0,0, 1);
    add_qbias<<<4096, 256, 0, stream>>>(P1 + 1024LL * 3072, 3072LL, 2048LL * 3072,
                                        rwb, rrb, qwb, qrb);
    transpose_v<<<dim3(64,2,64), tb, 0, stream>>>(P1, vtb, 2048, 3072, 2048);
    fattn<2048,0><<<dim3(64,64), 512, 0, stream>>>(qwb, qrb, P1 + 1024, R12, vtb,
                                                   selfP, ob, 3072);
    // Wo1, split-K x2 merged (z selects K-half; C-halves summed in ln_res)
    gemm_bt<4,4,0,0><<<dim3(8,32,2), 256, 0, stream>>>(ob, Wo1t, projb, nullptr,
        4096,1024,512, 1024,1024,1024, 0,512, 0,512, 0,PJ2, 1);
    ln_res<<<4096, 256, 0, stream>>>(tgt, projb, projb2, nullptr, ln1g, ln1b, out1_32, out1_bf);

    // ---- layer 2: cross relative attention (K=1024)
    gemm_bt<4,4,1,0><<<dim3(8,32,1), 256, 0, stream>>>(out1_bf, Wq2t, qb2, nullptr,
        4096,1024,1024, 1024,1024,1024, 0,0,0,0,0,0, 1);
    gemm_bt<4,4,1,0><<<dim3(16,32,1), 256, 0, stream>>>(src_bf, W2t, P2, nullptr,
        4096,2048,1024, 1024,1024,2048, 0,0,0,0,0,0, 1);
    add_qbias<<<4096, 256, 0, stream>>>(qb2, 1024LL, 1048576LL, rwb, rrb, qwb, qrb);
    transpose_v<<<dim3(32,2,64), tb, 0, stream>>>(P2, vtb, 1024, 2048, 1024);
    fattn<1024,1><<<dim3(64,64), 512, 0, stream>>>(qwb, qrb, P2,
        R12 + 1024LL * 2048 + 1024, vtb, interP, ob, 2048);
    gemm_bt<4,4,0,0><<<dim3(8,32,2), 256, 0, stream>>>(ob, Wo2t, projb, nullptr,
        4096,1024,512, 1024,1024,1024, 0,512, 0,512, 0,PJ2, 1);
    ln_res<<<4096, 256, 0, stream>>>(out1_32, projb, projb2, nullptr, ln2g, ln2b, out2_32, out2_bf);

    // ---- layer 3: FF
    gemm_bt<4,4,1,2><<<dim3(32,32,1), 256, 0, stream>>>(out2_bf, Wf1t, hb, bf1,
        4096,4096,1024, 1024,1024,4096, 0,0,0,0,0,0, 1);
    // FF2 split-K x2 merged; bf2 bias folded into ln_res
    gemm_bt<4,4,0,0><<<dim3(8,32,2), 256, 0, stream>>>(hb, Wf2t, projb, nullptr,
        4096,1024,2048, 4096,4096,1024, 0,2048, 0,2048, 0,PJ2, 1);
    ln_res<<<4096, 256, 0, stream>>>(out2_32, projb, projb2, bf2, ln3g, ln3b, outp, nullptr);
}

// Round 8
// 971.673 us; speedup vs baseline: 1.8220x; 1.0733x over previous
//
#include <hip/hip_runtime.h>

typedef unsigned short u16;
typedef __attribute__((ext_vector_type(8))) short short8;
typedef __attribute__((ext_vector_type(4))) float f4;
typedef __attribute__((ext_vector_type(4))) unsigned short u16x4;

__device__ __forceinline__ float b2f(u16 u) {
    unsigned int x = ((unsigned int)u) << 16;
    return __builtin_bit_cast(float, x);
}
__device__ __forceinline__ u16 f2b(float f) {
    unsigned int u = __builtin_bit_cast(unsigned int, f);
    u += 0x7FFFu + ((u >> 16) & 1u);   // round-to-nearest-even
    return (u16)(u >> 16);
}

__device__ __forceinline__ void gl16(const void* g, void* l) {
    __builtin_amdgcn_global_load_lds(
        (const __attribute__((address_space(1))) void*)g,
        (__attribute__((address_space(3))) void*)l, 16, 0, 0);
}

// ---------------------------------------------------------------------------
// bf16 MFMA GEMM, global_load_lds staging (m97 structure):
//   C[M,N] = A[M,K] @ Bt[N,K]^T  (+bias, +relu)
// Tile 128x128, BK=32, 4 waves (2x2). CBF: 0 f32-out, 1 bf16-out.
// EPI: 0 none, 1 +bias, 2 +bias+relu. Split-K / multi-source via batch strides.
// ---------------------------------------------------------------------------
template<int FM, int FN, int CBF, int EPI>
__global__ __launch_bounds__(256, 3)
void gemm_bt(const u16* __restrict__ Ap, const u16* __restrict__ Bp,
             void* __restrict__ Cp, const float* __restrict__ bias,
             int M, int N, int K, int lda, int ldb, int ldc,
             long long sAh, long long sAb, long long sBh, long long sBb,
             long long sCh, long long sCb, int batchH)
{
    constexpr int BM = FM * 32;
    constexpr int BN = FN * 32;
    __shared__ __align__(16) u16 As[BM * 32];
    __shared__ __align__(16) u16 Bs[BN * 32];

    const int tid  = threadIdx.x;
    const int z    = blockIdx.z;
    const int bb   = z / batchH;
    const int hh   = z - bb * batchH;
    const int m0   = blockIdx.y * BM;
    const int n0   = blockIdx.x * BN;
    const int w    = tid >> 6;
    const int lane = tid & 63;
    const int wr   = w >> 1;
    const int wc   = w & 1;
    const int lrow = lane & 15;
    const int lk   = (lane >> 4) << 3;
    const int lrow4 = lane >> 2;
    const int lch   = lane & 3;

    const u16* Ag = Ap + sAb * bb + sAh * hh;
    const u16* Bg = Bp + sBb * bb + sBh * hh;

    f4 acc[FM][FN] = {};

    const int nKt = K >> 5;
    for (int kt = 0; kt < nKt; ++kt) {
        const int kb = kt << 5;
        __syncthreads();
        #pragma unroll
        for (int i = 0; i < BM / 64; ++i) {
            const int row0 = (w + i * 4) << 4;
            gl16(Ag + (long long)(m0 + row0 + lrow4) * lda + kb + (lch << 3),
                 &As[row0 * 32]);
        }
        #pragma unroll
        for (int i = 0; i < BN / 64; ++i) {
            const int row0 = (w + i * 4) << 4;
            gl16(Bg + (long long)(n0 + row0 + lrow4) * ldb + kb + (lch << 3),
                 &Bs[row0 * 32]);
        }
        __syncthreads();

        short8 af[FM], bv[FN];
        #pragma unroll
        for (int m = 0; m < FM; ++m)
            af[m] = *(const short8*)(&As[(wr * FM * 16 + m * 16 + lrow) * 32 + lk]);
        #pragma unroll
        for (int n = 0; n < FN; ++n)
            bv[n] = *(const short8*)(&Bs[(wc * FN * 16 + n * 16 + lrow) * 32 + lk]);
        #pragma unroll
        for (int m = 0; m < FM; ++m)
            #pragma unroll
            for (int n = 0; n < FN; ++n)
                acc[m][n] = __builtin_amdgcn_mfma_f32_16x16x32_bf16(af[m], bv[n], acc[m][n], 0, 0, 0);
    }

    const int crow0 = m0 + wr * FM * 16 + ((lane >> 4) << 2);
    const int ccol0 = n0 + wc * FN * 16 + lrow;
    if (CBF == 0) {
        float* Cg = (float*)Cp + sCb * bb + sCh * hh;
        #pragma unroll
        for (int m = 0; m < FM; ++m) {
            #pragma unroll
            for (int n = 0; n < FN; ++n) {
                const int col = ccol0 + n * 16;
                float bvv = (EPI >= 1) ? bias[col] : 0.f;
                #pragma unroll
                for (int r = 0; r < 4; ++r) {
                    float vv = acc[m][n][r] + bvv;
                    if (EPI == 2) vv = fmaxf(vv, 0.f);
                    Cg[(long long)(crow0 + m * 16 + r) * ldc + col] = vv;
                }
            }
        }
    } else {
        u16* Cg = (u16*)Cp + sCb * bb + sCh * hh;
        #pragma unroll
        for (int m = 0; m < FM; ++m) {
            #pragma unroll
            for (int n = 0; n < FN; ++n) {
                const int col = ccol0 + n * 16;
                float bvv = (EPI >= 1) ? bias[col] : 0.f;
                #pragma unroll
                for (int r = 0; r < 4; ++r) {
                    float vv = acc[m][n][r] + bvv;
                    if (EPI == 2) vv = fmaxf(vv, 0.f);
                    Cg[(long long)(crow0 + m * 16 + r) * ldc + col] = f2b(vv);
                }
            }
        }
    }
}

// ---------------------------------------------------------------------------
// Fused attention v6 (swapped-operand, wave-interleaved, fused q-bias staging).
// 16 q-rows, 512 threads (8 waves). Tiles round-robin across waves.
// Staging: qws = (q+rwb)*0.125, qrs = (q+rrb)*0.125 read from raw Q proj.
//  A0: BD~ = mfma(r, qr), written PRE-SHIFTED into e (write-only; no RMW).
//  A1: AC = mfma(K, qw); read 4 BD (8B), add, exp in-register, partial
//      row-sum in register, store exp bf16 (8B). shfl(16,32) -> psum.
//  B/C concurrent: waves 4-7 write normalized f32 probs (non-temporal);
//      waves 0-3 PV MFMA.
// MODE 0: self causal (limit=t+1024), KK=2048. MODE 1: cross, KK=1024.
// ---------------------------------------------------------------------------
template<int KK, int MODE>
__global__ __launch_bounds__(512)
void fattn(const u16* __restrict__ qsrc, long long qld, long long qsb,
           const float* __restrict__ rwb, const float* __restrict__ rrb,
           const u16* __restrict__ kb, const u16* __restrict__ rr,
           const u16* __restrict__ vt,
           float* __restrict__ probs, u16* __restrict__ ob, int kld)
{
    constexpr int LE = KK + 8;
    constexpr int NT = KK / 16;
    __shared__ __align__(16) u16 e[16 * LE];
    __shared__ __align__(16) u16 qws[16 * 72];
    __shared__ __align__(16) u16 qrs[17 * 72];
    __shared__ float psum[8][16];

    const int tid = threadIdx.x;
    const int bh  = blockIdx.y;
    const int b   = bh >> 4, h = bh & 15;
    const int t0  = blockIdx.x << 4;

    // ---- staging: q + bias, scaled 0.125, to LDS
    if (tid < 264) {
        int row, ch; const float* bias; u16* dst; bool act = true;
        if (tid < 128)      { row = tid >> 3;        ch = tid & 7; bias = rwb; dst = &qws[row * 72 + ch * 8]; }
        else if (tid < 256) { row = (tid - 128) >> 3; ch = tid & 7; bias = rrb; dst = &qrs[row * 72 + ch * 8]; }
        else if (MODE == 1) { row = 16;              ch = tid - 256; bias = rrb; dst = &qrs[16 * 72 + ch * 8]; }
        else act = false;
        if (act) {
            int trow = t0 + row; if (trow > 1023) trow = 1023;   // clamp (predicated off)
            short8 qv = *(const short8*)(qsrc + b * qsb + (long long)trow * qld + h * 64 + ch * 8);
            const float* bp = bias + h * 64 + ch * 8;
            f4 b0 = *(const f4*)bp, b1 = *(const f4*)(bp + 4);
            short8 o;
            o[0] = (short)f2b((b2f((u16)qv[0]) + b0.x) * 0.125f);
            o[1] = (short)f2b((b2f((u16)qv[1]) + b0.y) * 0.125f);
            o[2] = (short)f2b((b2f((u16)qv[2]) + b0.z) * 0.125f);
            o[3] = (short)f2b((b2f((u16)qv[3]) + b0.w) * 0.125f);
            o[4] = (short)f2b((b2f((u16)qv[4]) + b1.x) * 0.125f);
            o[5] = (short)f2b((b2f((u16)qv[5]) + b1.y) * 0.125f);
            o[6] = (short)f2b((b2f((u16)qv[6]) + b1.z) * 0.125f);
            o[7] = (short)f2b((b2f((u16)qv[7]) + b1.w) * 0.125f);
            *(short8*)dst = o;
        }
    }
    __syncthreads();

    const int w = tid >> 6, lane = tid & 63;
    const int lc = lane & 15, g = lane >> 4, lk = g << 3;
    const int t = t0 + lc;

    const short8 bq0 = *(const short8*)&qws[lc * 72 + lk];
    const short8 bq1 = *(const short8*)&qws[lc * 72 + 32 + lk];
    const short8 br0 = *(const short8*)&qrs[lc * 72 + lk];
    const short8 br1 = *(const short8*)&qrs[lc * 72 + 32 + lk];
    short8 bs0 = {}, bs1 = {};
    if (MODE == 1) {
        bs0 = *(const short8*)&qrs[(lc + 1) * 72 + lk];
        bs1 = *(const short8*)&qrs[(lc + 1) * 72 + 32 + lk];
    }

    // ---- A0: BD~ pre-shifted write-only (interleaved tiles)
    #pragma unroll 2
    for (int ut = w; ut < NT; ut += 8) {
        const int u0 = ut << 4;
        const bool need1 = (u0 + t0 + 30 >= 1023);
        const bool need2 = (MODE == 1) && (u0 + t0 <= 1021);
        if (!need1 && !need2) continue;
        const u16* rg = rr + (long long)(u0 + lc) * 2048 + h * 64;
        const short8 a0 = *(const short8*)(rg + lk);
        const short8 a1 = *(const short8*)(rg + 32 + lk);
        if (need1) {
            f4 acc = {};
            acc = __builtin_amdgcn_mfma_f32_16x16x32_bf16(a0, br0, acc, 0, 0, 0);
            acc = __builtin_amdgcn_mfma_f32_16x16x32_bf16(a1, br1, acc, 0, 0, 0);
            #pragma unroll
            for (int i = 0; i < 4; ++i) {
                const int j = u0 + 4 * g + i + t - 1023;
                if (j >= 0) e[lc * LE + j] = f2b(acc[i]);
            }
        }
        if (MODE == 1 && need2) {
            f4 acc = {};
            acc = __builtin_amdgcn_mfma_f32_16x16x32_bf16(a0, bs0, acc, 0, 0, 0);
            acc = __builtin_amdgcn_mfma_f32_16x16x32_bf16(a1, bs1, acc, 0, 0, 0);
            #pragma unroll
            for (int i = 0; i < 4; ++i) {
                const int j = u0 + 4 * g + i + t + 2;
                if (j < KK) e[lc * LE + j] = f2b(acc[i]);
            }
        }
    }
    __syncthreads();

    // ---- A1: AC + BD-add + exp + row-sum (interleaved tiles)
    float sum = 0.f;
    const int limit = t + 1024;
    const int jvt = (MODE == 0) ? ((t0 + 1039) >> 4) : (NT - 1);
    #pragma unroll 4
    for (int jt = w; jt < NT; jt += 8) {
        const int j0 = jt << 4;
        const int jme = j0 + 4 * g;
        if (MODE == 0 && jt > jvt) {            // fully masked tile: zero-fill
            u16x4 z = {0, 0, 0, 0};
            *(u16x4*)&e[lc * LE + jme] = z;
            continue;
        }
        const u16* kg = kb + (long long)(b * KK + j0 + lc) * kld + h * 64;
        const short8 a0 = *(const short8*)(kg + lk);
        const short8 a1 = *(const short8*)(kg + 32 + lk);
        f4 acc = {};
        acc = __builtin_amdgcn_mfma_f32_16x16x32_bf16(a0, bq0, acc, 0, 0, 0);
        acc = __builtin_amdgcn_mfma_f32_16x16x32_bf16(a1, bq1, acc, 0, 0, 0);
        u16x4 bd4 = *(const u16x4*)&e[lc * LE + jme];
        u16x4 st;
        #pragma unroll
        for (int i = 0; i < 4; ++i) {
            const int j = jme + i;
            float bd = b2f(bd4[i]);
            if (MODE == 1 && j == t + 1) bd = 0.f;
            float ev = __expf(acc[i] + bd);
            if (MODE == 0 && j > limit) ev = 0.f;
            sum += ev;
            st[i] = f2b(ev);
        }
        *(u16x4*)&e[lc * LE + jme] = st;
    }
    sum += __shfl_xor(sum, 16);
    sum += __shfl_xor(sum, 32);
    if (g == 0) psum[w][lc] = sum;
    __syncthreads();

    if (w >= 4) {
        // ---- B: normalized f32 probs write (waves 4-7), non-temporal
        const int r = (tid >> 4) & 15;
        const int q = tid & 15;
        float s = 0.f;
        #pragma unroll
        for (int w2 = 0; w2 < 8; ++w2) s += psum[w2][r];
        const float inv = 1.f / s;
        float* pr = probs + ((long long)bh * 1024 + t0 + r) * KK;
        #pragma unroll 4
        for (int i2 = 0; i2 < KK / 128; ++i2) {
            const int j0 = q * 8 + i2 * 128;
            u16x4 e0 = *(const u16x4*)&e[r * LE + j0];
            u16x4 e1 = *(const u16x4*)&e[r * LE + j0 + 4];
            f4 p0, p1;
            p0.x = b2f(e0.x) * inv; p0.y = b2f(e0.y) * inv;
            p0.z = b2f(e0.z) * inv; p0.w = b2f(e0.w) * inv;
            p1.x = b2f(e1.x) * inv; p1.y = b2f(e1.y) * inv;
            p1.z = b2f(e1.z) * inv; p1.w = b2f(e1.w) * inv;
            __builtin_nontemporal_store(p0, (f4*)(pr + j0));
            __builtin_nontemporal_store(p1, (f4*)(pr + j0 + 4));
        }
    } else {
        // ---- C: PV (waves 0-3, 16 d-cols each)
        const int db = w << 4;
        const u16* vrow = vt + ((long long)(bh * 64 + db + lc)) * KK + lk;
        int kcend = KK / 32;
        if (MODE == 0) {
            const int ke = (t0 + 1071) >> 5;
            if (ke < kcend) kcend = ke;
        }
        f4 acc = {};
        #pragma unroll 2
        for (int kc = 0; kc < kcend; ++kc) {
            short8 a = *(const short8*)&e[lc * LE + kc * 32 + lk];
            short8 bv = *(const short8*)(vrow + kc * 32);
            acc = __builtin_amdgcn_mfma_f32_16x16x32_bf16(a, bv, acc, 0, 0, 0);
        }
        #pragma unroll
        for (int i = 0; i < 4; ++i) {
            const int trow = g * 4 + i;
            float s = 0.f;
            #pragma unroll
            for (int w2 = 0; w2 < 8; ++w2) s += psum[w2][trow];
            ob[((long long)(b * 1024 + t0 + trow)) * 1024 + h * 64 + db + lc] = f2b(acc[i] / s);
        }
    }
}

// ---------------------------------------------------------------------------
// Elementwise / layout kernels
// ---------------------------------------------------------------------------
__global__ void conv_f2b(const float* __restrict__ in, u16* __restrict__ out, long long n4)
{
    long long i = (long long)blockIdx.x * 256 + threadIdx.x;
    if (i >= n4) return;
    f4 v = *(const f4*)(in + i * 4);
    u16x4 o; o.x = f2b(v.x); o.y = f2b(v.y); o.z = f2b(v.z); o.w = f2b(v.w);
    *(u16x4*)(out + i * 4) = o;
}

__global__ void concat_mem(const float* __restrict__ mem, const float* __restrict__ tgt,
                           float* __restrict__ nm, u16* __restrict__ cat)
{
    long long i = (long long)blockIdx.x * 256 + threadIdx.x;
    long long b = i >> 19;
    int rem = (int)(i & 524287);
    int r = rem >> 8, c4 = rem & 255;
    const float* sp = (r < 1024) ? (mem + ((b << 10) + r) * 1024 + c4 * 4)
                                 : (tgt + ((b << 10) + (r - 1024)) * 1024 + c4 * 4);
    f4 v = *(const f4*)sp;
    __builtin_nontemporal_store(v, (f4*)(nm + i * 4));
    u16x4 o; o.x = f2b(v.x); o.y = f2b(v.y); o.z = f2b(v.z); o.w = f2b(v.w);
    *(u16x4*)(cat + i * 4) = o;
}

struct TWS { const float* s; u16* d; int sld, dld; };
struct TW18 { TWS t[18]; };
__global__ void transpose_w18(TW18 p)
{
    __shared__ float tile[32][33];
    const TWS ts = p.t[blockIdx.z];
    int c0 = blockIdx.x * 32, r0 = blockIdx.y * 32;
    int tx = threadIdx.x, ty = threadIdx.y;
    tile[ty][tx] = ts.s[(long long)(r0 + ty) * ts.sld + c0 + tx];
    __syncthreads();
    ts.d[(long long)(c0 + ty) * ts.dld + r0 + tx] = f2b(tile[tx][ty]);
}

// V^T: vt[(b*16+h)*64+d][j] = v[(b*KK+j)*ld + coff + h*64 + d]
// 64x64 tiles, short8 coalesced reads AND writes through LDS transpose.
__global__ __launch_bounds__(256) void transpose_v(const u16* __restrict__ v, u16* __restrict__ vt,
                                                   int KK, int ld, int coff)
{
    __shared__ u16 tile[64][68];
    const int z = blockIdx.z, b = z >> 4, h = z & 15;
    const int j0 = blockIdx.x << 6;
    const int rr8 = threadIdx.x >> 3;       // 0..31
    const int c8 = (threadIdx.x & 7) << 3;  // 0,8,..,56
    #pragma unroll
    for (int p = 0; p < 2; ++p) {
        const int jr = p * 32 + rr8;
        short8 val = *(const short8*)(v + ((long long)(b * KK + j0 + jr)) * ld + coff + h * 64 + c8);
        #pragma unroll
        for (int k = 0; k < 8; ++k) tile[c8 + k][jr] = (u16)val[k];
    }
    __syncthreads();
    #pragma unroll
    for (int p = 0; p < 2; ++p) {
        const int d = p * 32 + rr8;
        short8 o;
        #pragma unroll
        for (int k = 0; k < 8; ++k) o[k] = (short)tile[d][c8 + k];
        *(short8*)(vt + ((long long)((b * 16 + h) * 64 + d)) * KK + j0 + c8) = o;
    }
}

// out = LN(x + h1 + h2 + hbias?) * g + bl ; optional bf16 copy.
__global__ __launch_bounds__(256) void ln_res(const float* __restrict__ x,
                                              const float* __restrict__ h1,
                                              const float* __restrict__ h2,
                                              const float* __restrict__ hbias,
                                              const float* __restrict__ g, const float* __restrict__ bl,
                                              float* __restrict__ o32, u16* __restrict__ obf)
{
    const long long row = blockIdx.x;
    const int tid = threadIdx.x;
    const long long base = row * 1024 + tid * 4;
    f4 xa = *(const f4*)(x + base);
    f4 ha = *(const f4*)(h1 + base);
    f4 hb = *(const f4*)(h2 + base);
    f4 hc = {0.f, 0.f, 0.f, 0.f};
    if (hbias) hc = *(const f4*)(hbias + tid * 4);
    float v0 = xa.x + ha.x + hb.x + hc.x, v1 = xa.y + ha.y + hb.y + hc.y;
    float v2 = xa.z + ha.z + hb.z + hc.z, v3 = xa.w + ha.w + hb.w + hc.w;
    float lsum = v0 + v1 + v2 + v3;
    float lsq = v0 * v0 + v1 * v1 + v2 * v2 + v3 * v3;
    #pragma unroll
    for (int o2 = 32; o2; o2 >>= 1) { lsum += __shfl_xor(lsum, o2); lsq += __shfl_xor(lsq, o2); }
    __shared__ float r1[4], r2[4];
    int w = tid >> 6, lane = tid & 63;
    if (lane == 0) { r1[w] = lsum; r2[w] = lsq; }
    __syncthreads();
    lsum = r1[0] + r1[1] + r1[2] + r1[3];
    lsq  = r2[0] + r2[1] + r2[2] + r2[3];
    const float mu = lsum * 0.0009765625f;
    const float var = lsq * 0.0009765625f - mu * mu;
    const float rsd = rsqrtf(var + 1e-5f);
    const int c = tid * 4;
    f4 gv = *(const f4*)(g + c);
    f4 bv = *(const f4*)(bl + c);
    f4 y;
    y.x = (v0 - mu) * rsd * gv.x + bv.x;
    y.y = (v1 - mu) * rsd * gv.y + bv.y;
    y.z = (v2 - mu) * rsd * gv.z + bv.z;
    y.w = (v3 - mu) * rsd * gv.w + bv.w;
    *(f4*)(o32 + base) = y;
    if (obf) {
        u16x4 u; u.x = f2b(y.x); u.y = f2b(y.y); u.z = f2b(y.z); u.w = f2b(y.w);
        *(u16x4*)(obf + base) = u;
    }
}

// ---------------------------------------------------------------------------
extern "C" void kernel_launch(void* const* d_in, const int* in_sizes, int n_in,
                              void* d_out, int out_size, void* d_ws, size_t ws_size,
                              hipStream_t stream)
{
    (void)in_sizes; (void)n_in; (void)out_size;
    const float* src  = (const float*)d_in[0];
    const float* tgt  = (const float*)d_in[1];
    const float* mem  = (const float*)d_in[2];
    const float* pos  = (const float*)d_in[3];
    const float* rwb  = (const float*)d_in[4];
    const float* rrb  = (const float*)d_in[5];
    const float* Wq1  = (const float*)d_in[6];
    const float* Wk1  = (const float*)d_in[7];
    const float* Wv1  = (const float*)d_in[8];
    const float* Wr1  = (const float*)d_in[9];
    const float* Wo1  = (const float*)d_in[10];
    const float* ln1g = (const float*)d_in[11];
    const float* ln1b = (const float*)d_in[12];
    const float* Wq2  = (const float*)d_in[13];
    const float* Wk2  = (const float*)d_in[14];
    const float* Wv2  = (const float*)d_in[15];
    const float* Wr2  = (const float*)d_in[16];
    const float* Wo2  = (const float*)d_in[17];
    const float* ln2g = (const float*)d_in[18];
    const float* ln2b = (const float*)d_in[19];
    const float* Wf1  = (const float*)d_in[20];
    const float* bf1  = (const float*)d_in[21];
    const float* Wf2  = (const float*)d_in[22];
    const float* bf2  = (const float*)d_in[23];
    const float* ln3g = (const float*)d_in[24];
    const float* ln3b = (const float*)d_in[25];

    float* outp   = (float*)d_out;            // [4,1024,1024]
    float* newmem = outp + 4194304;           // [4,2048,1024]
    float* selfP  = outp + 12582912;          // [4,16,1024,2048]
    float* interP = outp + 146800640;         // [4,16,1024,1024]

    char* ws = (char*)d_ws;
    size_t off = 0;
    auto alloc = [&](size_t bytes) -> void* {
        void* p = ws + off;
        off = (off + bytes + 255) & ~(size_t)255;
        return p;
    };
    u16*   src_bf  = (u16*)alloc(8u << 20);       // [4096][1024]
    u16*   cat_bf  = (u16*)alloc(16u << 20);      // [8192][1024]
    u16*   pos_bf  = (u16*)alloc(4u << 20);       // [2048][1024]
    u16*   W1t    = (u16*)alloc(6u << 20);        // [3072][1024]  Wq1|Wk1|Wv1 ^T
    u16*   Wr12t  = (u16*)alloc(4u << 20);        // [2048][1024]  Wr1|Wr2 ^T
    u16*   W2t    = (u16*)alloc(4u << 20);        // [2048][1024]  Wk2|Wv2 ^T
    u16*   Wq2t   = (u16*)alloc(2u << 20);
    u16*   Wo1t   = (u16*)alloc(2u << 20);
    u16*   Wo2t   = (u16*)alloc(2u << 20);
    u16*   Wf1t   = (u16*)alloc(8u << 20);
    u16*   Wf2t   = (u16*)alloc(8u << 20);
    u16*   P1     = (u16*)alloc(48u << 20);       // [8192][3072]  Q|K|V self
    u16*   P2k    = (u16*)alloc(8u << 20);        // [4096][1024]  K cross
    u16*   P2v    = (u16*)alloc(8u << 20);        // [4096][1024]  V cross
    u16*   R12    = (u16*)alloc(8u << 20);        // [2048][2048]  r1 | r2
    u16*   qb2    = (u16*)alloc(8u << 20);        // cross Q proj
    u16*   vtb    = (u16*)alloc(16u << 20);       // V^T (reused both layers)
    u16*   ob     = (u16*)alloc(8u << 20);
    float* projb  = (float*)alloc(16u << 20);
    float* projb2 = (float*)alloc(16u << 20);
    float* out1_32 = (float*)alloc(16u << 20);
    u16*   out1_bf = (u16*)alloc(8u << 20);
    float* out2_32 = (float*)alloc(16u << 20);
    u16*   out2_bf = (u16*)alloc(8u << 20);
    u16*   hb     = (u16*)alloc(32u << 20);       // [4096][4096]
    if (off > ws_size) return;
    const long long PJ2 = projb2 - projb;

    dim3 tb(32, 32);

    // ---- phase 0: conversions / transposes / new_mem
    concat_mem<<<8192, 256, 0, stream>>>(mem, tgt, newmem, cat_bf);
    conv_f2b<<<4096, 256, 0, stream>>>(src, src_bf, 1048576);
    conv_f2b<<<2048, 256, 0, stream>>>(pos, pos_bf, 524288);
    TW18 tw;
    tw.t[0] = {Wq1, W1t, 1024, 1024};
    tw.t[1] = {Wk1, W1t + 1048576, 1024, 1024};
    tw.t[2] = {Wv1, W1t + 2097152, 1024, 1024};
    tw.t[3] = {Wr1, Wr12t, 1024, 1024};
    tw.t[4] = {Wr2, Wr12t + 1048576, 1024, 1024};
    tw.t[5] = {Wk2, W2t, 1024, 1024};
    tw.t[6] = {Wv2, W2t + 1048576, 1024, 1024};
    tw.t[7] = {Wq2, Wq2t, 1024, 1024};
    tw.t[8] = {Wo1, Wo1t, 1024, 1024};
    tw.t[9] = {Wo2, Wo2t, 1024, 1024};
    for (int zz = 0; zz < 4; ++zz) {
        tw.t[10 + zz] = {Wf1 + zz * 1024, Wf1t + (long long)zz * 1048576, 4096, 1024};
        tw.t[14 + zz] = {Wf2 + (long long)zz * 1048576, Wf2t + zz * 1024, 1024, 4096};
    }
    transpose_w18<<<dim3(32, 32, 18), tb, 0, stream>>>(tw);

    // ---- layer 1: self relative attention (K=2048)
    gemm_bt<4,4,1,0><<<dim3(24,64,1), 256, 0, stream>>>(cat_bf, W1t, P1, nullptr,
        8192,3072,1024, 1024,1024,3072, 0,0,0,0,0,0, 1);
    gemm_bt<4,4,1,0><<<dim3(16,16,1), 256, 0, stream>>>(pos_bf, Wr12t, R12, nullptr,
        2048,2048,1024, 1024,1024,2048, 0,0,0,0,0,0, 1);
    transpose_v<<<dim3(32,1,64), 256, 0, stream>>>(P1, vtb, 2048, 3072, 2048);
    fattn<2048,0><<<dim3(64,64), 512, 0, stream>>>(P1 + 1024LL * 3072, 3072LL, 2048LL * 3072,
        rwb, rrb, P1 + 1024, R12, vtb, selfP, ob, 3072);
    gemm_bt<4,4,0,0><<<dim3(8,32,2), 256, 0, stream>>>(ob, Wo1t, projb, nullptr,
        4096,1024,512, 1024,1024,1024, 0,512, 0,512, 0,PJ2, 1);
    ln_res<<<4096, 256, 0, stream>>>(tgt, projb, projb2, nullptr, ln1g, ln1b, out1_32, out1_bf);

    // ---- layer 2: cross relative attention (K=1024)
    // merged Q2/K2/V2: z=0 -> out1@Wq2 -> qb2; z=1 -> src@Wk2 -> P2k; z=2 -> src@Wv2 -> P2v
    {
        const long long dA = (long long)(src_bf - out1_bf);
        const long long dB1 = (long long)(W2t - Wq2t);
        const long long dB2 = (long long)((W2t + 1048576) - Wq2t);
        const long long dC1 = (long long)(P2k - qb2);
        const long long dC2 = (long long)(P2v - qb2);
        gemm_bt<4,4,1,0><<<dim3(8,32,3), 256, 0, stream>>>(out1_bf, Wq2t, qb2, nullptr,
            4096,1024,1024, 1024,1024,1024, dA,dA, dB1,dB2, dC1,dC2, 2);
    }
    transpose_v<<<dim3(16,1,64), 256, 0, stream>>>(P2v, vtb, 1024, 1024, 0);
    fattn<1024,1><<<dim3(64,64), 512, 0, stream>>>(qb2, 1024LL, 1048576LL,
        rwb, rrb, P2k, R12 + 1024LL * 2048 + 1024, vtb, interP, ob, 1024);
    gemm_bt<4,4,0,0><<<dim3(8,32,2), 256, 0, stream>>>(ob, Wo2t, projb, nullptr,
        4096,1024,512, 1024,1024,1024, 0,512, 0,512, 0,PJ2, 1);
    ln_res<<<4096, 256, 0, stream>>>(out1_32, projb, projb2, nullptr, ln2g, ln2b, out2_32, out2_bf);

    // ---- layer 3: FF
    gemm_bt<4,4,1,2><<<dim3(32,32,1), 256, 0, stream>>>(out2_bf, Wf1t, hb, bf1,
        4096,4096,1024, 1024,1024,4096, 0,0,0,0,0,0, 1);
    gemm_bt<4,4,0,0><<<dim3(8,32,2), 256, 0, stream>>>(hb, Wf2t, projb, nullptr,
        4096,1024,2048, 4096,4096,1024, 0,2048, 0,2048, 0,PJ2, 1);
    ln_res<<<4096, 256, 0, stream>>>(out2_32, projb, projb2, bf2, ln3g, ln3b, outp, nullptr);
}

// Round 9
// 965.071 us; speedup vs baseline: 1.8344x; 1.0068x over previous
//
#include <hip/hip_runtime.h>

typedef unsigned short u16;
typedef __attribute__((ext_vector_type(8))) short short8;
typedef __attribute__((ext_vector_type(4))) float f4;
typedef __attribute__((ext_vector_type(4))) unsigned short u16x4;

__device__ __forceinline__ float b2f(u16 u) {
    unsigned int x = ((unsigned int)u) << 16;
    return __builtin_bit_cast(float, x);
}
__device__ __forceinline__ u16 f2b(float f) {
    unsigned int u = __builtin_bit_cast(unsigned int, f);
    u += 0x7FFFu + ((u >> 16) & 1u);   // round-to-nearest-even
    return (u16)(u >> 16);
}

__device__ __forceinline__ void gl16(const void* g, void* l) {
    __builtin_amdgcn_global_load_lds(
        (const __attribute__((address_space(1))) void*)g,
        (__attribute__((address_space(3))) void*)l, 16, 0, 0);
}

// ---------------------------------------------------------------------------
// bf16 MFMA GEMM, global_load_lds staging + DOUBLE-BUFFERED LDS (T3 2-phase):
//   C[M,N] = A[M,K] @ Bt[N,K]^T  (+bias, +relu)
// Tile 128x128, BK=32, 4 waves (2x2). Per K-step: issue next-tile stage
// FIRST, then ds_read+MFMA current tile, then one barrier (vmcnt drain
// happens after MFMA covered the load latency). CBF: 0 f32-out, 1 bf16-out.
// EPI: 0 none, 1 +bias, 2 +bias+relu. Split-K / multi-source via batch strides.
// ---------------------------------------------------------------------------
template<int FM, int FN, int CBF, int EPI>
__global__ __launch_bounds__(256, 3)
void gemm_bt(const u16* __restrict__ Ap, const u16* __restrict__ Bp,
             void* __restrict__ Cp, const float* __restrict__ bias,
             int M, int N, int K, int lda, int ldb, int ldc,
             long long sAh, long long sAb, long long sBh, long long sBb,
             long long sCh, long long sCb, int batchH)
{
    constexpr int BM = FM * 32;
    constexpr int BN = FN * 32;
    __shared__ __align__(16) u16 As[2][BM * 32];
    __shared__ __align__(16) u16 Bs[2][BN * 32];

    const int tid  = threadIdx.x;
    const int z    = blockIdx.z;
    const int bb   = z / batchH;
    const int hh   = z - bb * batchH;
    const int m0   = blockIdx.y * BM;
    const int n0   = blockIdx.x * BN;
    const int w    = tid >> 6;
    const int lane = tid & 63;
    const int wr   = w >> 1;
    const int wc   = w & 1;
    const int lrow = lane & 15;
    const int lk   = (lane >> 4) << 3;
    const int lrow4 = lane >> 2;
    const int lch   = lane & 3;

    const u16* Ag = Ap + sAb * bb + sAh * hh;
    const u16* Bg = Bp + sBb * bb + sBh * hh;

    f4 acc[FM][FN] = {};

    auto stage = [&](int buf, int kt) {
        const int kb = kt << 5;
        #pragma unroll
        for (int i = 0; i < BM / 64; ++i) {
            const int row0 = (w + i * 4) << 4;
            gl16(Ag + (long long)(m0 + row0 + lrow4) * lda + kb + (lch << 3),
                 &As[buf][row0 * 32]);
        }
        #pragma unroll
        for (int i = 0; i < BN / 64; ++i) {
            const int row0 = (w + i * 4) << 4;
            gl16(Bg + (long long)(n0 + row0 + lrow4) * ldb + kb + (lch << 3),
                 &Bs[buf][row0 * 32]);
        }
    };

    const int nKt = K >> 5;
    stage(0, 0);
    __syncthreads();            // drain prologue stage
    int cur = 0;
    for (int kt = 0; kt < nKt; ++kt) {
        if (kt + 1 < nKt) stage(cur ^ 1, kt + 1);   // issue next tile's loads

        short8 af[FM], bv[FN];
        #pragma unroll
        for (int m = 0; m < FM; ++m)
            af[m] = *(const short8*)(&As[cur][(wr * FM * 16 + m * 16 + lrow) * 32 + lk]);
        #pragma unroll
        for (int n = 0; n < FN; ++n)
            bv[n] = *(const short8*)(&Bs[cur][(wc * FN * 16 + n * 16 + lrow) * 32 + lk]);
        #pragma unroll
        for (int m = 0; m < FM; ++m)
            #pragma unroll
            for (int n = 0; n < FN; ++n)
                acc[m][n] = __builtin_amdgcn_mfma_f32_16x16x32_bf16(af[m], bv[n], acc[m][n], 0, 0, 0);

        __syncthreads();        // one barrier/K-step: drains next-tile loads
        cur ^= 1;
    }

    const int crow0 = m0 + wr * FM * 16 + ((lane >> 4) << 2);
    const int ccol0 = n0 + wc * FN * 16 + lrow;
    if (CBF == 0) {
        float* Cg = (float*)Cp + sCb * bb + sCh * hh;
        #pragma unroll
        for (int m = 0; m < FM; ++m) {
            #pragma unroll
            for (int n = 0; n < FN; ++n) {
                const int col = ccol0 + n * 16;
                float bvv = (EPI >= 1) ? bias[col] : 0.f;
                #pragma unroll
                for (int r = 0; r < 4; ++r) {
                    float vv = acc[m][n][r] + bvv;
                    if (EPI == 2) vv = fmaxf(vv, 0.f);
                    Cg[(long long)(crow0 + m * 16 + r) * ldc + col] = vv;
                }
            }
        }
    } else {
        u16* Cg = (u16*)Cp + sCb * bb + sCh * hh;
        #pragma unroll
        for (int m = 0; m < FM; ++m) {
            #pragma unroll
            for (int n = 0; n < FN; ++n) {
                const int col = ccol0 + n * 16;
                float bvv = (EPI >= 1) ? bias[col] : 0.f;
                #pragma unroll
                for (int r = 0; r < 4; ++r) {
                    float vv = acc[m][n][r] + bvv;
                    if (EPI == 2) vv = fmaxf(vv, 0.f);
                    Cg[(long long)(crow0 + m * 16 + r) * ldc + col] = f2b(vv);
                }
            }
        }
    }
}

// ---------------------------------------------------------------------------
// Fused attention v6 (swapped-operand, wave-interleaved, fused q-bias staging).
// 16 q-rows, 512 threads (8 waves). Tiles round-robin across waves.
// MODE 0: self causal (limit=t+1024), KK=2048. MODE 1: cross, KK=1024.
// ---------------------------------------------------------------------------
template<int KK, int MODE>
__global__ __launch_bounds__(512)
void fattn(const u16* __restrict__ qsrc, long long qld, long long qsb,
           const float* __restrict__ rwb, const float* __restrict__ rrb,
           const u16* __restrict__ kb, const u16* __restrict__ rr,
           const u16* __restrict__ vt,
           float* __restrict__ probs, u16* __restrict__ ob, int kld)
{
    constexpr int LE = KK + 8;
    constexpr int NT = KK / 16;
    __shared__ __align__(16) u16 e[16 * LE];
    __shared__ __align__(16) u16 qws[16 * 72];
    __shared__ __align__(16) u16 qrs[17 * 72];
    __shared__ float psum[8][16];

    const int tid = threadIdx.x;
    const int bh  = blockIdx.y;
    const int b   = bh >> 4, h = bh & 15;
    const int t0  = blockIdx.x << 4;

    // ---- staging: q + bias, scaled 0.125, to LDS
    if (tid < 264) {
        int row, ch; const float* bias; u16* dst; bool act = true;
        if (tid < 128)      { row = tid >> 3;        ch = tid & 7; bias = rwb; dst = &qws[row * 72 + ch * 8]; }
        else if (tid < 256) { row = (tid - 128) >> 3; ch = tid & 7; bias = rrb; dst = &qrs[row * 72 + ch * 8]; }
        else if (MODE == 1) { row = 16;              ch = tid - 256; bias = rrb; dst = &qrs[16 * 72 + ch * 8]; }
        else act = false;
        if (act) {
            int trow = t0 + row; if (trow > 1023) trow = 1023;   // clamp (predicated off)
            short8 qv = *(const short8*)(qsrc + b * qsb + (long long)trow * qld + h * 64 + ch * 8);
            const float* bp = bias + h * 64 + ch * 8;
            f4 b0 = *(const f4*)bp, b1 = *(const f4*)(bp + 4);
            short8 o;
            o[0] = (short)f2b((b2f((u16)qv[0]) + b0.x) * 0.125f);
            o[1] = (short)f2b((b2f((u16)qv[1]) + b0.y) * 0.125f);
            o[2] = (short)f2b((b2f((u16)qv[2]) + b0.z) * 0.125f);
            o[3] = (short)f2b((b2f((u16)qv[3]) + b0.w) * 0.125f);
            o[4] = (short)f2b((b2f((u16)qv[4]) + b1.x) * 0.125f);
            o[5] = (short)f2b((b2f((u16)qv[5]) + b1.y) * 0.125f);
            o[6] = (short)f2b((b2f((u16)qv[6]) + b1.z) * 0.125f);
            o[7] = (short)f2b((b2f((u16)qv[7]) + b1.w) * 0.125f);
            *(short8*)dst = o;
        }
    }
    __syncthreads();

    const int w = tid >> 6, lane = tid & 63;
    const int lc = lane & 15, g = lane >> 4, lk = g << 3;
    const int t = t0 + lc;

    const short8 bq0 = *(const short8*)&qws[lc * 72 + lk];
    const short8 bq1 = *(const short8*)&qws[lc * 72 + 32 + lk];
    const short8 br0 = *(const short8*)&qrs[lc * 72 + lk];
    const short8 br1 = *(const short8*)&qrs[lc * 72 + 32 + lk];
    short8 bs0 = {}, bs1 = {};
    if (MODE == 1) {
        bs0 = *(const short8*)&qrs[(lc + 1) * 72 + lk];
        bs1 = *(const short8*)&qrs[(lc + 1) * 72 + 32 + lk];
    }

    // ---- A0: BD~ pre-shifted write-only (interleaved tiles)
    #pragma unroll 2
    for (int ut = w; ut < NT; ut += 8) {
        const int u0 = ut << 4;
        const bool need1 = (u0 + t0 + 30 >= 1023);
        const bool need2 = (MODE == 1) && (u0 + t0 <= 1021);
        if (!need1 && !need2) continue;
        const u16* rg = rr + (long long)(u0 + lc) * 2048 + h * 64;
        const short8 a0 = *(const short8*)(rg + lk);
        const short8 a1 = *(const short8*)(rg + 32 + lk);
        if (need1) {
            f4 acc = {};
            acc = __builtin_amdgcn_mfma_f32_16x16x32_bf16(a0, br0, acc, 0, 0, 0);
            acc = __builtin_amdgcn_mfma_f32_16x16x32_bf16(a1, br1, acc, 0, 0, 0);
            #pragma unroll
            for (int i = 0; i < 4; ++i) {
                const int j = u0 + 4 * g + i + t - 1023;
                if (j >= 0) e[lc * LE + j] = f2b(acc[i]);
            }
        }
        if (MODE == 1 && need2) {
            f4 acc = {};
            acc = __builtin_amdgcn_mfma_f32_16x16x32_bf16(a0, bs0, acc, 0, 0, 0);
            acc = __builtin_amdgcn_mfma_f32_16x16x32_bf16(a1, bs1, acc, 0, 0, 0);
            #pragma unroll
            for (int i = 0; i < 4; ++i) {
                const int j = u0 + 4 * g + i + t + 2;
                if (j < KK) e[lc * LE + j] = f2b(acc[i]);
            }
        }
    }
    __syncthreads();

    // ---- A1: AC + BD-add + exp + row-sum (interleaved tiles)
    float sum = 0.f;
    const int limit = t + 1024;
    const int jvt = (MODE == 0) ? ((t0 + 1039) >> 4) : (NT - 1);
    #pragma unroll 4
    for (int jt = w; jt < NT; jt += 8) {
        const int j0 = jt << 4;
        const int jme = j0 + 4 * g;
        if (MODE == 0 && jt > jvt) {            // fully masked tile: zero-fill
            u16x4 z = {0, 0, 0, 0};
            *(u16x4*)&e[lc * LE + jme] = z;
            continue;
        }
        const u16* kg = kb + (long long)(b * KK + j0 + lc) * kld + h * 64;
        const short8 a0 = *(const short8*)(kg + lk);
        const short8 a1 = *(const short8*)(kg + 32 + lk);
        f4 acc = {};
        acc = __builtin_amdgcn_mfma_f32_16x16x32_bf16(a0, bq0, acc, 0, 0, 0);
        acc = __builtin_amdgcn_mfma_f32_16x16x32_bf16(a1, bq1, acc, 0, 0, 0);
        u16x4 bd4 = *(const u16x4*)&e[lc * LE + jme];
        u16x4 st;
        #pragma unroll
        for (int i = 0; i < 4; ++i) {
            const int j = jme + i;
            float bd = b2f(bd4[i]);
            if (MODE == 1 && j == t + 1) bd = 0.f;
            float ev = __expf(acc[i] + bd);
            if (MODE == 0 && j > limit) ev = 0.f;
            sum += ev;
            st[i] = f2b(ev);
        }
        *(u16x4*)&e[lc * LE + jme] = st;
    }
    sum += __shfl_xor(sum, 16);
    sum += __shfl_xor(sum, 32);
    if (g == 0) psum[w][lc] = sum;
    __syncthreads();

    if (w >= 4) {
        // ---- B: normalized f32 probs write (waves 4-7), non-temporal
        const int r = (tid >> 4) & 15;
        const int q = tid & 15;
        float s = 0.f;
        #pragma unroll
        for (int w2 = 0; w2 < 8; ++w2) s += psum[w2][r];
        const float inv = 1.f / s;
        float* pr = probs + ((long long)bh * 1024 + t0 + r) * KK;
        #pragma unroll 4
        for (int i2 = 0; i2 < KK / 128; ++i2) {
            const int j0 = q * 8 + i2 * 128;
            u16x4 e0 = *(const u16x4*)&e[r * LE + j0];
            u16x4 e1 = *(const u16x4*)&e[r * LE + j0 + 4];
            f4 p0, p1;
            p0.x = b2f(e0.x) * inv; p0.y = b2f(e0.y) * inv;
            p0.z = b2f(e0.z) * inv; p0.w = b2f(e0.w) * inv;
            p1.x = b2f(e1.x) * inv; p1.y = b2f(e1.y) * inv;
            p1.z = b2f(e1.z) * inv; p1.w = b2f(e1.w) * inv;
            __builtin_nontemporal_store(p0, (f4*)(pr + j0));
            __builtin_nontemporal_store(p1, (f4*)(pr + j0 + 4));
        }
    } else {
        // ---- C: PV (waves 0-3, 16 d-cols each)
        const int db = w << 4;
        const u16* vrow = vt + ((long long)(bh * 64 + db + lc)) * KK + lk;
        int kcend = KK / 32;
        if (MODE == 0) {
            const int ke = (t0 + 1071) >> 5;
            if (ke < kcend) kcend = ke;
        }
        f4 acc = {};
        #pragma unroll 2
        for (int kc = 0; kc < kcend; ++kc) {
            short8 a = *(const short8*)&e[lc * LE + kc * 32 + lk];
            short8 bv = *(const short8*)(vrow + kc * 32);
            acc = __builtin_amdgcn_mfma_f32_16x16x32_bf16(a, bv, acc, 0, 0, 0);
        }
        #pragma unroll
        for (int i = 0; i < 4; ++i) {
            const int trow = g * 4 + i;
            float s = 0.f;
            #pragma unroll
            for (int w2 = 0; w2 < 8; ++w2) s += psum[w2][trow];
            ob[((long long)(b * 1024 + t0 + trow)) * 1024 + h * 64 + db + lc] = f2b(acc[i] / s);
        }
    }
}

// ---------------------------------------------------------------------------
// Elementwise / layout kernels
// ---------------------------------------------------------------------------
__global__ void conv_f2b(const float* __restrict__ in, u16* __restrict__ out, long long n4)
{
    long long i = (long long)blockIdx.x * 256 + threadIdx.x;
    if (i >= n4) return;
    f4 v = *(const f4*)(in + i * 4);
    u16x4 o; o.x = f2b(v.x); o.y = f2b(v.y); o.z = f2b(v.z); o.w = f2b(v.w);
    *(u16x4*)(out + i * 4) = o;
}

__global__ void concat_mem(const float* __restrict__ mem, const float* __restrict__ tgt,
                           float* __restrict__ nm, u16* __restrict__ cat)
{
    long long i = (long long)blockIdx.x * 256 + threadIdx.x;
    long long b = i >> 19;
    int rem = (int)(i & 524287);
    int r = rem >> 8, c4 = rem & 255;
    const float* sp = (r < 1024) ? (mem + ((b << 10) + r) * 1024 + c4 * 4)
                                 : (tgt + ((b << 10) + (r - 1024)) * 1024 + c4 * 4);
    f4 v = *(const f4*)sp;
    __builtin_nontemporal_store(v, (f4*)(nm + i * 4));
    u16x4 o; o.x = f2b(v.x); o.y = f2b(v.y); o.z = f2b(v.z); o.w = f2b(v.w);
    *(u16x4*)(cat + i * 4) = o;
}

struct TWS { const float* s; u16* d; int sld, dld; };
struct TW18 { TWS t[18]; };
__global__ void transpose_w18(TW18 p)
{
    __shared__ float tile[32][33];
    const TWS ts = p.t[blockIdx.z];
    int c0 = blockIdx.x * 32, r0 = blockIdx.y * 32;
    int tx = threadIdx.x, ty = threadIdx.y;
    tile[ty][tx] = ts.s[(long long)(r0 + ty) * ts.sld + c0 + tx];
    __syncthreads();
    ts.d[(long long)(c0 + ty) * ts.dld + r0 + tx] = f2b(tile[tx][ty]);
}

// V^T: vt[(b*16+h)*64+d][j] = v[(b*KK+j)*ld + coff + h*64 + d]
__global__ __launch_bounds__(256) void transpose_v(const u16* __restrict__ v, u16* __restrict__ vt,
                                                   int KK, int ld, int coff)
{
    __shared__ u16 tile[64][68];
    const int z = blockIdx.z, b = z >> 4, h = z & 15;
    const int j0 = blockIdx.x << 6;
    const int rr8 = threadIdx.x >> 3;       // 0..31
    const int c8 = (threadIdx.x & 7) << 3;  // 0,8,..,56
    #pragma unroll
    for (int p = 0; p < 2; ++p) {
        const int jr = p * 32 + rr8;
        short8 val = *(const short8*)(v + ((long long)(b * KK + j0 + jr)) * ld + coff + h * 64 + c8);
        #pragma unroll
        for (int k = 0; k < 8; ++k) tile[c8 + k][jr] = (u16)val[k];
    }
    __syncthreads();
    #pragma unroll
    for (int p = 0; p < 2; ++p) {
        const int d = p * 32 + rr8;
        short8 o;
        #pragma unroll
        for (int k = 0; k < 8; ++k) o[k] = (short)tile[d][c8 + k];
        *(short8*)(vt + ((long long)((b * 16 + h) * 64 + d)) * KK + j0 + c8) = o;
    }
}

// out = LN(x + h1 + h2 + hbias?) * g + bl ; optional bf16 copy.
__global__ __launch_bounds__(256) void ln_res(const float* __restrict__ x,
                                              const float* __restrict__ h1,
                                              const float* __restrict__ h2,
                                              const float* __restrict__ hbias,
                                              const float* __restrict__ g, const float* __restrict__ bl,
                                              float* __restrict__ o32, u16* __restrict__ obf)
{
    const long long row = blockIdx.x;
    const int tid = threadIdx.x;
    const long long base = row * 1024 + tid * 4;
    f4 xa = *(const f4*)(x + base);
    f4 ha = *(const f4*)(h1 + base);
    f4 hb = *(const f4*)(h2 + base);
    f4 hc = {0.f, 0.f, 0.f, 0.f};
    if (hbias) hc = *(const f4*)(hbias + tid * 4);
    float v0 = xa.x + ha.x + hb.x + hc.x, v1 = xa.y + ha.y + hb.y + hc.y;
    float v2 = xa.z + ha.z + hb.z + hc.z, v3 = xa.w + ha.w + hb.w + hc.w;
    float lsum = v0 + v1 + v2 + v3;
    float lsq = v0 * v0 + v1 * v1 + v2 * v2 + v3 * v3;
    #pragma unroll
    for (int o2 = 32; o2; o2 >>= 1) { lsum += __shfl_xor(lsum, o2); lsq += __shfl_xor(lsq, o2); }
    __shared__ float r1[4], r2[4];
    int w = tid >> 6, lane = tid & 63;
    if (lane == 0) { r1[w] = lsum; r2[w] = lsq; }
    __syncthreads();
    lsum = r1[0] + r1[1] + r1[2] + r1[3];
    lsq  = r2[0] + r2[1] + r2[2] + r2[3];
    const float mu = lsum * 0.0009765625f;
    const float var = lsq * 0.0009765625f - mu * mu;
    const float rsd = rsqrtf(var + 1e-5f);
    const int c = tid * 4;
    f4 gv = *(const f4*)(g + c);
    f4 bv = *(const f4*)(bl + c);
    f4 y;
    y.x = (v0 - mu) * rsd * gv.x + bv.x;
    y.y = (v1 - mu) * rsd * gv.y + bv.y;
    y.z = (v2 - mu) * rsd * gv.z + bv.z;
    y.w = (v3 - mu) * rsd * gv.w + bv.w;
    *(f4*)(o32 + base) = y;
    if (obf) {
        u16x4 u; u.x = f2b(y.x); u.y = f2b(y.y); u.z = f2b(y.z); u.w = f2b(y.w);
        *(u16x4*)(obf + base) = u;
    }
}

// ---------------------------------------------------------------------------
extern "C" void kernel_launch(void* const* d_in, const int* in_sizes, int n_in,
                              void* d_out, int out_size, void* d_ws, size_t ws_size,
                              hipStream_t stream)
{
    (void)in_sizes; (void)n_in; (void)out_size;
    const float* src  = (const float*)d_in[0];
    const float* tgt  = (const float*)d_in[1];
    const float* mem  = (const float*)d_in[2];
    const float* pos  = (const float*)d_in[3];
    const float* rwb  = (const float*)d_in[4];
    const float* rrb  = (const float*)d_in[5];
    const float* Wq1  = (const float*)d_in[6];
    const float* Wk1  = (const float*)d_in[7];
    const float* Wv1  = (const float*)d_in[8];
    const float* Wr1  = (const float*)d_in[9];
    const float* Wo1  = (const float*)d_in[10];
    const float* ln1g = (const float*)d_in[11];
    const float* ln1b = (const float*)d_in[12];
    const float* Wq2  = (const float*)d_in[13];
    const float* Wk2  = (const float*)d_in[14];
    const float* Wv2  = (const float*)d_in[15];
    const float* Wr2  = (const float*)d_in[16];
    const float* Wo2  = (const float*)d_in[17];
    const float* ln2g = (const float*)d_in[18];
    const float* ln2b = (const float*)d_in[19];
    const float* Wf1  = (const float*)d_in[20];
    const float* bf1  = (const float*)d_in[21];
    const float* Wf2  = (const float*)d_in[22];
    const float* bf2  = (const float*)d_in[23];
    const float* ln3g = (const float*)d_in[24];
    const float* ln3b = (const float*)d_in[25];

    float* outp   = (float*)d_out;            // [4,1024,1024]
    float* newmem = outp + 4194304;           // [4,2048,1024]
    float* selfP  = outp + 12582912;          // [4,16,1024,2048]
    float* interP = outp + 146800640;         // [4,16,1024,1024]

    char* ws = (char*)d_ws;
    size_t off = 0;
    auto alloc = [&](size_t bytes) -> void* {
        void* p = ws + off;
        off = (off + bytes + 255) & ~(size_t)255;
        return p;
    };
    u16*   src_bf  = (u16*)alloc(8u << 20);       // [4096][1024]
    u16*   cat_bf  = (u16*)alloc(16u << 20);      // [8192][1024]
    u16*   pos_bf  = (u16*)alloc(4u << 20);       // [2048][1024]
    u16*   W1t    = (u16*)alloc(6u << 20);        // [3072][1024]  Wq1|Wk1|Wv1 ^T
    u16*   Wr12t  = (u16*)alloc(4u << 20);        // [2048][1024]  Wr1|Wr2 ^T
    u16*   W2t    = (u16*)alloc(4u << 20);        // [2048][1024]  Wk2|Wv2 ^T
    u16*   Wq2t   = (u16*)alloc(2u << 20);
    u16*   Wo1t   = (u16*)alloc(2u << 20);
    u16*   Wo2t   = (u16*)alloc(2u << 20);
    u16*   Wf1t   = (u16*)alloc(8u << 20);
    u16*   Wf2t   = (u16*)alloc(8u << 20);
    u16*   P1     = (u16*)alloc(48u << 20);       // [8192][3072]  Q|K|V self
    u16*   P2k    = (u16*)alloc(8u << 20);        // [4096][1024]  K cross
    u16*   P2v    = (u16*)alloc(8u << 20);        // [4096][1024]  V cross
    u16*   R12    = (u16*)alloc(8u << 20);        // [2048][2048]  r1 | r2
    u16*   qb2    = (u16*)alloc(8u << 20);        // cross Q proj
    u16*   vtb    = (u16*)alloc(16u << 20);       // V^T (reused both layers)
    u16*   ob     = (u16*)alloc(8u << 20);
    float* projb  = (float*)alloc(16u << 20);
    float* projb2 = (float*)alloc(16u << 20);
    float* out1_32 = (float*)alloc(16u << 20);
    u16*   out1_bf = (u16*)alloc(8u << 20);
    float* out2_32 = (float*)alloc(16u << 20);
    u16*   out2_bf = (u16*)alloc(8u << 20);
    u16*   hb     = (u16*)alloc(32u << 20);       // [4096][4096]
    if (off > ws_size) return;
    const long long PJ2 = projb2 - projb;

    dim3 tb(32, 32);

    // ---- phase 0: conversions / transposes / new_mem
    concat_mem<<<8192, 256, 0, stream>>>(mem, tgt, newmem, cat_bf);
    conv_f2b<<<4096, 256, 0, stream>>>(src, src_bf, 1048576);
    conv_f2b<<<2048, 256, 0, stream>>>(pos, pos_bf, 524288);
    TW18 tw;
    tw.t[0] = {Wq1, W1t, 1024, 1024};
    tw.t[1] = {Wk1, W1t + 1048576, 1024, 1024};
    tw.t[2] = {Wv1, W1t + 2097152, 1024, 1024};
    tw.t[3] = {Wr1, Wr12t, 1024, 1024};
    tw.t[4] = {Wr2, Wr12t + 1048576, 1024, 1024};
    tw.t[5] = {Wk2, W2t, 1024, 1024};
    tw.t[6] = {Wv2, W2t + 1048576, 1024, 1024};
    tw.t[7] = {Wq2, Wq2t, 1024, 1024};
    tw.t[8] = {Wo1, Wo1t, 1024, 1024};
    tw.t[9] = {Wo2, Wo2t, 1024, 1024};
    for (int zz = 0; zz < 4; ++zz) {
        tw.t[10 + zz] = {Wf1 + zz * 1024, Wf1t + (long long)zz * 1048576, 4096, 1024};
        tw.t[14 + zz] = {Wf2 + (long long)zz * 1048576, Wf2t + zz * 1024, 1024, 4096};
    }
    transpose_w18<<<dim3(32, 32, 18), tb, 0, stream>>>(tw);

    // ---- layer 1: self relative attention (K=2048)
    gemm_bt<4,4,1,0><<<dim3(24,64,1), 256, 0, stream>>>(cat_bf, W1t, P1, nullptr,
        8192,3072,1024, 1024,1024,3072, 0,0,0,0,0,0, 1);
    gemm_bt<4,4,1,0><<<dim3(16,16,1), 256, 0, stream>>>(pos_bf, Wr12t, R12, nullptr,
        2048,2048,1024, 1024,1024,2048, 0,0,0,0,0,0, 1);
    transpose_v<<<dim3(32,1,64), 256, 0, stream>>>(P1, vtb, 2048, 3072, 2048);
    fattn<2048,0><<<dim3(64,64), 512, 0, stream>>>(P1 + 1024LL * 3072, 3072LL, 2048LL * 3072,
        rwb, rrb, P1 + 1024, R12, vtb, selfP, ob, 3072);
    gemm_bt<4,4,0,0><<<dim3(8,32,2), 256, 0, stream>>>(ob, Wo1t, projb, nullptr,
        4096,1024,512, 1024,1024,1024, 0,512, 0,512, 0,PJ2, 1);
    ln_res<<<4096, 256, 0, stream>>>(tgt, projb, projb2, nullptr, ln1g, ln1b, out1_32, out1_bf);

    // ---- layer 2: cross relative attention (K=1024)
    {
        const long long dA = (long long)(src_bf - out1_bf);
        const long long dB1 = (long long)(W2t - Wq2t);
        const long long dB2 = (long long)((W2t + 1048576) - Wq2t);
        const long long dC1 = (long long)(P2k - qb2);
        const long long dC2 = (long long)(P2v - qb2);
        gemm_bt<4,4,1,0><<<dim3(8,32,3), 256, 0, stream>>>(out1_bf, Wq2t, qb2, nullptr,
            4096,1024,1024, 1024,1024,1024, dA,dA, dB1,dB2, dC1,dC2, 2);
    }
    transpose_v<<<dim3(16,1,64), 256, 0, stream>>>(P2v, vtb, 1024, 1024, 0);
    fattn<1024,1><<<dim3(64,64), 512, 0, stream>>>(qb2, 1024LL, 1048576LL,
        rwb, rrb, P2k, R12 + 1024LL * 2048 + 1024, vtb, interP, ob, 1024);
    gemm_bt<4,4,0,0><<<dim3(8,32,2), 256, 0, stream>>>(ob, Wo2t, projb, nullptr,
        4096,1024,512, 1024,1024,1024, 0,512, 0,512, 0,PJ2, 1);
    ln_res<<<4096, 256, 0, stream>>>(out1_32, projb, projb2, nullptr, ln2g, ln2b, out2_32, out2_bf);

    // ---- layer 3: FF
    gemm_bt<4,4,1,2><<<dim3(32,32,1), 256, 0, stream>>>(out2_bf, Wf1t, hb, bf1,
        4096,4096,1024, 1024,1024,4096, 0,0,0,0,0,0, 1);
    gemm_bt<4,4,0,0><<<dim3(8,32,2), 256, 0, stream>>>(hb, Wf2t, projb, nullptr,
        4096,1024,2048, 4096,4096,1024, 0,2048, 0,2048, 0,PJ2, 1);
    ln_res<<<4096, 256, 0, stream>>>(out2_32, projb, projb2, bf2, ln3g, ln3b, outp, nullptr);
}

// Round 10
// 928.275 us; speedup vs baseline: 1.9072x; 1.0396x over previous
//
#include <hip/hip_runtime.h>

typedef unsigned short u16;
typedef __attribute__((ext_vector_type(8))) short short8;
typedef __attribute__((ext_vector_type(4))) float f4;
typedef __attribute__((ext_vector_type(4))) unsigned short u16x4;

__device__ __forceinline__ float b2f(u16 u) {
    unsigned int x = ((unsigned int)u) << 16;
    return __builtin_bit_cast(float, x);
}
__device__ __forceinline__ u16 f2b(float f) {
    unsigned int u = __builtin_bit_cast(unsigned int, f);
    u += 0x7FFFu + ((u >> 16) & 1u);   // round-to-nearest-even
    return (u16)(u >> 16);
}

__device__ __forceinline__ void gl16(const void* g, void* l) {
    __builtin_amdgcn_global_load_lds(
        (const __attribute__((address_space(1))) void*)g,
        (__attribute__((address_space(3))) void*)l, 16, 0, 0);
}

// ---------------------------------------------------------------------------
// bf16 MFMA GEMM, global_load_lds staging + double-buffered LDS:
//   C[M,N] = A[M,K] @ Bt[N,K]^T  (+bias, +relu)
// Tile 128x128, BK=32, 4 waves (2x2). CBF: 0 f32-out, 1 bf16-out.
// EPI: 0 none, 1 +bias, 2 +bias+relu. Split-K / multi-source via batch strides.
// ---------------------------------------------------------------------------
template<int FM, int FN, int CBF, int EPI>
__global__ __launch_bounds__(256, 3)
void gemm_bt(const u16* __restrict__ Ap, const u16* __restrict__ Bp,
             void* __restrict__ Cp, const float* __restrict__ bias,
             int M, int N, int K, int lda, int ldb, int ldc,
             long long sAh, long long sAb, long long sBh, long long sBb,
             long long sCh, long long sCb, int batchH)
{
    constexpr int BM = FM * 32;
    constexpr int BN = FN * 32;
    __shared__ __align__(16) u16 As[2][BM * 32];
    __shared__ __align__(16) u16 Bs[2][BN * 32];

    const int tid  = threadIdx.x;
    const int z    = blockIdx.z;
    const int bb   = z / batchH;
    const int hh   = z - bb * batchH;
    const int m0   = blockIdx.y * BM;
    const int n0   = blockIdx.x * BN;
    const int w    = tid >> 6;
    const int lane = tid & 63;
    const int wr   = w >> 1;
    const int wc   = w & 1;
    const int lrow = lane & 15;
    const int lk   = (lane >> 4) << 3;
    const int lrow4 = lane >> 2;
    const int lch   = lane & 3;

    const u16* Ag = Ap + sAb * bb + sAh * hh;
    const u16* Bg = Bp + sBb * bb + sBh * hh;

    f4 acc[FM][FN] = {};

    auto stage = [&](int buf, int kt) {
        const int kb = kt << 5;
        #pragma unroll
        for (int i = 0; i < BM / 64; ++i) {
            const int row0 = (w + i * 4) << 4;
            gl16(Ag + (long long)(m0 + row0 + lrow4) * lda + kb + (lch << 3),
                 &As[buf][row0 * 32]);
        }
        #pragma unroll
        for (int i = 0; i < BN / 64; ++i) {
            const int row0 = (w + i * 4) << 4;
            gl16(Bg + (long long)(n0 + row0 + lrow4) * ldb + kb + (lch << 3),
                 &Bs[buf][row0 * 32]);
        }
    };

    const int nKt = K >> 5;
    stage(0, 0);
    __syncthreads();
    int cur = 0;
    for (int kt = 0; kt < nKt; ++kt) {
        if (kt + 1 < nKt) stage(cur ^ 1, kt + 1);

        short8 af[FM], bv[FN];
        #pragma unroll
        for (int m = 0; m < FM; ++m)
            af[m] = *(const short8*)(&As[cur][(wr * FM * 16 + m * 16 + lrow) * 32 + lk]);
        #pragma unroll
        for (int n = 0; n < FN; ++n)
            bv[n] = *(const short8*)(&Bs[cur][(wc * FN * 16 + n * 16 + lrow) * 32 + lk]);
        #pragma unroll
        for (int m = 0; m < FM; ++m)
            #pragma unroll
            for (int n = 0; n < FN; ++n)
                acc[m][n] = __builtin_amdgcn_mfma_f32_16x16x32_bf16(af[m], bv[n], acc[m][n], 0, 0, 0);

        __syncthreads();
        cur ^= 1;
    }

    const int crow0 = m0 + wr * FM * 16 + ((lane >> 4) << 2);
    const int ccol0 = n0 + wc * FN * 16 + lrow;
    if (CBF == 0) {
        float* Cg = (float*)Cp + sCb * bb + sCh * hh;
        #pragma unroll
        for (int m = 0; m < FM; ++m) {
            #pragma unroll
            for (int n = 0; n < FN; ++n) {
                const int col = ccol0 + n * 16;
                float bvv = (EPI >= 1) ? bias[col] : 0.f;
                #pragma unroll
                for (int r = 0; r < 4; ++r) {
                    float vv = acc[m][n][r] + bvv;
                    if (EPI == 2) vv = fmaxf(vv, 0.f);
                    Cg[(long long)(crow0 + m * 16 + r) * ldc + col] = vv;
                }
            }
        }
    } else {
        u16* Cg = (u16*)Cp + sCb * bb + sCh * hh;
        #pragma unroll
        for (int m = 0; m < FM; ++m) {
            #pragma unroll
            for (int n = 0; n < FN; ++n) {
                const int col = ccol0 + n * 16;
                float bvv = (EPI >= 1) ? bias[col] : 0.f;
                #pragma unroll
                for (int r = 0; r < 4; ++r) {
                    float vv = acc[m][n][r] + bvv;
                    if (EPI == 2) vv = fmaxf(vv, 0.f);
                    Cg[(long long)(crow0 + m * 16 + r) * ldc + col] = f2b(vv);
                }
            }
        }
    }
}

// ---------------------------------------------------------------------------
// Fused attention v7: swapped-operand + wave-interleaved + BATCH-LOADED
// gathers (explicit 4-deep MLP in A1, 2-deep in A0 — loads issue before any
// LDS/branch so latency overlaps). 16 q-rows, 512 threads (8 waves).
// MODE 0: self causal (limit=t+1024), KK=2048. MODE 1: cross, KK=1024.
// ---------------------------------------------------------------------------
template<int KK, int MODE>
__global__ __launch_bounds__(512, 4)
void fattn(const u16* __restrict__ qsrc, long long qld, long long qsb,
           const float* __restrict__ rwb, const float* __restrict__ rrb,
           const u16* __restrict__ kb, const u16* __restrict__ rr,
           const u16* __restrict__ vt,
           float* __restrict__ probs, u16* __restrict__ ob, int kld)
{
    constexpr int LE = KK + 8;
    constexpr int NT = KK / 16;
    constexpr int NI = NT / 8;          // tiles per wave (16 self, 8 cross)
    __shared__ __align__(16) u16 e[16 * LE];
    __shared__ __align__(16) u16 qws[16 * 72];
    __shared__ __align__(16) u16 qrs[17 * 72];
    __shared__ float psum[8][16];

    const int tid = threadIdx.x;
    const int bh  = blockIdx.y;
    const int b   = bh >> 4, h = bh & 15;
    const int t0  = blockIdx.x << 4;

    // ---- staging: q + bias, scaled 0.125, to LDS
    if (tid < 264) {
        int row, ch; const float* bias; u16* dst; bool act = true;
        if (tid < 128)      { row = tid >> 3;        ch = tid & 7; bias = rwb; dst = &qws[row * 72 + ch * 8]; }
        else if (tid < 256) { row = (tid - 128) >> 3; ch = tid & 7; bias = rrb; dst = &qrs[row * 72 + ch * 8]; }
        else if (MODE == 1) { row = 16;              ch = tid - 256; bias = rrb; dst = &qrs[16 * 72 + ch * 8]; }
        else act = false;
        if (act) {
            int trow = t0 + row; if (trow > 1023) trow = 1023;
            short8 qv = *(const short8*)(qsrc + b * qsb + (long long)trow * qld + h * 64 + ch * 8);
            const float* bp = bias + h * 64 + ch * 8;
            f4 b0 = *(const f4*)bp, b1 = *(const f4*)(bp + 4);
            short8 o;
            o[0] = (short)f2b((b2f((u16)qv[0]) + b0.x) * 0.125f);
            o[1] = (short)f2b((b2f((u16)qv[1]) + b0.y) * 0.125f);
            o[2] = (short)f2b((b2f((u16)qv[2]) + b0.z) * 0.125f);
            o[3] = (short)f2b((b2f((u16)qv[3]) + b0.w) * 0.125f);
            o[4] = (short)f2b((b2f((u16)qv[4]) + b1.x) * 0.125f);
            o[5] = (short)f2b((b2f((u16)qv[5]) + b1.y) * 0.125f);
            o[6] = (short)f2b((b2f((u16)qv[6]) + b1.z) * 0.125f);
            o[7] = (short)f2b((b2f((u16)qv[7]) + b1.w) * 0.125f);
            *(short8*)dst = o;
        }
    }
    __syncthreads();

    const int w = tid >> 6, lane = tid & 63;
    const int lc = lane & 15, g = lane >> 4, lk = g << 3;
    const int t = t0 + lc;

    const short8 bq0 = *(const short8*)&qws[lc * 72 + lk];
    const short8 bq1 = *(const short8*)&qws[lc * 72 + 32 + lk];
    const short8 br0 = *(const short8*)&qrs[lc * 72 + lk];
    const short8 br1 = *(const short8*)&qrs[lc * 72 + 32 + lk];
    short8 bs0 = {}, bs1 = {};
    if (MODE == 1) {
        bs0 = *(const short8*)&qrs[(lc + 1) * 72 + lk];
        bs1 = *(const short8*)&qrs[(lc + 1) * 72 + 32 + lk];
    }

    // ---- A0: BD~ pre-shifted write-only; 2-deep batched R-gathers
    #pragma unroll
    for (int Bb = 0; Bb < NI; Bb += 2) {
        short8 R0[2], R1[2];
        #pragma unroll
        for (int u = 0; u < 2; ++u) {
            const int ut = w + (Bb + u) * 8;
            const int u0 = ut << 4;
            const bool nd = (u0 + t0 + 30 >= 1023) || (MODE == 1 && u0 + t0 <= 1021);
            if (nd) {
                const u16* rg = rr + (long long)(u0 + lc) * 2048 + h * 64;
                R0[u] = *(const short8*)(rg + lk);
                R1[u] = *(const short8*)(rg + 32 + lk);
            }
        }
        #pragma unroll
        for (int u = 0; u < 2; ++u) {
            const int ut = w + (Bb + u) * 8;
            const int u0 = ut << 4;
            const bool need1 = (u0 + t0 + 30 >= 1023);
            const bool need2 = (MODE == 1) && (u0 + t0 <= 1021);
            if (need1) {
                f4 acc = {};
                acc = __builtin_amdgcn_mfma_f32_16x16x32_bf16(R0[u], br0, acc, 0, 0, 0);
                acc = __builtin_amdgcn_mfma_f32_16x16x32_bf16(R1[u], br1, acc, 0, 0, 0);
                #pragma unroll
                for (int i = 0; i < 4; ++i) {
                    const int j = u0 + 4 * g + i + t - 1023;
                    if (j >= 0) e[lc * LE + j] = f2b(acc[i]);
                }
            }
            if (MODE == 1 && need2) {
                f4 acc = {};
                acc = __builtin_amdgcn_mfma_f32_16x16x32_bf16(R0[u], bs0, acc, 0, 0, 0);
                acc = __builtin_amdgcn_mfma_f32_16x16x32_bf16(R1[u], bs1, acc, 0, 0, 0);
                #pragma unroll
                for (int i = 0; i < 4; ++i) {
                    const int j = u0 + 4 * g + i + t + 2;
                    if (j < KK) e[lc * LE + j] = f2b(acc[i]);
                }
            }
        }
    }
    __syncthreads();

    // ---- A1: AC + BD-add + exp + row-sum; 4-deep batched K-gathers
    float sum = 0.f;
    const int limit = t + 1024;
    const int jvt = (MODE == 0) ? ((t0 + 1039) >> 4) : (NT - 1);
    #pragma unroll
    for (int Bb = 0; Bb < NI; Bb += 4) {
        short8 K0[4], K1[4];
        #pragma unroll
        for (int u = 0; u < 4; ++u) {
            const int jt = w + (Bb + u) * 8;
            if (MODE != 0 || jt <= jvt) {
                const u16* kg = kb + (long long)(b * KK + (jt << 4) + lc) * kld + h * 64;
                K0[u] = *(const short8*)(kg + lk);
                K1[u] = *(const short8*)(kg + 32 + lk);
            }
        }
        #pragma unroll
        for (int u = 0; u < 4; ++u) {
            const int jt = w + (Bb + u) * 8;
            const int jme = (jt << 4) + 4 * g;
            if (MODE == 0 && jt > jvt) {
                u16x4 z = {0, 0, 0, 0};
                *(u16x4*)&e[lc * LE + jme] = z;
            } else {
                f4 acc = {};
                acc = __builtin_amdgcn_mfma_f32_16x16x32_bf16(K0[u], bq0, acc, 0, 0, 0);
                acc = __builtin_amdgcn_mfma_f32_16x16x32_bf16(K1[u], bq1, acc, 0, 0, 0);
                u16x4 bd4 = *(const u16x4*)&e[lc * LE + jme];
                u16x4 st;
                #pragma unroll
                for (int i = 0; i < 4; ++i) {
                    const int j = jme + i;
                    float bd = b2f(bd4[i]);
                    if (MODE == 1 && j == t + 1) bd = 0.f;
                    float ev = __expf(acc[i] + bd);
                    if (MODE == 0 && j > limit) ev = 0.f;
                    sum += ev;
                    st[i] = f2b(ev);
                }
                *(u16x4*)&e[lc * LE + jme] = st;
            }
        }
    }
    sum += __shfl_xor(sum, 16);
    sum += __shfl_xor(sum, 32);
    if (g == 0) psum[w][lc] = sum;
    __syncthreads();

    if (w >= 4) {
        // ---- B: normalized f32 probs write (waves 4-7), non-temporal
        const int r = (tid >> 4) & 15;
        const int q = tid & 15;
        float s = 0.f;
        #pragma unroll
        for (int w2 = 0; w2 < 8; ++w2) s += psum[w2][r];
        const float inv = 1.f / s;
        float* pr = probs + ((long long)bh * 1024 + t0 + r) * KK;
        #pragma unroll 4
        for (int i2 = 0; i2 < KK / 128; ++i2) {
            const int j0 = q * 8 + i2 * 128;
            u16x4 e0 = *(const u16x4*)&e[r * LE + j0];
            u16x4 e1 = *(const u16x4*)&e[r * LE + j0 + 4];
            f4 p0, p1;
            p0.x = b2f(e0.x) * inv; p0.y = b2f(e0.y) * inv;
            p0.z = b2f(e0.z) * inv; p0.w = b2f(e0.w) * inv;
            p1.x = b2f(e1.x) * inv; p1.y = b2f(e1.y) * inv;
            p1.z = b2f(e1.z) * inv; p1.w = b2f(e1.w) * inv;
            __builtin_nontemporal_store(p0, (f4*)(pr + j0));
            __builtin_nontemporal_store(p1, (f4*)(pr + j0 + 4));
        }
    } else {
        // ---- C: PV (waves 0-3, 16 d-cols each)
        const int db = w << 4;
        const u16* vrow = vt + ((long long)(bh * 64 + db + lc)) * KK + lk;
        int kcend = KK / 32;
        if (MODE == 0) {
            const int ke = (t0 + 1071) >> 5;
            if (ke < kcend) kcend = ke;
        }
        f4 acc = {};
        #pragma unroll 2
        for (int kc = 0; kc < kcend; ++kc) {
            short8 a = *(const short8*)&e[lc * LE + kc * 32 + lk];
            short8 bv = *(const short8*)(vrow + kc * 32);
            acc = __builtin_amdgcn_mfma_f32_16x16x32_bf16(a, bv, acc, 0, 0, 0);
        }
        #pragma unroll
        for (int i = 0; i < 4; ++i) {
            const int trow = g * 4 + i;
            float s = 0.f;
            #pragma unroll
            for (int w2 = 0; w2 < 8; ++w2) s += psum[w2][trow];
            ob[((long long)(b * 1024 + t0 + trow)) * 1024 + h * 64 + db + lc] = f2b(acc[i] / s);
        }
    }
}

// ---------------------------------------------------------------------------
// Elementwise / layout kernels
// ---------------------------------------------------------------------------
__global__ void conv_f2b(const float* __restrict__ in, u16* __restrict__ out, long long n4)
{
    long long i = (long long)blockIdx.x * 256 + threadIdx.x;
    if (i >= n4) return;
    f4 v = *(const f4*)(in + i * 4);
    u16x4 o; o.x = f2b(v.x); o.y = f2b(v.y); o.z = f2b(v.z); o.w = f2b(v.w);
    *(u16x4*)(out + i * 4) = o;
}

__global__ void concat_mem(const float* __restrict__ mem, const float* __restrict__ tgt,
                           float* __restrict__ nm, u16* __restrict__ cat)
{
    long long i = (long long)blockIdx.x * 256 + threadIdx.x;
    long long b = i >> 19;
    int rem = (int)(i & 524287);
    int r = rem >> 8, c4 = rem & 255;
    const float* sp = (r < 1024) ? (mem + ((b << 10) + r) * 1024 + c4 * 4)
                                 : (tgt + ((b << 10) + (r - 1024)) * 1024 + c4 * 4);
    f4 v = *(const f4*)sp;
    __builtin_nontemporal_store(v, (f4*)(nm + i * 4));
    u16x4 o; o.x = f2b(v.x); o.y = f2b(v.y); o.z = f2b(v.z); o.w = f2b(v.w);
    *(u16x4*)(cat + i * 4) = o;
}

struct TWS { const float* s; u16* d; int sld, dld; };
struct TW18 { TWS t[18]; };
__global__ void transpose_w18(TW18 p)
{
    __shared__ float tile[32][33];
    const TWS ts = p.t[blockIdx.z];
    int c0 = blockIdx.x * 32, r0 = blockIdx.y * 32;
    int tx = threadIdx.x, ty = threadIdx.y;
    tile[ty][tx] = ts.s[(long long)(r0 + ty) * ts.sld + c0 + tx];
    __syncthreads();
    ts.d[(long long)(c0 + ty) * ts.dld + r0 + tx] = f2b(tile[tx][ty]);
}

// V^T: vt[(b*16+h)*64+d][j] = v[(b*KK+j)*ld + coff + h*64 + d]
__global__ __launch_bounds__(256) void transpose_v(const u16* __restrict__ v, u16* __restrict__ vt,
                                                   int KK, int ld, int coff)
{
    __shared__ u16 tile[64][68];
    const int z = blockIdx.z, b = z >> 4, h = z & 15;
    const int j0 = blockIdx.x << 6;
    const int rr8 = threadIdx.x >> 3;
    const int c8 = (threadIdx.x & 7) << 3;
    #pragma unroll
    for (int p = 0; p < 2; ++p) {
        const int jr = p * 32 + rr8;
        short8 val = *(const short8*)(v + ((long long)(b * KK + j0 + jr)) * ld + coff + h * 64 + c8);
        #pragma unroll
        for (int k = 0; k < 8; ++k) tile[c8 + k][jr] = (u16)val[k];
    }
    __syncthreads();
    #pragma unroll
    for (int p = 0; p < 2; ++p) {
        const int d = p * 32 + rr8;
        short8 o;
        #pragma unroll
        for (int k = 0; k < 8; ++k) o[k] = (short)tile[d][c8 + k];
        *(short8*)(vt + ((long long)((b * 16 + h) * 64 + d)) * KK + j0 + c8) = o;
    }
}

// out = LN(x + h1 + h2 + hbias?) * g + bl ; optional bf16 copy.
__global__ __launch_bounds__(256) void ln_res(const float* __restrict__ x,
                                              const float* __restrict__ h1,
                                              const float* __restrict__ h2,
                                              const float* __restrict__ hbias,
                                              const float* __restrict__ g, const float* __restrict__ bl,
                                              float* __restrict__ o32, u16* __restrict__ obf)
{
    const long long row = blockIdx.x;
    const int tid = threadIdx.x;
    const long long base = row * 1024 + tid * 4;
    f4 xa = *(const f4*)(x + base);
    f4 ha = *(const f4*)(h1 + base);
    f4 hb = *(const f4*)(h2 + base);
    f4 hc = {0.f, 0.f, 0.f, 0.f};
    if (hbias) hc = *(const f4*)(hbias + tid * 4);
    float v0 = xa.x + ha.x + hb.x + hc.x, v1 = xa.y + ha.y + hb.y + hc.y;
    float v2 = xa.z + ha.z + hb.z + hc.z, v3 = xa.w + ha.w + hb.w + hc.w;
    float lsum = v0 + v1 + v2 + v3;
    float lsq = v0 * v0 + v1 * v1 + v2 * v2 + v3 * v3;
    #pragma unroll
    for (int o2 = 32; o2; o2 >>= 1) { lsum += __shfl_xor(lsum, o2); lsq += __shfl_xor(lsq, o2); }
    __shared__ float r1[4], r2[4];
    int w = tid >> 6, lane = tid & 63;
    if (lane == 0) { r1[w] = lsum; r2[w] = lsq; }
    __syncthreads();
    lsum = r1[0] + r1[1] + r1[2] + r1[3];
    lsq  = r2[0] + r2[1] + r2[2] + r2[3];
    const float mu = lsum * 0.0009765625f;
    const float var = lsq * 0.0009765625f - mu * mu;
    const float rsd = rsqrtf(var + 1e-5f);
    const int c = tid * 4;
    f4 gv = *(const f4*)(g + c);
    f4 bv = *(const f4*)(bl + c);
    f4 y;
    y.x = (v0 - mu) * rsd * gv.x + bv.x;
    y.y = (v1 - mu) * rsd * gv.y + bv.y;
    y.z = (v2 - mu) * rsd * gv.z + bv.z;
    y.w = (v3 - mu) * rsd * gv.w + bv.w;
    *(f4*)(o32 + base) = y;
    if (obf) {
        u16x4 u; u.x = f2b(y.x); u.y = f2b(y.y); u.z = f2b(y.z); u.w = f2b(y.w);
        *(u16x4*)(obf + base) = u;
    }
}

// ---------------------------------------------------------------------------
extern "C" void kernel_launch(void* const* d_in, const int* in_sizes, int n_in,
                              void* d_out, int out_size, void* d_ws, size_t ws_size,
                              hipStream_t stream)
{
    (void)in_sizes; (void)n_in; (void)out_size;
    const float* src  = (const float*)d_in[0];
    const float* tgt  = (const float*)d_in[1];
    const float* mem  = (const float*)d_in[2];
    const float* pos  = (const float*)d_in[3];
    const float* rwb  = (const float*)d_in[4];
    const float* rrb  = (const float*)d_in[5];
    const float* Wq1  = (const float*)d_in[6];
    const float* Wk1  = (const float*)d_in[7];
    const float* Wv1  = (const float*)d_in[8];
    const float* Wr1  = (const float*)d_in[9];
    const float* Wo1  = (const float*)d_in[10];
    const float* ln1g = (const float*)d_in[11];
    const float* ln1b = (const float*)d_in[12];
    const float* Wq2  = (const float*)d_in[13];
    const float* Wk2  = (const float*)d_in[14];
    const float* Wv2  = (const float*)d_in[15];
    const float* Wr2  = (const float*)d_in[16];
    const float* Wo2  = (const float*)d_in[17];
    const float* ln2g = (const float*)d_in[18];
    const float* ln2b = (const float*)d_in[19];
    const float* Wf1  = (const float*)d_in[20];
    const float* bf1  = (const float*)d_in[21];
    const float* Wf2  = (const float*)d_in[22];
    const float* bf2  = (const float*)d_in[23];
    const float* ln3g = (const float*)d_in[24];
    const float* ln3b = (const float*)d_in[25];

    float* outp   = (float*)d_out;            // [4,1024,1024]
    float* newmem = outp + 4194304;           // [4,2048,1024]
    float* selfP  = outp + 12582912;          // [4,16,1024,2048]
    float* interP = outp + 146800640;         // [4,16,1024,1024]

    char* ws = (char*)d_ws;
    size_t off = 0;
    auto alloc = [&](size_t bytes) -> void* {
        void* p = ws + off;
        off = (off + bytes + 255) & ~(size_t)255;
        return p;
    };
    u16*   src_bf  = (u16*)alloc(8u << 20);       // [4096][1024]
    u16*   cat_bf  = (u16*)alloc(16u << 20);      // [8192][1024]
    u16*   pos_bf  = (u16*)alloc(4u << 20);       // [2048][1024]
    u16*   W1t    = (u16*)alloc(6u << 20);        // [3072][1024]  Wq1|Wk1|Wv1 ^T
    u16*   Wr12t  = (u16*)alloc(4u << 20);        // [2048][1024]  Wr1|Wr2 ^T
    u16*   W2t    = (u16*)alloc(4u << 20);        // [2048][1024]  Wk2|Wv2 ^T
    u16*   Wq2t   = (u16*)alloc(2u << 20);
    u16*   Wo1t   = (u16*)alloc(2u << 20);
    u16*   Wo2t   = (u16*)alloc(2u << 20);
    u16*   Wf1t   = (u16*)alloc(8u << 20);
    u16*   Wf2t   = (u16*)alloc(8u << 20);
    u16*   P1kv   = (u16*)alloc(34u << 20);       // [8192][2080]  K|V self (ld 2080)
    u16*   qb1    = (u16*)alloc(8u << 20);        // [4096][1024]  Q self (tgt rows)
    u16*   P2k    = (u16*)alloc(8u << 20);        // [4096][1024]  K cross
    u16*   P2v    = (u16*)alloc(8u << 20);        // [4096][1024]  V cross
    u16*   R12    = (u16*)alloc(8u << 20);        // [2048][2048]  r1 | r2
    u16*   qb2    = (u16*)alloc(8u << 20);        // cross Q proj
    u16*   vtb    = (u16*)alloc(16u << 20);       // V^T (reused both layers)
    u16*   ob     = (u16*)alloc(8u << 20);
    float* projb  = (float*)alloc(16u << 20);
    float* projb2 = (float*)alloc(16u << 20);
    float* out1_32 = (float*)alloc(16u << 20);
    u16*   out1_bf = (u16*)alloc(8u << 20);
    float* out2_32 = (float*)alloc(16u << 20);
    u16*   out2_bf = (u16*)alloc(8u << 20);
    u16*   hb     = (u16*)alloc(32u << 20);       // [4096][4096]
    if (off > ws_size) return;
    const long long PJ2 = projb2 - projb;

    dim3 tb(32, 32);

    // ---- phase 0: conversions / transposes / new_mem
    concat_mem<<<8192, 256, 0, stream>>>(mem, tgt, newmem, cat_bf);
    conv_f2b<<<4096, 256, 0, stream>>>(src, src_bf, 1048576);
    conv_f2b<<<2048, 256, 0, stream>>>(pos, pos_bf, 524288);
    TW18 tw;
    tw.t[0] = {Wq1, W1t, 1024, 1024};
    tw.t[1] = {Wk1, W1t + 1048576, 1024, 1024};
    tw.t[2] = {Wv1, W1t + 2097152, 1024, 1024};
    tw.t[3] = {Wr1, Wr12t, 1024, 1024};
    tw.t[4] = {Wr2, Wr12t + 1048576, 1024, 1024};
    tw.t[5] = {Wk2, W2t, 1024, 1024};
    tw.t[6] = {Wv2, W2t + 1048576, 1024, 1024};
    tw.t[7] = {Wq2, Wq2t, 1024, 1024};
    tw.t[8] = {Wo1, Wo1t, 1024, 1024};
    tw.t[9] = {Wo2, Wo2t, 1024, 1024};
    for (int zz = 0; zz < 4; ++zz) {
        tw.t[10 + zz] = {Wf1 + zz * 1024, Wf1t + (long long)zz * 1048576, 4096, 1024};
        tw.t[14 + zz] = {Wf2 + (long long)zz * 1048576, Wf2t + zz * 1024, 1024, 4096};
    }
    transpose_w18<<<dim3(32, 32, 18), tb, 0, stream>>>(tw);

    // ---- layer 1: self relative attention (K=2048)
    // K|V over full cat (ldc 2080 to de-alias L2 sets for fattn K gathers)
    gemm_bt<4,4,1,0><<<dim3(16,64,1), 256, 0, stream>>>(cat_bf, W1t + 1048576, P1kv, nullptr,
        8192,2048,1024, 1024,1024,2080, 0,0,0,0,0,0, 1);
    // Q over tgt rows only (batched by b: rows b*2048+1024..2047 of cat)
    gemm_bt<4,4,1,0><<<dim3(8,8,4), 256, 0, stream>>>(cat_bf + 1048576, W1t, qb1, nullptr,
        1024,1024,1024, 1024,1024,1024, 0,2048LL*1024, 0,0, 0,1048576LL, 1);
    gemm_bt<4,4,1,0><<<dim3(16,16,1), 256, 0, stream>>>(pos_bf, Wr12t, R12, nullptr,
        2048,2048,1024, 1024,1024,2048, 0,0,0,0,0,0, 1);
    transpose_v<<<dim3(32,1,64), 256, 0, stream>>>(P1kv, vtb, 2048, 2080, 1024);
    fattn<2048,0><<<dim3(64,64), 512, 0, stream>>>(qb1, 1024LL, 1048576LL,
        rwb, rrb, P1kv, R12, vtb, selfP, ob, 2080);
    gemm_bt<4,4,0,0><<<dim3(8,32,2), 256, 0, stream>>>(ob, Wo1t, projb, nullptr,
        4096,1024,512, 1024,1024,1024, 0,512, 0,512, 0,PJ2, 1);
    ln_res<<<4096, 256, 0, stream>>>(tgt, projb, projb2, nullptr, ln1g, ln1b, out1_32, out1_bf);

    // ---- layer 2: cross relative attention (K=1024)
    {
        const long long dA = (long long)(src_bf - out1_bf);
        const long long dB1 = (long long)(W2t - Wq2t);
        const long long dB2 = (long long)((W2t + 1048576) - Wq2t);
        const long long dC1 = (long long)(P2k - qb2);
        const long long dC2 = (long long)(P2v - qb2);
        gemm_bt<4,4,1,0><<<dim3(8,32,3), 256, 0, stream>>>(out1_bf, Wq2t, qb2, nullptr,
            4096,1024,1024, 1024,1024,1024, dA,dA, dB1,dB2, dC1,dC2, 2);
    }
    transpose_v<<<dim3(16,1,64), 256, 0, stream>>>(P2v, vtb, 1024, 1024, 0);
    fattn<1024,1><<<dim3(64,64), 512, 0, stream>>>(qb2, 1024LL, 1048576LL,
        rwb, rrb, P2k, R12 + 1024LL * 2048 + 1024, vtb, interP, ob, 1024);
    gemm_bt<4,4,0,0><<<dim3(8,32,2), 256, 0, stream>>>(ob, Wo2t, projb, nullptr,
        4096,1024,512, 1024,1024,1024, 0,512, 0,512, 0,PJ2, 1);
    ln_res<<<4096, 256, 0, stream>>>(out1_32, projb, projb2, nullptr, ln2g, ln2b, out2_32, out2_bf);

    // ---- layer 3: FF
    gemm_bt<4,4,1,2><<<dim3(32,32,1), 256, 0, stream>>>(out2_bf, Wf1t, hb, bf1,
        4096,4096,1024, 1024,1024,4096, 0,0,0,0,0,0, 1);
    gemm_bt<4,4,0,0><<<dim3(8,32,2), 256, 0, stream>>>(hb, Wf2t, projb, nullptr,
        4096,1024,2048, 4096,4096,1024, 0,2048, 0,2048, 0,PJ2, 1);
    ln_res<<<4096, 256, 0, stream>>>(out2_32, projb, projb2, bf2, ln3g, ln3b, outp, nullptr);
}

// Round 11
// 903.215 us; speedup vs baseline: 1.9601x; 1.0277x over previous
//
#include <hip/hip_runtime.h>

typedef unsigned short u16;
typedef __attribute__((ext_vector_type(8))) short short8;
typedef __attribute__((ext_vector_type(4))) float f4;
typedef __attribute__((ext_vector_type(4))) unsigned short u16x4;

__device__ __forceinline__ float b2f(u16 u) {
    unsigned int x = ((unsigned int)u) << 16;
    return __builtin_bit_cast(float, x);
}
__device__ __forceinline__ u16 f2b(float f) {
    unsigned int u = __builtin_bit_cast(unsigned int, f);
    u += 0x7FFFu + ((u >> 16) & 1u);   // round-to-nearest-even
    return (u16)(u >> 16);
}

__device__ __forceinline__ void gl16(const void* g, void* l) {
    __builtin_amdgcn_global_load_lds(
        (const __attribute__((address_space(1))) void*)g,
        (__attribute__((address_space(3))) void*)l, 16, 0, 0);
}

// ---------------------------------------------------------------------------
// bf16 MFMA GEMM, global_load_lds staging + double-buffered LDS:
//   C[M,N] = A[M,K] @ Bt[N,K]^T  (+bias, +relu)
// Tile 128x128, BK=32, 4 waves (2x2). CBF: 0 f32-out, 1 bf16-out.
// EPI: 0 none, 1 +bias, 2 +bias+relu. Split-K / multi-source via batch strides.
// ---------------------------------------------------------------------------
template<int FM, int FN, int CBF, int EPI>
__global__ __launch_bounds__(256, 3)
void gemm_bt(const u16* __restrict__ Ap, const u16* __restrict__ Bp,
             void* __restrict__ Cp, const float* __restrict__ bias,
             int M, int N, int K, int lda, int ldb, int ldc,
             long long sAh, long long sAb, long long sBh, long long sBb,
             long long sCh, long long sCb, int batchH)
{
    constexpr int BM = FM * 32;
    constexpr int BN = FN * 32;
    __shared__ __align__(16) u16 As[2][BM * 32];
    __shared__ __align__(16) u16 Bs[2][BN * 32];

    const int tid  = threadIdx.x;
    const int z    = blockIdx.z;
    const int bb   = z / batchH;
    const int hh   = z - bb * batchH;
    const int m0   = blockIdx.y * BM;
    const int n0   = blockIdx.x * BN;
    const int w    = tid >> 6;
    const int lane = tid & 63;
    const int wr   = w >> 1;
    const int wc   = w & 1;
    const int lrow = lane & 15;
    const int lk   = (lane >> 4) << 3;
    const int lrow4 = lane >> 2;
    const int lch   = lane & 3;

    const u16* Ag = Ap + sAb * bb + sAh * hh;
    const u16* Bg = Bp + sBb * bb + sBh * hh;

    f4 acc[FM][FN] = {};

    auto stage = [&](int buf, int kt) {
        const int kb = kt << 5;
        #pragma unroll
        for (int i = 0; i < BM / 64; ++i) {
            const int row0 = (w + i * 4) << 4;
            gl16(Ag + (long long)(m0 + row0 + lrow4) * lda + kb + (lch << 3),
                 &As[buf][row0 * 32]);
        }
        #pragma unroll
        for (int i = 0; i < BN / 64; ++i) {
            const int row0 = (w + i * 4) << 4;
            gl16(Bg + (long long)(n0 + row0 + lrow4) * ldb + kb + (lch << 3),
                 &Bs[buf][row0 * 32]);
        }
    };

    const int nKt = K >> 5;
    stage(0, 0);
    __syncthreads();
    int cur = 0;
    for (int kt = 0; kt < nKt; ++kt) {
        if (kt + 1 < nKt) stage(cur ^ 1, kt + 1);

        short8 af[FM], bv[FN];
        #pragma unroll
        for (int m = 0; m < FM; ++m)
            af[m] = *(const short8*)(&As[cur][(wr * FM * 16 + m * 16 + lrow) * 32 + lk]);
        #pragma unroll
        for (int n = 0; n < FN; ++n)
            bv[n] = *(const short8*)(&Bs[cur][(wc * FN * 16 + n * 16 + lrow) * 32 + lk]);
        #pragma unroll
        for (int m = 0; m < FM; ++m)
            #pragma unroll
            for (int n = 0; n < FN; ++n)
                acc[m][n] = __builtin_amdgcn_mfma_f32_16x16x32_bf16(af[m], bv[n], acc[m][n], 0, 0, 0);

        __syncthreads();
        cur ^= 1;
    }

    const int crow0 = m0 + wr * FM * 16 + ((lane >> 4) << 2);
    const int ccol0 = n0 + wc * FN * 16 + lrow;
    if (CBF == 0) {
        float* Cg = (float*)Cp + sCb * bb + sCh * hh;
        #pragma unroll
        for (int m = 0; m < FM; ++m) {
            #pragma unroll
            for (int n = 0; n < FN; ++n) {
                const int col = ccol0 + n * 16;
                float bvv = (EPI >= 1) ? bias[col] : 0.f;
                #pragma unroll
                for (int r = 0; r < 4; ++r) {
                    float vv = acc[m][n][r] + bvv;
                    if (EPI == 2) vv = fmaxf(vv, 0.f);
                    Cg[(long long)(crow0 + m * 16 + r) * ldc + col] = vv;
                }
            }
        }
    } else {
        u16* Cg = (u16*)Cp + sCb * bb + sCh * hh;
        #pragma unroll
        for (int m = 0; m < FM; ++m) {
            #pragma unroll
            for (int n = 0; n < FN; ++n) {
                const int col = ccol0 + n * 16;
                float bvv = (EPI >= 1) ? bias[col] : 0.f;
                #pragma unroll
                for (int r = 0; r < 4; ++r) {
                    float vv = acc[m][n][r] + bvv;
                    if (EPI == 2) vv = fmaxf(vv, 0.f);
                    Cg[(long long)(crow0 + m * 16 + r) * ldc + col] = f2b(vv);
                }
            }
        }
    }
}

// ---------------------------------------------------------------------------
// Fused attention v8: swapped-operand + wave-interleaved + XCD-swizzled grid
// + software-pipelined K gathers + setprio around MFMA clusters.
// 16 q-rows, 512 threads (8 waves), 1D grid 4096 (bijective XCD chunking:
// each XCD gets 8 contiguous bh panels -> K/V/R stay L2-resident).
// MODE 0: self causal (limit=t+1024), KK=2048. MODE 1: cross, KK=1024.
// ---------------------------------------------------------------------------
template<int KK, int MODE>
__global__ __launch_bounds__(512, 4)
void fattn(const u16* __restrict__ qsrc, long long qld, long long qsb,
           const float* __restrict__ rwb, const float* __restrict__ rrb,
           const u16* __restrict__ kb, const u16* __restrict__ rr,
           const u16* __restrict__ vt,
           float* __restrict__ probs, u16* __restrict__ ob, int kld)
{
    constexpr int LE = KK + 8;
    constexpr int NT = KK / 16;
    constexpr int NI = NT / 8;          // tiles per wave (16 self, 8 cross)
    constexpr int NB = NI / 4;          // 4-tile batches per wave
    __shared__ __align__(16) u16 e[16 * LE];
    __shared__ __align__(16) u16 qws[16 * 72];
    __shared__ __align__(16) u16 qrs[17 * 72];
    __shared__ float psum[8][16];

    const int tid = threadIdx.x;
    const int bid = blockIdx.x;
    const int nid = ((bid & 7) << 9) + (bid >> 3);   // XCD-chunk swizzle (4096%8==0)
    const int bh  = nid >> 6;
    const int t0  = (nid & 63) << 4;
    const int b   = bh >> 4, h = bh & 15;

    // ---- staging: q + bias, scaled 0.125, to LDS
    if (tid < 264) {
        int row, ch; const float* bias; u16* dst; bool act = true;
        if (tid < 128)      { row = tid >> 3;        ch = tid & 7; bias = rwb; dst = &qws[row * 72 + ch * 8]; }
        else if (tid < 256) { row = (tid - 128) >> 3; ch = tid & 7; bias = rrb; dst = &qrs[row * 72 + ch * 8]; }
        else if (MODE == 1) { row = 16;              ch = tid - 256; bias = rrb; dst = &qrs[16 * 72 + ch * 8]; }
        else act = false;
        if (act) {
            int trow = t0 + row; if (trow > 1023) trow = 1023;
            short8 qv = *(const short8*)(qsrc + b * qsb + (long long)trow * qld + h * 64 + ch * 8);
            const float* bp = bias + h * 64 + ch * 8;
            f4 b0 = *(const f4*)bp, b1 = *(const f4*)(bp + 4);
            short8 o;
            o[0] = (short)f2b((b2f((u16)qv[0]) + b0.x) * 0.125f);
            o[1] = (short)f2b((b2f((u16)qv[1]) + b0.y) * 0.125f);
            o[2] = (short)f2b((b2f((u16)qv[2]) + b0.z) * 0.125f);
            o[3] = (short)f2b((b2f((u16)qv[3]) + b0.w) * 0.125f);
            o[4] = (short)f2b((b2f((u16)qv[4]) + b1.x) * 0.125f);
            o[5] = (short)f2b((b2f((u16)qv[5]) + b1.y) * 0.125f);
            o[6] = (short)f2b((b2f((u16)qv[6]) + b1.z) * 0.125f);
            o[7] = (short)f2b((b2f((u16)qv[7]) + b1.w) * 0.125f);
            *(short8*)dst = o;
        }
    }
    __syncthreads();

    const int w = tid >> 6, lane = tid & 63;
    const int lc = lane & 15, g = lane >> 4, lk = g << 3;
    const int t = t0 + lc;

    const short8 bq0 = *(const short8*)&qws[lc * 72 + lk];
    const short8 bq1 = *(const short8*)&qws[lc * 72 + 32 + lk];
    const short8 br0 = *(const short8*)&qrs[lc * 72 + lk];
    const short8 br1 = *(const short8*)&qrs[lc * 72 + 32 + lk];
    short8 bs0 = {}, bs1 = {};
    if (MODE == 1) {
        bs0 = *(const short8*)&qrs[(lc + 1) * 72 + lk];
        bs1 = *(const short8*)&qrs[(lc + 1) * 72 + 32 + lk];
    }

    // ---- A0: BD~ pre-shifted write-only; 2-deep batched R-gathers
    #pragma unroll
    for (int Bb = 0; Bb < NI; Bb += 2) {
        short8 R0[2], R1[2];
        #pragma unroll
        for (int u = 0; u < 2; ++u) {
            const int ut = w + (Bb + u) * 8;
            const int u0 = ut << 4;
            const bool nd = (u0 + t0 + 30 >= 1023) || (MODE == 1 && u0 + t0 <= 1021);
            if (nd) {
                const u16* rg = rr + (long long)(u0 + lc) * 2048 + h * 64;
                R0[u] = *(const short8*)(rg + lk);
                R1[u] = *(const short8*)(rg + 32 + lk);
            }
        }
        #pragma unroll
        for (int u = 0; u < 2; ++u) {
            const int ut = w + (Bb + u) * 8;
            const int u0 = ut << 4;
            const bool need1 = (u0 + t0 + 30 >= 1023);
            const bool need2 = (MODE == 1) && (u0 + t0 <= 1021);
            if (need1) {
                f4 acc = {};
                acc = __builtin_amdgcn_mfma_f32_16x16x32_bf16(R0[u], br0, acc, 0, 0, 0);
                acc = __builtin_amdgcn_mfma_f32_16x16x32_bf16(R1[u], br1, acc, 0, 0, 0);
                #pragma unroll
                for (int i = 0; i < 4; ++i) {
                    const int j = u0 + 4 * g + i + t - 1023;
                    if (j >= 0) e[lc * LE + j] = f2b(acc[i]);
                }
            }
            if (MODE == 1 && need2) {
                f4 acc = {};
                acc = __builtin_amdgcn_mfma_f32_16x16x32_bf16(R0[u], bs0, acc, 0, 0, 0);
                acc = __builtin_amdgcn_mfma_f32_16x16x32_bf16(R1[u], bs1, acc, 0, 0, 0);
                #pragma unroll
                for (int i = 0; i < 4; ++i) {
                    const int j = u0 + 4 * g + i + t + 2;
                    if (j < KK) e[lc * LE + j] = f2b(acc[i]);
                }
            }
        }
    }
    __syncthreads();

    // ---- A1: AC + BD-add + exp + row-sum; pipelined 4-deep batched K-gathers
    float sum = 0.f;
    const int limit = t + 1024;
    const int jvt = (MODE == 0) ? ((t0 + 1039) >> 4) : (NT - 1);
    {
        short8 K0a[4], K0b[4], K1c[4];
        auto ldK0 = [&](short8* dst, int B2) {
            #pragma unroll
            for (int u = 0; u < 4; ++u) {
                const int jt = w + (B2 * 4 + u) * 8;
                if (MODE != 0 || jt <= jvt) {
                    const u16* kg = kb + (long long)(b * KK + (jt << 4) + lc) * kld + h * 64;
                    dst[u] = *(const short8*)(kg + lk);
                }
            }
        };
        ldK0(K0a, 0);
        #pragma unroll
        for (int B2 = 0; B2 < NB; ++B2) {
            short8* K0c = (B2 & 1) ? K0b : K0a;
            short8* K0n = (B2 & 1) ? K0a : K0b;
            #pragma unroll
            for (int u = 0; u < 4; ++u) {
                const int jt = w + (B2 * 4 + u) * 8;
                if (MODE != 0 || jt <= jvt) {
                    const u16* kg = kb + (long long)(b * KK + (jt << 4) + lc) * kld + h * 64;
                    K1c[u] = *(const short8*)(kg + 32 + lk);
                }
            }
            if (B2 + 1 < NB) ldK0(K0n, B2 + 1);
            __builtin_amdgcn_s_setprio(1);
            #pragma unroll
            for (int u = 0; u < 4; ++u) {
                const int jt = w + (B2 * 4 + u) * 8;
                const int jme = (jt << 4) + 4 * g;
                if (MODE == 0 && jt > jvt) {
                    u16x4 z = {0, 0, 0, 0};
                    *(u16x4*)&e[lc * LE + jme] = z;
                } else {
                    f4 acc = {};
                    acc = __builtin_amdgcn_mfma_f32_16x16x32_bf16(K0c[u], bq0, acc, 0, 0, 0);
                    acc = __builtin_amdgcn_mfma_f32_16x16x32_bf16(K1c[u], bq1, acc, 0, 0, 0);
                    u16x4 bd4 = *(const u16x4*)&e[lc * LE + jme];
                    u16x4 st;
                    #pragma unroll
                    for (int i = 0; i < 4; ++i) {
                        const int j = jme + i;
                        float bd = b2f(bd4[i]);
                        if (MODE == 1 && j == t + 1) bd = 0.f;
                        float ev = __expf(acc[i] + bd);
                        if (MODE == 0 && j > limit) ev = 0.f;
                        sum += ev;
                        st[i] = f2b(ev);
                    }
                    *(u16x4*)&e[lc * LE + jme] = st;
                }
            }
            __builtin_amdgcn_s_setprio(0);
        }
    }
    sum += __shfl_xor(sum, 16);
    sum += __shfl_xor(sum, 32);
    if (g == 0) psum[w][lc] = sum;
    __syncthreads();

    if (w >= 4) {
        // ---- B: normalized f32 probs write (waves 4-7), non-temporal
        const int r = (tid >> 4) & 15;
        const int q = tid & 15;
        float s = 0.f;
        #pragma unroll
        for (int w2 = 0; w2 < 8; ++w2) s += psum[w2][r];
        const float inv = 1.f / s;
        float* pr = probs + ((long long)bh * 1024 + t0 + r) * KK;
        #pragma unroll 4
        for (int i2 = 0; i2 < KK / 128; ++i2) {
            const int j0 = q * 8 + i2 * 128;
            u16x4 e0 = *(const u16x4*)&e[r * LE + j0];
            u16x4 e1 = *(const u16x4*)&e[r * LE + j0 + 4];
            f4 p0, p1;
            p0.x = b2f(e0.x) * inv; p0.y = b2f(e0.y) * inv;
            p0.z = b2f(e0.z) * inv; p0.w = b2f(e0.w) * inv;
            p1.x = b2f(e1.x) * inv; p1.y = b2f(e1.y) * inv;
            p1.z = b2f(e1.z) * inv; p1.w = b2f(e1.w) * inv;
            __builtin_nontemporal_store(p0, (f4*)(pr + j0));
            __builtin_nontemporal_store(p1, (f4*)(pr + j0 + 4));
        }
    } else {
        // ---- C: PV (waves 0-3, 16 d-cols each)
        const int db = w << 4;
        const u16* vrow = vt + ((long long)(bh * 64 + db + lc)) * KK + lk;
        int kcend = KK / 32;
        if (MODE == 0) {
            const int ke = (t0 + 1071) >> 5;
            if (ke < kcend) kcend = ke;
        }
        f4 acc = {};
        __builtin_amdgcn_s_setprio(1);
        #pragma unroll 2
        for (int kc = 0; kc < kcend; ++kc) {
            short8 a = *(const short8*)&e[lc * LE + kc * 32 + lk];
            short8 bv = *(const short8*)(vrow + kc * 32);
            acc = __builtin_amdgcn_mfma_f32_16x16x32_bf16(a, bv, acc, 0, 0, 0);
        }
        __builtin_amdgcn_s_setprio(0);
        #pragma unroll
        for (int i = 0; i < 4; ++i) {
            const int trow = g * 4 + i;
            float s = 0.f;
            #pragma unroll
            for (int w2 = 0; w2 < 8; ++w2) s += psum[w2][trow];
            ob[((long long)(b * 1024 + t0 + trow)) * 1024 + h * 64 + db + lc] = f2b(acc[i] / s);
        }
    }
}

// ---------------------------------------------------------------------------
// Elementwise / layout kernels
// ---------------------------------------------------------------------------
// Merged phase-0: blocks [0,8192): concat_mem; [8192,12288): conv src;
// [12288,14336): conv pos.
__global__ void prep0(const float* __restrict__ mem, const float* __restrict__ tgt,
                      const float* __restrict__ src, const float* __restrict__ pos,
                      float* __restrict__ nm, u16* __restrict__ cat,
                      u16* __restrict__ srcb, u16* __restrict__ posb)
{
    const int bid = blockIdx.x;
    const int tid = threadIdx.x;
    if (bid < 8192) {
        long long i = (long long)bid * 256 + tid;
        long long b = i >> 19;
        int rem = (int)(i & 524287);
        int r = rem >> 8, c4 = rem & 255;
        const float* sp = (r < 1024) ? (mem + ((b << 10) + r) * 1024 + c4 * 4)
                                     : (tgt + ((b << 10) + (r - 1024)) * 1024 + c4 * 4);
        f4 v = *(const f4*)sp;
        __builtin_nontemporal_store(v, (f4*)(nm + i * 4));
        u16x4 o; o.x = f2b(v.x); o.y = f2b(v.y); o.z = f2b(v.z); o.w = f2b(v.w);
        *(u16x4*)(cat + i * 4) = o;
    } else if (bid < 12288) {
        long long i = (long long)(bid - 8192) * 256 + tid;
        f4 v = *(const f4*)(src + i * 4);
        u16x4 o; o.x = f2b(v.x); o.y = f2b(v.y); o.z = f2b(v.z); o.w = f2b(v.w);
        *(u16x4*)(srcb + i * 4) = o;
    } else {
        long long i = (long long)(bid - 12288) * 256 + tid;
        f4 v = *(const f4*)(pos + i * 4);
        u16x4 o; o.x = f2b(v.x); o.y = f2b(v.y); o.z = f2b(v.z); o.w = f2b(v.w);
        *(u16x4*)(posb + i * 4) = o;
    }
}

struct TWS { const float* s; u16* d; int sld, dld; };
struct TW18 { TWS t[18]; };
__global__ void transpose_w18(TW18 p)
{
    __shared__ float tile[32][33];
    const TWS ts = p.t[blockIdx.z];
    int c0 = blockIdx.x * 32, r0 = blockIdx.y * 32;
    int tx = threadIdx.x, ty = threadIdx.y;
    tile[ty][tx] = ts.s[(long long)(r0 + ty) * ts.sld + c0 + tx];
    __syncthreads();
    ts.d[(long long)(c0 + ty) * ts.dld + r0 + tx] = f2b(tile[tx][ty]);
}

// V^T: vt[(b*16+h)*64+d][j] = v[(b*KK+j)*ld + coff + h*64 + d]
__global__ __launch_bounds__(256) void transpose_v(const u16* __restrict__ v, u16* __restrict__ vt,
                                                   int KK, int ld, int coff)
{
    __shared__ u16 tile[64][68];
    const int z = blockIdx.z, b = z >> 4, h = z & 15;
    const int j0 = blockIdx.x << 6;
    const int rr8 = threadIdx.x >> 3;
    const int c8 = (threadIdx.x & 7) << 3;
    #pragma unroll
    for (int p = 0; p < 2; ++p) {
        const int jr = p * 32 + rr8;
        short8 val = *(const short8*)(v + ((long long)(b * KK + j0 + jr)) * ld + coff + h * 64 + c8);
        #pragma unroll
        for (int k = 0; k < 8; ++k) tile[c8 + k][jr] = (u16)val[k];
    }
    __syncthreads();
    #pragma unroll
    for (int p = 0; p < 2; ++p) {
        const int d = p * 32 + rr8;
        short8 o;
        #pragma unroll
        for (int k = 0; k < 8; ++k) o[k] = (short)tile[d][c8 + k];
        *(short8*)(vt + ((long long)((b * 16 + h) * 64 + d)) * KK + j0 + c8) = o;
    }
}

// out = LN(x + h1 + h2 + hbias?) * g + bl ; optional bf16 copy.
__global__ __launch_bounds__(256) void ln_res(const float* __restrict__ x,
                                              const float* __restrict__ h1,
                                              const float* __restrict__ h2,
                                              const float* __restrict__ hbias,
                                              const float* __restrict__ g, const float* __restrict__ bl,
                                              float* __restrict__ o32, u16* __restrict__ obf)
{
    const long long row = blockIdx.x;
    const int tid = threadIdx.x;
    const long long base = row * 1024 + tid * 4;
    f4 xa = *(const f4*)(x + base);
    f4 ha = *(const f4*)(h1 + base);
    f4 hb = *(const f4*)(h2 + base);
    f4 hc = {0.f, 0.f, 0.f, 0.f};
    if (hbias) hc = *(const f4*)(hbias + tid * 4);
    float v0 = xa.x + ha.x + hb.x + hc.x, v1 = xa.y + ha.y + hb.y + hc.y;
    float v2 = xa.z + ha.z + hb.z + hc.z, v3 = xa.w + ha.w + hb.w + hc.w;
    float lsum = v0 + v1 + v2 + v3;
    float lsq = v0 * v0 + v1 * v1 + v2 * v2 + v3 * v3;
    #pragma unroll
    for (int o2 = 32; o2; o2 >>= 1) { lsum += __shfl_xor(lsum, o2); lsq += __shfl_xor(lsq, o2); }
    __shared__ float r1[4], r2[4];
    int w = tid >> 6, lane = tid & 63;
    if (lane == 0) { r1[w] = lsum; r2[w] = lsq; }
    __syncthreads();
    lsum = r1[0] + r1[1] + r1[2] + r1[3];
    lsq  = r2[0] + r2[1] + r2[2] + r2[3];
    const float mu = lsum * 0.0009765625f;
    const float var = lsq * 0.0009765625f - mu * mu;
    const float rsd = rsqrtf(var + 1e-5f);
    const int c = tid * 4;
    f4 gv = *(const f4*)(g + c);
    f4 bv = *(const f4*)(bl + c);
    f4 y;
    y.x = (v0 - mu) * rsd * gv.x + bv.x;
    y.y = (v1 - mu) * rsd * gv.y + bv.y;
    y.z = (v2 - mu) * rsd * gv.z + bv.z;
    y.w = (v3 - mu) * rsd * gv.w + bv.w;
    *(f4*)(o32 + base) = y;
    if (obf) {
        u16x4 u; u.x = f2b(y.x); u.y = f2b(y.y); u.z = f2b(y.z); u.w = f2b(y.w);
        *(u16x4*)(obf + base) = u;
    }
}

// ---------------------------------------------------------------------------
extern "C" void kernel_launch(void* const* d_in, const int* in_sizes, int n_in,
                              void* d_out, int out_size, void* d_ws, size_t ws_size,
                              hipStream_t stream)
{
    (void)in_sizes; (void)n_in; (void)out_size;
    const float* src  = (const float*)d_in[0];
    const float* tgt  = (const float*)d_in[1];
    const float* mem  = (const float*)d_in[2];
    const float* pos  = (const float*)d_in[3];
    const float* rwb  = (const float*)d_in[4];
    const float* rrb  = (const float*)d_in[5];
    const float* Wq1  = (const float*)d_in[6];
    const float* Wk1  = (const float*)d_in[7];
    const float* Wv1  = (const float*)d_in[8];
    const float* Wr1  = (const float*)d_in[9];
    const float* Wo1  = (const float*)d_in[10];
    const float* ln1g = (const float*)d_in[11];
    const float* ln1b = (const float*)d_in[12];
    const float* Wq2  = (const float*)d_in[13];
    const float* Wk2  = (const float*)d_in[14];
    const float* Wv2  = (const float*)d_in[15];
    const float* Wr2  = (const float*)d_in[16];
    const float* Wo2  = (const float*)d_in[17];
    const float* ln2g = (const float*)d_in[18];
    const float* ln2b = (const float*)d_in[19];
    const float* Wf1  = (const float*)d_in[20];
    const float* bf1  = (const float*)d_in[21];
    const float* Wf2  = (const float*)d_in[22];
    const float* bf2  = (const float*)d_in[23];
    const float* ln3g = (const float*)d_in[24];
    const float* ln3b = (const float*)d_in[25];

    float* outp   = (float*)d_out;            // [4,1024,1024]
    float* newmem = outp + 4194304;           // [4,2048,1024]
    float* selfP  = outp + 12582912;          // [4,16,1024,2048]
    float* interP = outp + 146800640;         // [4,16,1024,1024]

    char* ws = (char*)d_ws;
    size_t off = 0;
    auto alloc = [&](size_t bytes) -> void* {
        void* p = ws + off;
        off = (off + bytes + 255) & ~(size_t)255;
        return p;
    };
    u16*   src_bf  = (u16*)alloc(8u << 20);       // [4096][1024]
    u16*   cat_bf  = (u16*)alloc(16u << 20);      // [8192][1024]
    u16*   pos_bf  = (u16*)alloc(4u << 20);       // [2048][1024]
    u16*   W1t    = (u16*)alloc(6u << 20);        // [3072][1024]  Wq1|Wk1|Wv1 ^T
    u16*   Wr12t  = (u16*)alloc(4u << 20);        // [2048][1024]  Wr1|Wr2 ^T
    u16*   W2t    = (u16*)alloc(4u << 20);        // [2048][1024]  Wk2|Wv2 ^T
    u16*   Wq2t   = (u16*)alloc(2u << 20);
    u16*   Wo1t   = (u16*)alloc(2u << 20);
    u16*   Wo2t   = (u16*)alloc(2u << 20);
    u16*   Wf1t   = (u16*)alloc(8u << 20);
    u16*   Wf2t   = (u16*)alloc(8u << 20);
    u16*   P1kv   = (u16*)alloc(34u << 20);       // [8192][2080]  K|V self (ld 2080)
    u16*   qb1    = (u16*)alloc(8u << 20);        // [4096][1024]  Q self (tgt rows)
    u16*   P2k    = (u16*)alloc(8u << 20);        // [4096][1024]  K cross
    u16*   P2v    = (u16*)alloc(8u << 20);        // [4096][1024]  V cross
    u16*   R12    = (u16*)alloc(8u << 20);        // [2048][2048]  r1 | r2
    u16*   qb2    = (u16*)alloc(8u << 20);        // cross Q proj
    u16*   vtb    = (u16*)alloc(16u << 20);       // V^T (reused both layers)
    u16*   ob     = (u16*)alloc(8u << 20);
    float* projb  = (float*)alloc(16u << 20);
    float* projb2 = (float*)alloc(16u << 20);
    float* out1_32 = (float*)alloc(16u << 20);
    u16*   out1_bf = (u16*)alloc(8u << 20);
    float* out2_32 = (float*)alloc(16u << 20);
    u16*   out2_bf = (u16*)alloc(8u << 20);
    u16*   hb     = (u16*)alloc(32u << 20);       // [4096][4096]
    if (off > ws_size) return;
    const long long PJ2 = projb2 - projb;

    dim3 tb(32, 32);

    // ---- phase 0: conversions / transposes / new_mem
    prep0<<<14336, 256, 0, stream>>>(mem, tgt, src, pos, newmem, cat_bf, src_bf, pos_bf);
    TW18 tw;
    tw.t[0] = {Wq1, W1t, 1024, 1024};
    tw.t[1] = {Wk1, W1t + 1048576, 1024, 1024};
    tw.t[2] = {Wv1, W1t + 2097152, 1024, 1024};
    tw.t[3] = {Wr1, Wr12t, 1024, 1024};
    tw.t[4] = {Wr2, Wr12t + 1048576, 1024, 1024};
    tw.t[5] = {Wk2, W2t, 1024, 1024};
    tw.t[6] = {Wv2, W2t + 1048576, 1024, 1024};
    tw.t[7] = {Wq2, Wq2t, 1024, 1024};
    tw.t[8] = {Wo1, Wo1t, 1024, 1024};
    tw.t[9] = {Wo2, Wo2t, 1024, 1024};
    for (int zz = 0; zz < 4; ++zz) {
        tw.t[10 + zz] = {Wf1 + zz * 1024, Wf1t + (long long)zz * 1048576, 4096, 1024};
        tw.t[14 + zz] = {Wf2 + (long long)zz * 1048576, Wf2t + zz * 1024, 1024, 4096};
    }
    transpose_w18<<<dim3(32, 32, 18), tb, 0, stream>>>(tw);

    // ---- layer 1: self relative attention (K=2048)
    gemm_bt<4,4,1,0><<<dim3(16,64,1), 256, 0, stream>>>(cat_bf, W1t + 1048576, P1kv, nullptr,
        8192,2048,1024, 1024,1024,2080, 0,0,0,0,0,0, 1);
    gemm_bt<4,4,1,0><<<dim3(8,8,4), 256, 0, stream>>>(cat_bf + 1048576, W1t, qb1, nullptr,
        1024,1024,1024, 1024,1024,1024, 0,2048LL*1024, 0,0, 0,1048576LL, 1);
    gemm_bt<4,4,1,0><<<dim3(16,16,1), 256, 0, stream>>>(pos_bf, Wr12t, R12, nullptr,
        2048,2048,1024, 1024,1024,2048, 0,0,0,0,0,0, 1);
    transpose_v<<<dim3(32,1,64), 256, 0, stream>>>(P1kv, vtb, 2048, 2080, 1024);
    fattn<2048,0><<<4096, 512, 0, stream>>>(qb1, 1024LL, 1048576LL,
        rwb, rrb, P1kv, R12, vtb, selfP, ob, 2080);
    gemm_bt<4,4,0,0><<<dim3(8,32,2), 256, 0, stream>>>(ob, Wo1t, projb, nullptr,
        4096,1024,512, 1024,1024,1024, 0,512, 0,512, 0,PJ2, 1);
    ln_res<<<4096, 256, 0, stream>>>(tgt, projb, projb2, nullptr, ln1g, ln1b, out1_32, out1_bf);

    // ---- layer 2: cross relative attention (K=1024)
    {
        const long long dA = (long long)(src_bf - out1_bf);
        const long long dB1 = (long long)(W2t - Wq2t);
        const long long dB2 = (long long)((W2t + 1048576) - Wq2t);
        const long long dC1 = (long long)(P2k - qb2);
        const long long dC2 = (long long)(P2v - qb2);
        gemm_bt<4,4,1,0><<<dim3(8,32,3), 256, 0, stream>>>(out1_bf, Wq2t, qb2, nullptr,
            4096,1024,1024, 1024,1024,1024, dA,dA, dB1,dB2, dC1,dC2, 2);
    }
    transpose_v<<<dim3(16,1,64), 256, 0, stream>>>(P2v, vtb, 1024, 1024, 0);
    fattn<1024,1><<<4096, 512, 0, stream>>>(qb2, 1024LL, 1048576LL,
        rwb, rrb, P2k, R12 + 1024LL * 2048 + 1024, vtb, interP, ob, 1024);
    gemm_bt<4,4,0,0><<<dim3(8,32,2), 256, 0, stream>>>(ob, Wo2t, projb, nullptr,
        4096,1024,512, 1024,1024,1024, 0,512, 0,512, 0,PJ2, 1);
    ln_res<<<4096, 256, 0, stream>>>(out1_32, projb, projb2, nullptr, ln2g, ln2b, out2_32, out2_bf);

    // ---- layer 3: FF
    gemm_bt<4,4,1,2><<<dim3(32,32,1), 256, 0, stream>>>(out2_bf, Wf1t, hb, bf1,
        4096,4096,1024, 1024,1024,4096, 0,0,0,0,0,0, 1);
    gemm_bt<4,4,0,0><<<dim3(8,32,2), 256, 0, stream>>>(hb, Wf2t, projb, nullptr,
        4096,1024,2048, 4096,4096,1024, 0,2048, 0,2048, 0,PJ2, 1);
    ln_res<<<4096, 256, 0, stream>>>(out2_32, projb, projb2, bf2, ln3g, ln3b, outp, nullptr);
}

// Round 12
// 898.196 us; speedup vs baseline: 1.9710x; 1.0056x over previous
//
#include <hip/hip_runtime.h>

typedef unsigned short u16;
typedef __attribute__((ext_vector_type(8))) short short8;
typedef __attribute__((ext_vector_type(4))) float f4;
typedef __attribute__((ext_vector_type(4))) unsigned short u16x4;

__device__ __forceinline__ float b2f(u16 u) {
    unsigned int x = ((unsigned int)u) << 16;
    return __builtin_bit_cast(float, x);
}
__device__ __forceinline__ u16 f2b(float f) {
    unsigned int u = __builtin_bit_cast(unsigned int, f);
    u += 0x7FFFu + ((u >> 16) & 1u);   // round-to-nearest-even
    return (u16)(u >> 16);
}

__device__ __forceinline__ void gl16(const void* g, void* l) {
    __builtin_amdgcn_global_load_lds(
        (const __attribute__((address_space(1))) void*)g,
        (__attribute__((address_space(3))) void*)l, 16, 0, 0);
}

// ---------------------------------------------------------------------------
// bf16 MFMA GEMM, global_load_lds staging + double-buffered LDS:
//   C[M,N] = A[M,K] @ Bt[N,K]^T  (+bias, +relu)
// Tile (FM*32)x(FN*32), BK=32, 4 waves (2x2). FM=4: 128x128 for big grids;
// FM=2: 64x128 for small grids (half VGPR/LDS -> ~5 blocks/CU latency hiding).
// CBF: 0 f32-out, 1 bf16-out. EPI: 0 none, 1 +bias, 2 +bias+relu.
// Split-K / multi-source via batch strides.
// ---------------------------------------------------------------------------
template<int FM, int FN, int CBF, int EPI>
__global__ __launch_bounds__(256, 3)
void gemm_bt(const u16* __restrict__ Ap, const u16* __restrict__ Bp,
             void* __restrict__ Cp, const float* __restrict__ bias,
             int M, int N, int K, int lda, int ldb, int ldc,
             long long sAh, long long sAb, long long sBh, long long sBb,
             long long sCh, long long sCb, int batchH)
{
    constexpr int BM = FM * 32;
    constexpr int BN = FN * 32;
    __shared__ __align__(16) u16 As[2][BM * 32];
    __shared__ __align__(16) u16 Bs[2][BN * 32];

    const int tid  = threadIdx.x;
    const int z    = blockIdx.z;
    const int bb   = z / batchH;
    const int hh   = z - bb * batchH;
    const int m0   = blockIdx.y * BM;
    const int n0   = blockIdx.x * BN;
    const int w    = tid >> 6;
    const int lane = tid & 63;
    const int wr   = w >> 1;
    const int wc   = w & 1;
    const int lrow = lane & 15;
    const int lk   = (lane >> 4) << 3;
    const int lrow4 = lane >> 2;
    const int lch   = lane & 3;

    const u16* Ag = Ap + sAb * bb + sAh * hh;
    const u16* Bg = Bp + sBb * bb + sBh * hh;

    f4 acc[FM][FN] = {};

    auto stage = [&](int buf, int kt) {
        const int kb = kt << 5;
        #pragma unroll
        for (int i = 0; i < BM / 64; ++i) {
            const int row0 = (w + i * 4) << 4;
            gl16(Ag + (long long)(m0 + row0 + lrow4) * lda + kb + (lch << 3),
                 &As[buf][row0 * 32]);
        }
        #pragma unroll
        for (int i = 0; i < BN / 64; ++i) {
            const int row0 = (w + i * 4) << 4;
            gl16(Bg + (long long)(n0 + row0 + lrow4) * ldb + kb + (lch << 3),
                 &Bs[buf][row0 * 32]);
        }
    };

    const int nKt = K >> 5;
    stage(0, 0);
    __syncthreads();
    int cur = 0;
    for (int kt = 0; kt < nKt; ++kt) {
        if (kt + 1 < nKt) stage(cur ^ 1, kt + 1);

        short8 af[FM], bv[FN];
        #pragma unroll
        for (int m = 0; m < FM; ++m)
            af[m] = *(const short8*)(&As[cur][(wr * FM * 16 + m * 16 + lrow) * 32 + lk]);
        #pragma unroll
        for (int n = 0; n < FN; ++n)
            bv[n] = *(const short8*)(&Bs[cur][(wc * FN * 16 + n * 16 + lrow) * 32 + lk]);
        #pragma unroll
        for (int m = 0; m < FM; ++m)
            #pragma unroll
            for (int n = 0; n < FN; ++n)
                acc[m][n] = __builtin_amdgcn_mfma_f32_16x16x32_bf16(af[m], bv[n], acc[m][n], 0, 0, 0);

        __syncthreads();
        cur ^= 1;
    }

    const int crow0 = m0 + wr * FM * 16 + ((lane >> 4) << 2);
    const int ccol0 = n0 + wc * FN * 16 + lrow;
    if (CBF == 0) {
        float* Cg = (float*)Cp + sCb * bb + sCh * hh;
        #pragma unroll
        for (int m = 0; m < FM; ++m) {
            #pragma unroll
            for (int n = 0; n < FN; ++n) {
                const int col = ccol0 + n * 16;
                float bvv = (EPI >= 1) ? bias[col] : 0.f;
                #pragma unroll
                for (int r = 0; r < 4; ++r) {
                    float vv = acc[m][n][r] + bvv;
                    if (EPI == 2) vv = fmaxf(vv, 0.f);
                    Cg[(long long)(crow0 + m * 16 + r) * ldc + col] = vv;
                }
            }
        }
    } else {
        u16* Cg = (u16*)Cp + sCb * bb + sCh * hh;
        #pragma unroll
        for (int m = 0; m < FM; ++m) {
            #pragma unroll
            for (int n = 0; n < FN; ++n) {
                const int col = ccol0 + n * 16;
                float bvv = (EPI >= 1) ? bias[col] : 0.f;
                #pragma unroll
                for (int r = 0; r < 4; ++r) {
                    float vv = acc[m][n][r] + bvv;
                    if (EPI == 2) vv = fmaxf(vv, 0.f);
                    Cg[(long long)(crow0 + m * 16 + r) * ldc + col] = f2b(vv);
                }
            }
        }
    }
}

// ---------------------------------------------------------------------------
// Fused attention v8: swapped-operand + wave-interleaved + XCD-swizzled grid
// + software-pipelined K gathers + setprio around MFMA clusters.
// 16 q-rows, 512 threads (8 waves), 1D grid 4096 (bijective XCD chunking).
// MODE 0: self causal (limit=t+1024), KK=2048. MODE 1: cross, KK=1024.
// ---------------------------------------------------------------------------
template<int KK, int MODE>
__global__ __launch_bounds__(512, 4)
void fattn(const u16* __restrict__ qsrc, long long qld, long long qsb,
           const float* __restrict__ rwb, const float* __restrict__ rrb,
           const u16* __restrict__ kb, const u16* __restrict__ rr,
           const u16* __restrict__ vt,
           float* __restrict__ probs, u16* __restrict__ ob, int kld)
{
    constexpr int LE = KK + 8;
    constexpr int NT = KK / 16;
    constexpr int NI = NT / 8;          // tiles per wave (16 self, 8 cross)
    constexpr int NB = NI / 4;          // 4-tile batches per wave
    __shared__ __align__(16) u16 e[16 * LE];
    __shared__ __align__(16) u16 qws[16 * 72];
    __shared__ __align__(16) u16 qrs[17 * 72];
    __shared__ float psum[8][16];

    const int tid = threadIdx.x;
    const int bid = blockIdx.x;
    const int nid = ((bid & 7) << 9) + (bid >> 3);   // XCD-chunk swizzle (4096%8==0)
    const int bh  = nid >> 6;
    const int t0  = (nid & 63) << 4;
    const int b   = bh >> 4, h = bh & 15;

    // ---- staging: q + bias, scaled 0.125, to LDS
    if (tid < 264) {
        int row, ch; const float* bias; u16* dst; bool act = true;
        if (tid < 128)      { row = tid >> 3;        ch = tid & 7; bias = rwb; dst = &qws[row * 72 + ch * 8]; }
        else if (tid < 256) { row = (tid - 128) >> 3; ch = tid & 7; bias = rrb; dst = &qrs[row * 72 + ch * 8]; }
        else if (MODE == 1) { row = 16;              ch = tid - 256; bias = rrb; dst = &qrs[16 * 72 + ch * 8]; }
        else act = false;
        if (act) {
            int trow = t0 + row; if (trow > 1023) trow = 1023;
            short8 qv = *(const short8*)(qsrc + b * qsb + (long long)trow * qld + h * 64 + ch * 8);
            const float* bp = bias + h * 64 + ch * 8;
            f4 b0 = *(const f4*)bp, b1 = *(const f4*)(bp + 4);
            short8 o;
            o[0] = (short)f2b((b2f((u16)qv[0]) + b0.x) * 0.125f);
            o[1] = (short)f2b((b2f((u16)qv[1]) + b0.y) * 0.125f);
            o[2] = (short)f2b((b2f((u16)qv[2]) + b0.z) * 0.125f);
            o[3] = (short)f2b((b2f((u16)qv[3]) + b0.w) * 0.125f);
            o[4] = (short)f2b((b2f((u16)qv[4]) + b1.x) * 0.125f);
            o[5] = (short)f2b((b2f((u16)qv[5]) + b1.y) * 0.125f);
            o[6] = (short)f2b((b2f((u16)qv[6]) + b1.z) * 0.125f);
            o[7] = (short)f2b((b2f((u16)qv[7]) + b1.w) * 0.125f);
            *(short8*)dst = o;
        }
    }
    __syncthreads();

    const int w = tid >> 6, lane = tid & 63;
    const int lc = lane & 15, g = lane >> 4, lk = g << 3;
    const int t = t0 + lc;

    const short8 bq0 = *(const short8*)&qws[lc * 72 + lk];
    const short8 bq1 = *(const short8*)&qws[lc * 72 + 32 + lk];
    const short8 br0 = *(const short8*)&qrs[lc * 72 + lk];
    const short8 br1 = *(const short8*)&qrs[lc * 72 + 32 + lk];
    short8 bs0 = {}, bs1 = {};
    if (MODE == 1) {
        bs0 = *(const short8*)&qrs[(lc + 1) * 72 + lk];
        bs1 = *(const short8*)&qrs[(lc + 1) * 72 + 32 + lk];
    }

    // ---- A0: BD~ pre-shifted write-only; 2-deep batched R-gathers
    #pragma unroll
    for (int Bb = 0; Bb < NI; Bb += 2) {
        short8 R0[2], R1[2];
        #pragma unroll
        for (int u = 0; u < 2; ++u) {
            const int ut = w + (Bb + u) * 8;
            const int u0 = ut << 4;
            const bool nd = (u0 + t0 + 30 >= 1023) || (MODE == 1 && u0 + t0 <= 1021);
            if (nd) {
                const u16* rg = rr + (long long)(u0 + lc) * 2048 + h * 64;
                R0[u] = *(const short8*)(rg + lk);
                R1[u] = *(const short8*)(rg + 32 + lk);
            }
        }
        #pragma unroll
        for (int u = 0; u < 2; ++u) {
            const int ut = w + (Bb + u) * 8;
            const int u0 = ut << 4;
            const bool need1 = (u0 + t0 + 30 >= 1023);
            const bool need2 = (MODE == 1) && (u0 + t0 <= 1021);
            if (need1) {
                f4 acc = {};
                acc = __builtin_amdgcn_mfma_f32_16x16x32_bf16(R0[u], br0, acc, 0, 0, 0);
                acc = __builtin_amdgcn_mfma_f32_16x16x32_bf16(R1[u], br1, acc, 0, 0, 0);
                #pragma unroll
                for (int i = 0; i < 4; ++i) {
                    const int j = u0 + 4 * g + i + t - 1023;
                    if (j >= 0) e[lc * LE + j] = f2b(acc[i]);
                }
            }
            if (MODE == 1 && need2) {
                f4 acc = {};
                acc = __builtin_amdgcn_mfma_f32_16x16x32_bf16(R0[u], bs0, acc, 0, 0, 0);
                acc = __builtin_amdgcn_mfma_f32_16x16x32_bf16(R1[u], bs1, acc, 0, 0, 0);
                #pragma unroll
                for (int i = 0; i < 4; ++i) {
                    const int j = u0 + 4 * g + i + t + 2;
                    if (j < KK) e[lc * LE + j] = f2b(acc[i]);
                }
            }
        }
    }
    __syncthreads();

    // ---- A1: AC + BD-add + exp + row-sum; pipelined 4-deep batched K-gathers
    float sum = 0.f;
    const int limit = t + 1024;
    const int jvt = (MODE == 0) ? ((t0 + 1039) >> 4) : (NT - 1);
    {
        short8 K0a[4], K0b[4], K1c[4];
        auto ldK0 = [&](short8* dst, int B2) {
            #pragma unroll
            for (int u = 0; u < 4; ++u) {
                const int jt = w + (B2 * 4 + u) * 8;
                if (MODE != 0 || jt <= jvt) {
                    const u16* kg = kb + (long long)(b * KK + (jt << 4) + lc) * kld + h * 64;
                    dst[u] = *(const short8*)(kg + lk);
                }
            }
        };
        ldK0(K0a, 0);
        #pragma unroll
        for (int B2 = 0; B2 < NB; ++B2) {
            short8* K0c = (B2 & 1) ? K0b : K0a;
            short8* K0n = (B2 & 1) ? K0a : K0b;
            #pragma unroll
            for (int u = 0; u < 4; ++u) {
                const int jt = w + (B2 * 4 + u) * 8;
                if (MODE != 0 || jt <= jvt) {
                    const u16* kg = kb + (long long)(b * KK + (jt << 4) + lc) * kld + h * 64;
                    K1c[u] = *(const short8*)(kg + 32 + lk);
                }
            }
            if (B2 + 1 < NB) ldK0(K0n, B2 + 1);
            __builtin_amdgcn_s_setprio(1);
            #pragma unroll
            for (int u = 0; u < 4; ++u) {
                const int jt = w + (B2 * 4 + u) * 8;
                const int jme = (jt << 4) + 4 * g;
                if (MODE == 0 && jt > jvt) {
                    u16x4 z = {0, 0, 0, 0};
                    *(u16x4*)&e[lc * LE + jme] = z;
                } else {
                    f4 acc = {};
                    acc = __builtin_amdgcn_mfma_f32_16x16x32_bf16(K0c[u], bq0, acc, 0, 0, 0);
                    acc = __builtin_amdgcn_mfma_f32_16x16x32_bf16(K1c[u], bq1, acc, 0, 0, 0);
                    u16x4 bd4 = *(const u16x4*)&e[lc * LE + jme];
                    u16x4 st;
                    #pragma unroll
                    for (int i = 0; i < 4; ++i) {
                        const int j = jme + i;
                        float bd = b2f(bd4[i]);
                        if (MODE == 1 && j == t + 1) bd = 0.f;
                        float ev = __expf(acc[i] + bd);
                        if (MODE == 0 && j > limit) ev = 0.f;
                        sum += ev;
                        st[i] = f2b(ev);
                    }
                    *(u16x4*)&e[lc * LE + jme] = st;
                }
            }
            __builtin_amdgcn_s_setprio(0);
        }
    }
    sum += __shfl_xor(sum, 16);
    sum += __shfl_xor(sum, 32);
    if (g == 0) psum[w][lc] = sum;
    __syncthreads();

    if (w >= 4) {
        // ---- B: normalized f32 probs write (waves 4-7), non-temporal
        const int r = (tid >> 4) & 15;
        const int q = tid & 15;
        float s = 0.f;
        #pragma unroll
        for (int w2 = 0; w2 < 8; ++w2) s += psum[w2][r];
        const float inv = 1.f / s;
        float* pr = probs + ((long long)bh * 1024 + t0 + r) * KK;
        #pragma unroll 4
        for (int i2 = 0; i2 < KK / 128; ++i2) {
            const int j0 = q * 8 + i2 * 128;
            u16x4 e0 = *(const u16x4*)&e[r * LE + j0];
            u16x4 e1 = *(const u16x4*)&e[r * LE + j0 + 4];
            f4 p0, p1;
            p0.x = b2f(e0.x) * inv; p0.y = b2f(e0.y) * inv;
            p0.z = b2f(e0.z) * inv; p0.w = b2f(e0.w) * inv;
            p1.x = b2f(e1.x) * inv; p1.y = b2f(e1.y) * inv;
            p1.z = b2f(e1.z) * inv; p1.w = b2f(e1.w) * inv;
            __builtin_nontemporal_store(p0, (f4*)(pr + j0));
            __builtin_nontemporal_store(p1, (f4*)(pr + j0 + 4));
        }
    } else {
        // ---- C: PV (waves 0-3, 16 d-cols each)
        const int db = w << 4;
        const u16* vrow = vt + ((long long)(bh * 64 + db + lc)) * KK + lk;
        int kcend = KK / 32;
        if (MODE == 0) {
            const int ke = (t0 + 1071) >> 5;
            if (ke < kcend) kcend = ke;
        }
        f4 acc = {};
        __builtin_amdgcn_s_setprio(1);
        #pragma unroll 2
        for (int kc = 0; kc < kcend; ++kc) {
            short8 a = *(const short8*)&e[lc * LE + kc * 32 + lk];
            short8 bv = *(const short8*)(vrow + kc * 32);
            acc = __builtin_amdgcn_mfma_f32_16x16x32_bf16(a, bv, acc, 0, 0, 0);
        }
        __builtin_amdgcn_s_setprio(0);
        #pragma unroll
        for (int i = 0; i < 4; ++i) {
            const int trow = g * 4 + i;
            float s = 0.f;
            #pragma unroll
            for (int w2 = 0; w2 < 8; ++w2) s += psum[w2][trow];
            ob[((long long)(b * 1024 + t0 + trow)) * 1024 + h * 64 + db + lc] = f2b(acc[i] / s);
        }
    }
}

// ---------------------------------------------------------------------------
// Elementwise / layout kernels
// ---------------------------------------------------------------------------
__global__ void prep0(const float* __restrict__ mem, const float* __restrict__ tgt,
                      const float* __restrict__ src, const float* __restrict__ pos,
                      float* __restrict__ nm, u16* __restrict__ cat,
                      u16* __restrict__ srcb, u16* __restrict__ posb)
{
    const int bid = blockIdx.x;
    const int tid = threadIdx.x;
    if (bid < 8192) {
        long long i = (long long)bid * 256 + tid;
        long long b = i >> 19;
        int rem = (int)(i & 524287);
        int r = rem >> 8, c4 = rem & 255;
        const float* sp = (r < 1024) ? (mem + ((b << 10) + r) * 1024 + c4 * 4)
                                     : (tgt + ((b << 10) + (r - 1024)) * 1024 + c4 * 4);
        f4 v = *(const f4*)sp;
        __builtin_nontemporal_store(v, (f4*)(nm + i * 4));
        u16x4 o; o.x = f2b(v.x); o.y = f2b(v.y); o.z = f2b(v.z); o.w = f2b(v.w);
        *(u16x4*)(cat + i * 4) = o;
    } else if (bid < 12288) {
        long long i = (long long)(bid - 8192) * 256 + tid;
        f4 v = *(const f4*)(src + i * 4);
        u16x4 o; o.x = f2b(v.x); o.y = f2b(v.y); o.z = f2b(v.z); o.w = f2b(v.w);
        *(u16x4*)(srcb + i * 4) = o;
    } else {
        long long i = (long long)(bid - 12288) * 256 + tid;
        f4 v = *(const f4*)(pos + i * 4);
        u16x4 o; o.x = f2b(v.x); o.y = f2b(v.y); o.z = f2b(v.z); o.w = f2b(v.w);
        *(u16x4*)(posb + i * 4) = o;
    }
}

struct TWS { const float* s; u16* d; int sld, dld; };
struct TW18 { TWS t[18]; };
__global__ void transpose_w18(TW18 p)
{
    __shared__ float tile[32][33];
    const TWS ts = p.t[blockIdx.z];
    int c0 = blockIdx.x * 32, r0 = blockIdx.y * 32;
    int tx = threadIdx.x, ty = threadIdx.y;
    tile[ty][tx] = ts.s[(long long)(r0 + ty) * ts.sld + c0 + tx];
    __syncthreads();
    ts.d[(long long)(c0 + ty) * ts.dld + r0 + tx] = f2b(tile[tx][ty]);
}

// V^T: vt[(b*16+h)*64+d][j] = v[(b*KK+j)*ld + coff + h*64 + d]
__global__ __launch_bounds__(256) void transpose_v(const u16* __restrict__ v, u16* __restrict__ vt,
                                                   int KK, int ld, int coff)
{
    __shared__ u16 tile[64][68];
    const int z = blockIdx.z, b = z >> 4, h = z & 15;
    const int j0 = blockIdx.x << 6;
    const int rr8 = threadIdx.x >> 3;
    const int c8 = (threadIdx.x & 7) << 3;
    #pragma unroll
    for (int p = 0; p < 2; ++p) {
        const int jr = p * 32 + rr8;
        short8 val = *(const short8*)(v + ((long long)(b * KK + j0 + jr)) * ld + coff + h * 64 + c8);
        #pragma unroll
        for (int k = 0; k < 8; ++k) tile[c8 + k][jr] = (u16)val[k];
    }
    __syncthreads();
    #pragma unroll
    for (int p = 0; p < 2; ++p) {
        const int d = p * 32 + rr8;
        short8 o;
        #pragma unroll
        for (int k = 0; k < 8; ++k) o[k] = (short)tile[d][c8 + k];
        *(short8*)(vt + ((long long)((b * 16 + h) * 64 + d)) * KK + j0 + c8) = o;
    }
}

// out = LN(x + h1 + h2 + hbias?) * g + bl ; optional bf16 copy.
__global__ __launch_bounds__(256) void ln_res(const float* __restrict__ x,
                                              const float* __restrict__ h1,
                                              const float* __restrict__ h2,
                                              const float* __restrict__ hbias,
                                              const float* __restrict__ g, const float* __restrict__ bl,
                                              float* __restrict__ o32, u16* __restrict__ obf)
{
    const long long row = blockIdx.x;
    const int tid = threadIdx.x;
    const long long base = row * 1024 + tid * 4;
    f4 xa = *(const f4*)(x + base);
    f4 ha = *(const f4*)(h1 + base);
    f4 hb = *(const f4*)(h2 + base);
    f4 hc = {0.f, 0.f, 0.f, 0.f};
    if (hbias) hc = *(const f4*)(hbias + tid * 4);
    float v0 = xa.x + ha.x + hb.x + hc.x, v1 = xa.y + ha.y + hb.y + hc.y;
    float v2 = xa.z + ha.z + hb.z + hc.z, v3 = xa.w + ha.w + hb.w + hc.w;
    float lsum = v0 + v1 + v2 + v3;
    float lsq = v0 * v0 + v1 * v1 + v2 * v2 + v3 * v3;
    #pragma unroll
    for (int o2 = 32; o2; o2 >>= 1) { lsum += __shfl_xor(lsum, o2); lsq += __shfl_xor(lsq, o2); }
    __shared__ float r1[4], r2[4];
    int w = tid >> 6, lane = tid & 63;
    if (lane == 0) { r1[w] = lsum; r2[w] = lsq; }
    __syncthreads();
    lsum = r1[0] + r1[1] + r1[2] + r1[3];
    lsq  = r2[0] + r2[1] + r2[2] + r2[3];
    const float mu = lsum * 0.0009765625f;
    const float var = lsq * 0.0009765625f - mu * mu;
    const float rsd = rsqrtf(var + 1e-5f);
    const int c = tid * 4;
    f4 gv = *(const f4*)(g + c);
    f4 bv = *(const f4*)(bl + c);
    f4 y;
    y.x = (v0 - mu) * rsd * gv.x + bv.x;
    y.y = (v1 - mu) * rsd * gv.y + bv.y;
    y.z = (v2 - mu) * rsd * gv.z + bv.z;
    y.w = (v3 - mu) * rsd * gv.w + bv.w;
    *(f4*)(o32 + base) = y;
    if (obf) {
        u16x4 u; u.x = f2b(y.x); u.y = f2b(y.y); u.z = f2b(y.z); u.w = f2b(y.w);
        *(u16x4*)(obf + base) = u;
    }
}

// ---------------------------------------------------------------------------
extern "C" void kernel_launch(void* const* d_in, const int* in_sizes, int n_in,
                              void* d_out, int out_size, void* d_ws, size_t ws_size,
                              hipStream_t stream)
{
    (void)in_sizes; (void)n_in; (void)out_size;
    const float* src  = (const float*)d_in[0];
    const float* tgt  = (const float*)d_in[1];
    const float* mem  = (const float*)d_in[2];
    const float* pos  = (const float*)d_in[3];
    const float* rwb  = (const float*)d_in[4];
    const float* rrb  = (const float*)d_in[5];
    const float* Wq1  = (const float*)d_in[6];
    const float* Wk1  = (const float*)d_in[7];
    const float* Wv1  = (const float*)d_in[8];
    const float* Wr1  = (const float*)d_in[9];
    const float* Wo1  = (const float*)d_in[10];
    const float* ln1g = (const float*)d_in[11];
    const float* ln1b = (const float*)d_in[12];
    const float* Wq2  = (const float*)d_in[13];
    const float* Wk2  = (const float*)d_in[14];
    const float* Wv2  = (const float*)d_in[15];
    const float* Wr2  = (const float*)d_in[16];
    const float* Wo2  = (const float*)d_in[17];
    const float* ln2g = (const float*)d_in[18];
    const float* ln2b = (const float*)d_in[19];
    const float* Wf1  = (const float*)d_in[20];
    const float* bf1  = (const float*)d_in[21];
    const float* Wf2  = (const float*)d_in[22];
    const float* bf2  = (const float*)d_in[23];
    const float* ln3g = (const float*)d_in[24];
    const float* ln3b = (const float*)d_in[25];

    float* outp   = (float*)d_out;            // [4,1024,1024]
    float* newmem = outp + 4194304;           // [4,2048,1024]
    float* selfP  = outp + 12582912;          // [4,16,1024,2048]
    float* interP = outp + 146800640;         // [4,16,1024,1024]

    char* ws = (char*)d_ws;
    size_t off = 0;
    auto alloc = [&](size_t bytes) -> void* {
        void* p = ws + off;
        off = (off + bytes + 255) & ~(size_t)255;
        return p;
    };
    u16*   src_bf  = (u16*)alloc(8u << 20);       // [4096][1024]
    u16*   cat_bf  = (u16*)alloc(16u << 20);      // [8192][1024]
    u16*   pos_bf  = (u16*)alloc(4u << 20);       // [2048][1024]
    u16*   W1t    = (u16*)alloc(6u << 20);        // [3072][1024]  Wq1|Wk1|Wv1 ^T
    u16*   Wr12t  = (u16*)alloc(4u << 20);        // [2048][1024]  Wr1|Wr2 ^T
    u16*   W2t    = (u16*)alloc(4u << 20);        // [2048][1024]  Wk2|Wv2 ^T
    u16*   Wq2t   = (u16*)alloc(2u << 20);
    u16*   Wo1t   = (u16*)alloc(2u << 20);
    u16*   Wo2t   = (u16*)alloc(2u << 20);
    u16*   Wf1t   = (u16*)alloc(8u << 20);
    u16*   Wf2t   = (u16*)alloc(8u << 20);
    u16*   P1kv   = (u16*)alloc(34u << 20);       // [8192][2080]  K|V self (ld 2080)
    u16*   qb1    = (u16*)alloc(8u << 20);        // [4096][1024]  Q self (tgt rows)
    u16*   P2k    = (u16*)alloc(8u << 20);        // [4096][1024]  K cross
    u16*   P2v    = (u16*)alloc(8u << 20);        // [4096][1024]  V cross
    u16*   R12    = (u16*)alloc(8u << 20);        // [2048][2048]  r1 | r2
    u16*   qb2    = (u16*)alloc(8u << 20);        // cross Q proj
    u16*   vtb    = (u16*)alloc(16u << 20);       // V^T (reused both layers)
    u16*   ob     = (u16*)alloc(8u << 20);
    float* projb  = (float*)alloc(16u << 20);
    float* projb2 = (float*)alloc(16u << 20);
    float* out1_32 = (float*)alloc(16u << 20);
    u16*   out1_bf = (u16*)alloc(8u << 20);
    float* out2_32 = (float*)alloc(16u << 20);
    u16*   out2_bf = (u16*)alloc(8u << 20);
    u16*   hb     = (u16*)alloc(32u << 20);       // [4096][4096]
    if (off > ws_size) return;
    const long long PJ2 = projb2 - projb;

    dim3 tb(32, 32);

    // ---- phase 0: conversions / transposes / new_mem
    prep0<<<14336, 256, 0, stream>>>(mem, tgt, src, pos, newmem, cat_bf, src_bf, pos_bf);
    TW18 tw;
    tw.t[0] = {Wq1, W1t, 1024, 1024};
    tw.t[1] = {Wk1, W1t + 1048576, 1024, 1024};
    tw.t[2] = {Wv1, W1t + 2097152, 1024, 1024};
    tw.t[3] = {Wr1, Wr12t, 1024, 1024};
    tw.t[4] = {Wr2, Wr12t + 1048576, 1024, 1024};
    tw.t[5] = {Wk2, W2t, 1024, 1024};
    tw.t[6] = {Wv2, W2t + 1048576, 1024, 1024};
    tw.t[7] = {Wq2, Wq2t, 1024, 1024};
    tw.t[8] = {Wo1, Wo1t, 1024, 1024};
    tw.t[9] = {Wo2, Wo2t, 1024, 1024};
    for (int zz = 0; zz < 4; ++zz) {
        tw.t[10 + zz] = {Wf1 + zz * 1024, Wf1t + (long long)zz * 1048576, 4096, 1024};
        tw.t[14 + zz] = {Wf2 + (long long)zz * 1048576, Wf2t + zz * 1024, 1024, 4096};
    }
    transpose_w18<<<dim3(32, 32, 18), tb, 0, stream>>>(tw);

    // ---- layer 1: self relative attention (K=2048)
    gemm_bt<4,4,1,0><<<dim3(16,64,1), 256, 0, stream>>>(cat_bf, W1t + 1048576, P1kv, nullptr,
        8192,2048,1024, 1024,1024,2080, 0,0,0,0,0,0, 1);
    // Q over tgt rows only: 64x128 tile, grid 512 (occupancy fix)
    gemm_bt<2,4,1,0><<<dim3(8,16,4), 256, 0, stream>>>(cat_bf + 1048576, W1t, qb1, nullptr,
        1024,1024,1024, 1024,1024,1024, 0,2048LL*1024, 0,0, 0,1048576LL, 1);
    gemm_bt<2,4,1,0><<<dim3(16,32,1), 256, 0, stream>>>(pos_bf, Wr12t, R12, nullptr,
        2048,2048,1024, 1024,1024,2048, 0,0,0,0,0,0, 1);
    transpose_v<<<dim3(32,1,64), 256, 0, stream>>>(P1kv, vtb, 2048, 2080, 1024);
    fattn<2048,0><<<4096, 512, 0, stream>>>(qb1, 1024LL, 1048576LL,
        rwb, rrb, P1kv, R12, vtb, selfP, ob, 2080);
    gemm_bt<2,4,0,0><<<dim3(8,64,2), 256, 0, stream>>>(ob, Wo1t, projb, nullptr,
        4096,1024,512, 1024,1024,1024, 0,512, 0,512, 0,PJ2, 1);
    ln_res<<<4096, 256, 0, stream>>>(tgt, projb, projb2, nullptr, ln1g, ln1b, out1_32, out1_bf);

    // ---- layer 2: cross relative attention (K=1024)
    {
        const long long dA = (long long)(src_bf - out1_bf);
        const long long dB1 = (long long)(W2t - Wq2t);
        const long long dB2 = (long long)((W2t + 1048576) - Wq2t);
        const long long dC1 = (long long)(P2k - qb2);
        const long long dC2 = (long long)(P2v - qb2);
        gemm_bt<2,4,1,0><<<dim3(8,64,3), 256, 0, stream>>>(out1_bf, Wq2t, qb2, nullptr,
            4096,1024,1024, 1024,1024,1024, dA,dA, dB1,dB2, dC1,dC2, 2);
    }
    transpose_v<<<dim3(16,1,64), 256, 0, stream>>>(P2v, vtb, 1024, 1024, 0);
    fattn<1024,1><<<4096, 512, 0, stream>>>(qb2, 1024LL, 1048576LL,
        rwb, rrb, P2k, R12 + 1024LL * 2048 + 1024, vtb, interP, ob, 1024);
    gemm_bt<2,4,0,0><<<dim3(8,64,2), 256, 0, stream>>>(ob, Wo2t, projb, nullptr,
        4096,1024,512, 1024,1024,1024, 0,512, 0,512, 0,PJ2, 1);
    ln_res<<<4096, 256, 0, stream>>>(out1_32, projb, projb2, nullptr, ln2g, ln2b, out2_32, out2_bf);

    // ---- layer 3: FF
    gemm_bt<4,4,1,2><<<dim3(32,32,1), 256, 0, stream>>>(out2_bf, Wf1t, hb, bf1,
        4096,4096,1024, 1024,1024,4096, 0,0,0,0,0,0, 1);
    gemm_bt<2,4,0,0><<<dim3(8,64,2), 256, 0, stream>>>(hb, Wf2t, projb, nullptr,
        4096,1024,2048, 4096,4096,1024, 0,2048, 0,2048, 0,PJ2, 1);
    ln_res<<<4096, 256, 0, stream>>>(out2_32, projb, projb2, bf2, ln3g, ln3b, outp, nullptr);
}

// Round 13
// 891.355 us; speedup vs baseline: 1.9862x; 1.0077x over previous
//
#include <hip/hip_runtime.h>

typedef unsigned short u16;
typedef __attribute__((ext_vector_type(8))) short short8;
typedef __attribute__((ext_vector_type(4))) float f4;
typedef __attribute__((ext_vector_type(4))) unsigned short u16x4;

__device__ __forceinline__ float b2f(u16 u) {
    unsigned int x = ((unsigned int)u) << 16;
    return __builtin_bit_cast(float, x);
}
__device__ __forceinline__ u16 f2b(float f) {
    unsigned int u = __builtin_bit_cast(unsigned int, f);
    u += 0x7FFFu + ((u >> 16) & 1u);   // round-to-nearest-even
    return (u16)(u >> 16);
}

__device__ __forceinline__ void gl16(const void* g, void* l) {
    __builtin_amdgcn_global_load_lds(
        (const __attribute__((address_space(1))) void*)g,
        (__attribute__((address_space(3))) void*)l, 16, 0, 0);
}

// ---------------------------------------------------------------------------
// bf16 MFMA GEMM, global_load_lds staging + double-buffered LDS:
//   C[M,N] = A[M,K] @ Bt[N,K]^T  (+bias, +relu)
// Tile (FM*32)x(FN*32), BK=32, 4 waves (2x2).
// CBF: 0 f32-out, 1 bf16-out, 2 bf16 V^T-transposed out
//      (CBF=2: C[(b*1024+col)*ldc + row%ldc], b=row/ldc; ldc=KV length).
// EPI: 0 none, 1 +bias, 2 +bias+relu. Multi-source via batch strides.
// ---------------------------------------------------------------------------
template<int FM, int FN, int CBF, int EPI>
__global__ __launch_bounds__(256, 3)
void gemm_bt(const u16* __restrict__ Ap, const u16* __restrict__ Bp,
             void* __restrict__ Cp, const float* __restrict__ bias,
             int M, int N, int K, int lda, int ldb, int ldc,
             long long sAh, long long sAb, long long sBh, long long sBb,
             long long sCh, long long sCb, int batchH)
{
    constexpr int BM = FM * 32;
    constexpr int BN = FN * 32;
    __shared__ __align__(16) u16 As[2][BM * 32];
    __shared__ __align__(16) u16 Bs[2][BN * 32];

    const int tid  = threadIdx.x;
    const int z    = blockIdx.z;
    const int bb   = z / batchH;
    const int hh   = z - bb * batchH;
    const int m0   = blockIdx.y * BM;
    const int n0   = blockIdx.x * BN;
    const int w    = tid >> 6;
    const int lane = tid & 63;
    const int wr   = w >> 1;
    const int wc   = w & 1;
    const int lrow = lane & 15;
    const int lk   = (lane >> 4) << 3;
    const int lrow4 = lane >> 2;
    const int lch   = lane & 3;

    const u16* Ag = Ap + sAb * bb + sAh * hh;
    const u16* Bg = Bp + sBb * bb + sBh * hh;

    f4 acc[FM][FN] = {};

    auto stage = [&](int buf, int kt) {
        const int kb = kt << 5;
        #pragma unroll
        for (int i = 0; i < BM / 64; ++i) {
            const int row0 = (w + i * 4) << 4;
            gl16(Ag + (long long)(m0 + row0 + lrow4) * lda + kb + (lch << 3),
                 &As[buf][row0 * 32]);
        }
        #pragma unroll
        for (int i = 0; i < BN / 64; ++i) {
            const int row0 = (w + i * 4) << 4;
            gl16(Bg + (long long)(n0 + row0 + lrow4) * ldb + kb + (lch << 3),
                 &Bs[buf][row0 * 32]);
        }
    };

    const int nKt = K >> 5;
    stage(0, 0);
    __syncthreads();
    int cur = 0;
    for (int kt = 0; kt < nKt; ++kt) {
        if (kt + 1 < nKt) stage(cur ^ 1, kt + 1);

        short8 af[FM], bv[FN];
        #pragma unroll
        for (int m = 0; m < FM; ++m)
            af[m] = *(const short8*)(&As[cur][(wr * FM * 16 + m * 16 + lrow) * 32 + lk]);
        #pragma unroll
        for (int n = 0; n < FN; ++n)
            bv[n] = *(const short8*)(&Bs[cur][(wc * FN * 16 + n * 16 + lrow) * 32 + lk]);
        #pragma unroll
        for (int m = 0; m < FM; ++m)
            #pragma unroll
            for (int n = 0; n < FN; ++n)
                acc[m][n] = __builtin_amdgcn_mfma_f32_16x16x32_bf16(af[m], bv[n], acc[m][n], 0, 0, 0);

        __syncthreads();
        cur ^= 1;
    }

    const int crow0 = m0 + wr * FM * 16 + ((lane >> 4) << 2);
    const int ccol0 = n0 + wc * FN * 16 + lrow;
    if (CBF == 0) {
        float* Cg = (float*)Cp + sCb * bb + sCh * hh;
        #pragma unroll
        for (int m = 0; m < FM; ++m) {
            #pragma unroll
            for (int n = 0; n < FN; ++n) {
                const int col = ccol0 + n * 16;
                float bvv = (EPI >= 1) ? bias[col] : 0.f;
                #pragma unroll
                for (int r = 0; r < 4; ++r) {
                    float vv = acc[m][n][r] + bvv;
                    if (EPI == 2) vv = fmaxf(vv, 0.f);
                    Cg[(long long)(crow0 + m * 16 + r) * ldc + col] = vv;
                }
            }
        }
    } else if (CBF == 1) {
        u16* Cg = (u16*)Cp + sCb * bb + sCh * hh;
        #pragma unroll
        for (int m = 0; m < FM; ++m) {
            #pragma unroll
            for (int n = 0; n < FN; ++n) {
                const int col = ccol0 + n * 16;
                float bvv = (EPI >= 1) ? bias[col] : 0.f;
                #pragma unroll
                for (int r = 0; r < 4; ++r) {
                    float vv = acc[m][n][r] + bvv;
                    if (EPI == 2) vv = fmaxf(vv, 0.f);
                    Cg[(long long)(crow0 + m * 16 + r) * ldc + col] = f2b(vv);
                }
            }
        }
    } else {
        // CBF==2: V^T write. row = global j-row, col = d-index (0..1023).
        // vt[(b*1024 + col)*ldc + j], b = row/ldc, j = row%ldc. 4 r's consecutive.
        u16* Cg = (u16*)Cp;
        #pragma unroll
        for (int m = 0; m < FM; ++m) {
            const int row0 = crow0 + m * 16;
            const int b2 = row0 / ldc;
            const int j = row0 - b2 * ldc;
            #pragma unroll
            for (int n = 0; n < FN; ++n) {
                const int col = ccol0 + n * 16;
                u16x4 o;
                o.x = f2b(acc[m][n][0]); o.y = f2b(acc[m][n][1]);
                o.z = f2b(acc[m][n][2]); o.w = f2b(acc[m][n][3]);
                *(u16x4*)(Cg + ((long long)(b2 * 1024 + col)) * ldc + j) = o;
            }
        }
    }
}

// ---------------------------------------------------------------------------
// Fused attention v8: swapped-operand + wave-interleaved + XCD-swizzled grid
// + software-pipelined K gathers + setprio around MFMA clusters.
// 16 q-rows, 512 threads (8 waves), 1D grid 4096 (bijective XCD chunking).
// MODE 0: self causal (limit=t+1024), KK=2048. MODE 1: cross, KK=1024.
// ---------------------------------------------------------------------------
template<int KK, int MODE>
__global__ __launch_bounds__(512, 4)
void fattn(const u16* __restrict__ qsrc, long long qld, long long qsb,
           const float* __restrict__ rwb, const float* __restrict__ rrb,
           const u16* __restrict__ kb, const u16* __restrict__ rr,
           const u16* __restrict__ vt,
           float* __restrict__ probs, u16* __restrict__ ob, int kld)
{
    constexpr int LE = KK + 8;
    constexpr int NT = KK / 16;
    constexpr int NI = NT / 8;          // tiles per wave (16 self, 8 cross)
    constexpr int NB = NI / 4;          // 4-tile batches per wave
    __shared__ __align__(16) u16 e[16 * LE];
    __shared__ __align__(16) u16 qws[16 * 72];
    __shared__ __align__(16) u16 qrs[17 * 72];
    __shared__ float psum[8][16];

    const int tid = threadIdx.x;
    const int bid = blockIdx.x;
    const int nid = ((bid & 7) << 9) + (bid >> 3);   // XCD-chunk swizzle (4096%8==0)
    const int bh  = nid >> 6;
    const int t0  = (nid & 63) << 4;
    const int b   = bh >> 4, h = bh & 15;

    // ---- staging: q + bias, scaled 0.125, to LDS
    if (tid < 264) {
        int row, ch; const float* bias; u16* dst; bool act = true;
        if (tid < 128)      { row = tid >> 3;        ch = tid & 7; bias = rwb; dst = &qws[row * 72 + ch * 8]; }
        else if (tid < 256) { row = (tid - 128) >> 3; ch = tid & 7; bias = rrb; dst = &qrs[row * 72 + ch * 8]; }
        else if (MODE == 1) { row = 16;              ch = tid - 256; bias = rrb; dst = &qrs[16 * 72 + ch * 8]; }
        else act = false;
        if (act) {
            int trow = t0 + row; if (trow > 1023) trow = 1023;
            short8 qv = *(const short8*)(qsrc + b * qsb + (long long)trow * qld + h * 64 + ch * 8);
            const float* bp = bias + h * 64 + ch * 8;
            f4 b0 = *(const f4*)bp, b1 = *(const f4*)(bp + 4);
            short8 o;
            o[0] = (short)f2b((b2f((u16)qv[0]) + b0.x) * 0.125f);
            o[1] = (short)f2b((b2f((u16)qv[1]) + b0.y) * 0.125f);
            o[2] = (short)f2b((b2f((u16)qv[2]) + b0.z) * 0.125f);
            o[3] = (short)f2b((b2f((u16)qv[3]) + b0.w) * 0.125f);
            o[4] = (short)f2b((b2f((u16)qv[4]) + b1.x) * 0.125f);
            o[5] = (short)f2b((b2f((u16)qv[5]) + b1.y) * 0.125f);
            o[6] = (short)f2b((b2f((u16)qv[6]) + b1.z) * 0.125f);
            o[7] = (short)f2b((b2f((u16)qv[7]) + b1.w) * 0.125f);
            *(short8*)dst = o;
        }
    }
    __syncthreads();

    const int w = tid >> 6, lane = tid & 63;
    const int lc = lane & 15, g = lane >> 4, lk = g << 3;
    const int t = t0 + lc;

    const short8 bq0 = *(const short8*)&qws[lc * 72 + lk];
    const short8 bq1 = *(const short8*)&qws[lc * 72 + 32 + lk];
    const short8 br0 = *(const short8*)&qrs[lc * 72 + lk];
    const short8 br1 = *(const short8*)&qrs[lc * 72 + 32 + lk];
    short8 bs0 = {}, bs1 = {};
    if (MODE == 1) {
        bs0 = *(const short8*)&qrs[(lc + 1) * 72 + lk];
        bs1 = *(const short8*)&qrs[(lc + 1) * 72 + 32 + lk];
    }

    // ---- A0: BD~ pre-shifted write-only; 2-deep batched R-gathers
    #pragma unroll
    for (int Bb = 0; Bb < NI; Bb += 2) {
        short8 R0[2], R1[2];
        #pragma unroll
        for (int u = 0; u < 2; ++u) {
            const int ut = w + (Bb + u) * 8;
            const int u0 = ut << 4;
            const bool nd = (u0 + t0 + 30 >= 1023) || (MODE == 1 && u0 + t0 <= 1021);
            if (nd) {
                const u16* rg = rr + (long long)(u0 + lc) * 2048 + h * 64;
                R0[u] = *(const short8*)(rg + lk);
                R1[u] = *(const short8*)(rg + 32 + lk);
            }
        }
        #pragma unroll
        for (int u = 0; u < 2; ++u) {
            const int ut = w + (Bb + u) * 8;
            const int u0 = ut << 4;
            const bool need1 = (u0 + t0 + 30 >= 1023);
            const bool need2 = (MODE == 1) && (u0 + t0 <= 1021);
            if (need1) {
                f4 acc = {};
                acc = __builtin_amdgcn_mfma_f32_16x16x32_bf16(R0[u], br0, acc, 0, 0, 0);
                acc = __builtin_amdgcn_mfma_f32_16x16x32_bf16(R1[u], br1, acc, 0, 0, 0);
                #pragma unroll
                for (int i = 0; i < 4; ++i) {
                    const int j = u0 + 4 * g + i + t - 1023;
                    if (j >= 0) e[lc * LE + j] = f2b(acc[i]);
                }
            }
            if (MODE == 1 && need2) {
                f4 acc = {};
                acc = __builtin_amdgcn_mfma_f32_16x16x32_bf16(R0[u], bs0, acc, 0, 0, 0);
                acc = __builtin_amdgcn_mfma_f32_16x16x32_bf16(R1[u], bs1, acc, 0, 0, 0);
                #pragma unroll
                for (int i = 0; i < 4; ++i) {
                    const int j = u0 + 4 * g + i + t + 2;
                    if (j < KK) e[lc * LE + j] = f2b(acc[i]);
                }
            }
        }
    }
    __syncthreads();

    // ---- A1: AC + BD-add + exp + row-sum; pipelined 4-deep batched K-gathers
    float sum = 0.f;
    const int limit = t + 1024;
    const int jvt = (MODE == 0) ? ((t0 + 1039) >> 4) : (NT - 1);
    {
        short8 K0a[4], K0b[4], K1c[4];
        auto ldK0 = [&](short8* dst, int B2) {
            #pragma unroll
            for (int u = 0; u < 4; ++u) {
                const int jt = w + (B2 * 4 + u) * 8;
                if (MODE != 0 || jt <= jvt) {
                    const u16* kg = kb + (long long)(b * KK + (jt << 4) + lc) * kld + h * 64;
                    dst[u] = *(const short8*)(kg + lk);
                }
            }
        };
        ldK0(K0a, 0);
        #pragma unroll
        for (int B2 = 0; B2 < NB; ++B2) {
            short8* K0c = (B2 & 1) ? K0b : K0a;
            short8* K0n = (B2 & 1) ? K0a : K0b;
            #pragma unroll
            for (int u = 0; u < 4; ++u) {
                const int jt = w + (B2 * 4 + u) * 8;
                if (MODE != 0 || jt <= jvt) {
                    const u16* kg = kb + (long long)(b * KK + (jt << 4) + lc) * kld + h * 64;
                    K1c[u] = *(const short8*)(kg + 32 + lk);
                }
            }
            if (B2 + 1 < NB) ldK0(K0n, B2 + 1);
            __builtin_amdgcn_s_setprio(1);
            #pragma unroll
            for (int u = 0; u < 4; ++u) {
                const int jt = w + (B2 * 4 + u) * 8;
                const int jme = (jt << 4) + 4 * g;
                if (MODE == 0 && jt > jvt) {
                    u16x4 z = {0, 0, 0, 0};
                    *(u16x4*)&e[lc * LE + jme] = z;
                } else {
                    f4 acc = {};
                    acc = __builtin_amdgcn_mfma_f32_16x16x32_bf16(K0c[u], bq0, acc, 0, 0, 0);
                    acc = __builtin_amdgcn_mfma_f32_16x16x32_bf16(K1c[u], bq1, acc, 0, 0, 0);
                    u16x4 bd4 = *(const u16x4*)&e[lc * LE + jme];
                    u16x4 st;
                    #pragma unroll
                    for (int i = 0; i < 4; ++i) {
                        const int j = jme + i;
                        float bd = b2f(bd4[i]);
                        if (MODE == 1 && j == t + 1) bd = 0.f;
                        float ev = __expf(acc[i] + bd);
                        if (MODE == 0 && j > limit) ev = 0.f;
                        sum += ev;
                        st[i] = f2b(ev);
                    }
                    *(u16x4*)&e[lc * LE + jme] = st;
                }
            }
            __builtin_amdgcn_s_setprio(0);
        }
    }
    sum += __shfl_xor(sum, 16);
    sum += __shfl_xor(sum, 32);
    if (g == 0) psum[w][lc] = sum;
    __syncthreads();

    if (w >= 4) {
        // ---- B: normalized f32 probs write (waves 4-7), non-temporal
        const int r = (tid >> 4) & 15;
        const int q = tid & 15;
        float s = 0.f;
        #pragma unroll
        for (int w2 = 0; w2 < 8; ++w2) s += psum[w2][r];
        const float inv = 1.f / s;
        float* pr = probs + ((long long)bh * 1024 + t0 + r) * KK;
        #pragma unroll 4
        for (int i2 = 0; i2 < KK / 128; ++i2) {
            const int j0 = q * 8 + i2 * 128;
            u16x4 e0 = *(const u16x4*)&e[r * LE + j0];
            u16x4 e1 = *(const u16x4*)&e[r * LE + j0 + 4];
            f4 p0, p1;
            p0.x = b2f(e0.x) * inv; p0.y = b2f(e0.y) * inv;
            p0.z = b2f(e0.z) * inv; p0.w = b2f(e0.w) * inv;
            p1.x = b2f(e1.x) * inv; p1.y = b2f(e1.y) * inv;
            p1.z = b2f(e1.z) * inv; p1.w = b2f(e1.w) * inv;
            __builtin_nontemporal_store(p0, (f4*)(pr + j0));
            __builtin_nontemporal_store(p1, (f4*)(pr + j0 + 4));
        }
    } else {
        // ---- C: PV (waves 0-3, 16 d-cols each)
        const int db = w << 4;
        const u16* vrow = vt + ((long long)(bh * 64 + db + lc)) * KK + lk;
        int kcend = KK / 32;
        if (MODE == 0) {
            const int ke = (t0 + 1071) >> 5;
            if (ke < kcend) kcend = ke;
        }
        f4 acc = {};
        __builtin_amdgcn_s_setprio(1);
        #pragma unroll 2
        for (int kc = 0; kc < kcend; ++kc) {
            short8 a = *(const short8*)&e[lc * LE + kc * 32 + lk];
            short8 bv = *(const short8*)(vrow + kc * 32);
            acc = __builtin_amdgcn_mfma_f32_16x16x32_bf16(a, bv, acc, 0, 0, 0);
        }
        __builtin_amdgcn_s_setprio(0);
        #pragma unroll
        for (int i = 0; i < 4; ++i) {
            const int trow = g * 4 + i;
            float s = 0.f;
            #pragma unroll
            for (int w2 = 0; w2 < 8; ++w2) s += psum[w2][trow];
            ob[((long long)(b * 1024 + t0 + trow)) * 1024 + h * 64 + db + lc] = f2b(acc[i] / s);
        }
    }
}

// ---------------------------------------------------------------------------
// Elementwise / layout kernels
// ---------------------------------------------------------------------------
__global__ void prep0(const float* __restrict__ mem, const float* __restrict__ tgt,
                      const float* __restrict__ src, const float* __restrict__ pos,
                      float* __restrict__ nm, u16* __restrict__ cat,
                      u16* __restrict__ srcb, u16* __restrict__ posb)
{
    const int bid = blockIdx.x;
    const int tid = threadIdx.x;
    if (bid < 8192) {
        long long i = (long long)bid * 256 + tid;
        long long b = i >> 19;
        int rem = (int)(i & 524287);
        int r = rem >> 8, c4 = rem & 255;
        const float* sp = (r < 1024) ? (mem + ((b << 10) + r) * 1024 + c4 * 4)
                                     : (tgt + ((b << 10) + (r - 1024)) * 1024 + c4 * 4);
        f4 v = *(const f4*)sp;
        __builtin_nontemporal_store(v, (f4*)(nm + i * 4));
        u16x4 o; o.x = f2b(v.x); o.y = f2b(v.y); o.z = f2b(v.z); o.w = f2b(v.w);
        *(u16x4*)(cat + i * 4) = o;
    } else if (bid < 12288) {
        long long i = (long long)(bid - 8192) * 256 + tid;
        f4 v = *(const f4*)(src + i * 4);
        u16x4 o; o.x = f2b(v.x); o.y = f2b(v.y); o.z = f2b(v.z); o.w = f2b(v.w);
        *(u16x4*)(srcb + i * 4) = o;
    } else {
        long long i = (long long)(bid - 12288) * 256 + tid;
        f4 v = *(const f4*)(pos + i * 4);
        u16x4 o; o.x = f2b(v.x); o.y = f2b(v.y); o.z = f2b(v.z); o.w = f2b(v.w);
        *(u16x4*)(posb + i * 4) = o;
    }
}

struct TWS { const float* s; u16* d; int sld, dld; };
struct TW18 { TWS t[18]; };
__global__ void transpose_w18(TW18 p)
{
    __shared__ float tile[32][33];
    const TWS ts = p.t[blockIdx.z];
    int c0 = blockIdx.x * 32, r0 = blockIdx.y * 32;
    int tx = threadIdx.x, ty = threadIdx.y;
    tile[ty][tx] = ts.s[(long long)(r0 + ty) * ts.sld + c0 + tx];
    __syncthreads();
    ts.d[(long long)(c0 + ty) * ts.dld + r0 + tx] = f2b(tile[tx][ty]);
}

// out = LN(x + h1 + h2? + hbias?) * g + bl ; optional bf16 copy.
__global__ __launch_bounds__(256) void ln_res(const float* __restrict__ x,
                                              const float* __restrict__ h1,
                                              const float* __restrict__ h2,
                                              const float* __restrict__ hbias,
                                              const float* __restrict__ g, const float* __restrict__ bl,
                                              float* __restrict__ o32, u16* __restrict__ obf)
{
    const long long row = blockIdx.x;
    const int tid = threadIdx.x;
    const long long base = row * 1024 + tid * 4;
    f4 xa = *(const f4*)(x + base);
    f4 ha = *(const f4*)(h1 + base);
    f4 hb = {0.f, 0.f, 0.f, 0.f};
    if (h2) hb = *(const f4*)(h2 + base);
    f4 hc = {0.f, 0.f, 0.f, 0.f};
    if (hbias) hc = *(const f4*)(hbias + tid * 4);
    float v0 = xa.x + ha.x + hb.x + hc.x, v1 = xa.y + ha.y + hb.y + hc.y;
    float v2 = xa.z + ha.z + hb.z + hc.z, v3 = xa.w + ha.w + hb.w + hc.w;
    float lsum = v0 + v1 + v2 + v3;
    float lsq = v0 * v0 + v1 * v1 + v2 * v2 + v3 * v3;
    #pragma unroll
    for (int o2 = 32; o2; o2 >>= 1) { lsum += __shfl_xor(lsum, o2); lsq += __shfl_xor(lsq, o2); }
    __shared__ float r1[4], r2[4];
    int w = tid >> 6, lane = tid & 63;
    if (lane == 0) { r1[w] = lsum; r2[w] = lsq; }
    __syncthreads();
    lsum = r1[0] + r1[1] + r1[2] + r1[3];
    lsq  = r2[0] + r2[1] + r2[2] + r2[3];
    const float mu = lsum * 0.0009765625f;
    const float var = lsq * 0.0009765625f - mu * mu;
    const float rsd = rsqrtf(var + 1e-5f);
    const int c = tid * 4;
    f4 gv = *(const f4*)(g + c);
    f4 bv = *(const f4*)(bl + c);
    f4 y;
    y.x = (v0 - mu) * rsd * gv.x + bv.x;
    y.y = (v1 - mu) * rsd * gv.y + bv.y;
    y.z = (v2 - mu) * rsd * gv.z + bv.z;
    y.w = (v3 - mu) * rsd * gv.w + bv.w;
    *(f4*)(o32 + base) = y;
    if (obf) {
        u16x4 u; u.x = f2b(y.x); u.y = f2b(y.y); u.z = f2b(y.z); u.w = f2b(y.w);
        *(u16x4*)(obf + base) = u;
    }
}

// ---------------------------------------------------------------------------
extern "C" void kernel_launch(void* const* d_in, const int* in_sizes, int n_in,
                              void* d_out, int out_size, void* d_ws, size_t ws_size,
                              hipStream_t stream)
{
    (void)in_sizes; (void)n_in; (void)out_size;
    const float* src  = (const float*)d_in[0];
    const float* tgt  = (const float*)d_in[1];
    const float* mem  = (const float*)d_in[2];
    const float* pos  = (const float*)d_in[3];
    const float* rwb  = (const float*)d_in[4];
    const float* rrb  = (const float*)d_in[5];
    const float* Wq1  = (const float*)d_in[6];
    const float* Wk1  = (const float*)d_in[7];
    const float* Wv1  = (const float*)d_in[8];
    const float* Wr1  = (const float*)d_in[9];
    const float* Wo1  = (const float*)d_in[10];
    const float* ln1g = (const float*)d_in[11];
    const float* ln1b = (const float*)d_in[12];
    const float* Wq2  = (const float*)d_in[13];
    const float* Wk2  = (const float*)d_in[14];
    const float* Wv2  = (const float*)d_in[15];
    const float* Wr2  = (const float*)d_in[16];
    const float* Wo2  = (const float*)d_in[17];
    const float* ln2g = (const float*)d_in[18];
    const float* ln2b = (const float*)d_in[19];
    const float* Wf1  = (const float*)d_in[20];
    const float* bf1  = (const float*)d_in[21];
    const float* Wf2  = (const float*)d_in[22];
    const float* bf2  = (const float*)d_in[23];
    const float* ln3g = (const float*)d_in[24];
    const float* ln3b = (const float*)d_in[25];

    float* outp   = (float*)d_out;            // [4,1024,1024]
    float* newmem = outp + 4194304;           // [4,2048,1024]
    float* selfP  = outp + 12582912;          // [4,16,1024,2048]
    float* interP = outp + 146800640;         // [4,16,1024,1024]

    char* ws = (char*)d_ws;
    size_t off = 0;
    auto alloc = [&](size_t bytes) -> void* {
        void* p = ws + off;
        off = (off + bytes + 255) & ~(size_t)255;
        return p;
    };
    u16*   src_bf  = (u16*)alloc(8u << 20);       // [4096][1024]
    u16*   cat_bf  = (u16*)alloc(16u << 20);      // [8192][1024]
    u16*   pos_bf  = (u16*)alloc(4u << 20);       // [2048][1024]
    u16*   W1t    = (u16*)alloc(6u << 20);        // [3072][1024]  Wq1|Wk1|Wv1 ^T
    u16*   Wr12t  = (u16*)alloc(4u << 20);        // [2048][1024]  Wr1|Wr2 ^T
    u16*   W2t    = (u16*)alloc(4u << 20);        // [2048][1024]  Wk2|Wv2 ^T
    u16*   Wq2t   = (u16*)alloc(2u << 20);
    u16*   Wo1t   = (u16*)alloc(2u << 20);
    u16*   Wo2t   = (u16*)alloc(2u << 20);
    u16*   Wf1t   = (u16*)alloc(8u << 20);
    u16*   Wf2t   = (u16*)alloc(8u << 20);
    u16*   K1b    = (u16*)alloc(18u << 20);       // [8192][1056]  K self (de-aliased ld)
    u16*   qb1    = (u16*)alloc(8u << 20);        // [4096][1024]  Q self (tgt rows)
    u16*   P2k    = (u16*)alloc(8u << 20);        // [4096][1024]  K cross
    u16*   R12    = (u16*)alloc(8u << 20);        // [2048][2048]  r1 | r2
    u16*   qb2    = (u16*)alloc(8u << 20);        // cross Q proj
    u16*   vtb    = (u16*)alloc(16u << 20);       // V^T (reused both layers)
    u16*   ob     = (u16*)alloc(8u << 20);
    float* projb  = (float*)alloc(16u << 20);
    float* out1_32 = (float*)alloc(16u << 20);
    u16*   out1_bf = (u16*)alloc(8u << 20);
    float* out2_32 = (float*)alloc(16u << 20);
    u16*   out2_bf = (u16*)alloc(8u << 20);
    u16*   hb     = (u16*)alloc(32u << 20);       // [4096][4096]
    if (off > ws_size) return;

    dim3 tb(32, 32);

    // ---- phase 0: conversions / transposes / new_mem
    prep0<<<14336, 256, 0, stream>>>(mem, tgt, src, pos, newmem, cat_bf, src_bf, pos_bf);
    TW18 tw;
    tw.t[0] = {Wq1, W1t, 1024, 1024};
    tw.t[1] = {Wk1, W1t + 1048576, 1024, 1024};
    tw.t[2] = {Wv1, W1t + 2097152, 1024, 1024};
    tw.t[3] = {Wr1, Wr12t, 1024, 1024};
    tw.t[4] = {Wr2, Wr12t + 1048576, 1024, 1024};
    tw.t[5] = {Wk2, W2t, 1024, 1024};
    tw.t[6] = {Wv2, W2t + 1048576, 1024, 1024};
    tw.t[7] = {Wq2, Wq2t, 1024, 1024};
    tw.t[8] = {Wo1, Wo1t, 1024, 1024};
    tw.t[9] = {Wo2, Wo2t, 1024, 1024};
    for (int zz = 0; zz < 4; ++zz) {
        tw.t[10 + zz] = {Wf1 + zz * 1024, Wf1t + (long long)zz * 1048576, 4096, 1024};
        tw.t[14 + zz] = {Wf2 + (long long)zz * 1048576, Wf2t + zz * 1024, 1024, 4096};
    }
    transpose_w18<<<dim3(32, 32, 18), tb, 0, stream>>>(tw);

    // ---- layer 1: self relative attention (K=2048)
    // K1 = cat @ Wk1^T (ld 1056, de-aliased for fattn gathers)
    gemm_bt<4,4,1,0><<<dim3(8,64,1), 256, 0, stream>>>(cat_bf, W1t + 1048576, K1b, nullptr,
        8192,1024,1024, 1024,1024,1056, 0,0,0,0,0,0, 1);
    // V1^T = (cat @ Wv1^T)^T directly into vtb (KV length 2048)
    gemm_bt<4,4,2,0><<<dim3(8,64,1), 256, 0, stream>>>(cat_bf, W1t + 2097152, vtb, nullptr,
        8192,1024,1024, 1024,1024,2048, 0,0,0,0,0,0, 1);
    // Q over tgt rows only (batched by b)
    gemm_bt<2,4,1,0><<<dim3(8,16,4), 256, 0, stream>>>(cat_bf + 1048576, W1t, qb1, nullptr,
        1024,1024,1024, 1024,1024,1024, 0,2048LL*1024, 0,0, 0,1048576LL, 1);
    gemm_bt<2,4,1,0><<<dim3(16,32,1), 256, 0, stream>>>(pos_bf, Wr12t, R12, nullptr,
        2048,2048,1024, 1024,1024,2048, 0,0,0,0,0,0, 1);
    fattn<2048,0><<<4096, 512, 0, stream>>>(qb1, 1024LL, 1048576LL,
        rwb, rrb, K1b, R12, vtb, selfP, ob, 1056);
    gemm_bt<2,4,0,0><<<dim3(8,64,1), 256, 0, stream>>>(ob, Wo1t, projb, nullptr,
        4096,1024,1024, 1024,1024,1024, 0,0,0,0,0,0, 1);
    ln_res<<<4096, 256, 0, stream>>>(tgt, projb, nullptr, nullptr, ln1g, ln1b, out1_32, out1_bf);

    // ---- layer 2: cross relative attention (K=1024)
    {
        // merged Q2 / K2 (z=0: out1@Wq2 -> qb2 ; z=1: src@Wk2 -> P2k)
        const long long dA = (long long)(src_bf - out1_bf);
        const long long dB = (long long)(W2t - Wq2t);
        const long long dC = (long long)(P2k - qb2);
        gemm_bt<2,4,1,0><<<dim3(8,64,2), 256, 0, stream>>>(out1_bf, Wq2t, qb2, nullptr,
            4096,1024,1024, 1024,1024,1024, 0,dA, 0,dB, 0,dC, 1);
    }
    // V2^T directly into vtb (KV length 1024)
    gemm_bt<2,4,2,0><<<dim3(8,64,1), 256, 0, stream>>>(src_bf, W2t + 1048576, vtb, nullptr,
        4096,1024,1024, 1024,1024,1024, 0,0,0,0,0,0, 1);
    fattn<1024,1><<<4096, 512, 0, stream>>>(qb2, 1024LL, 1048576LL,
        rwb, rrb, P2k, R12 + 1024LL * 2048 + 1024, vtb, interP, ob, 1024);
    gemm_bt<2,4,0,0><<<dim3(8,64,1), 256, 0, stream>>>(ob, Wo2t, projb, nullptr,
        4096,1024,1024, 1024,1024,1024, 0,0,0,0,0,0, 1);
    ln_res<<<4096, 256, 0, stream>>>(out1_32, projb, nullptr, nullptr, ln2g, ln2b, out2_32, out2_bf);

    // ---- layer 3: FF
    gemm_bt<4,4,1,2><<<dim3(32,32,1), 256, 0, stream>>>(out2_bf, Wf1t, hb, bf1,
        4096,4096,1024, 1024,1024,4096, 0,0,0,0,0,0, 1);
    gemm_bt<2,4,0,0><<<dim3(8,64,1), 256, 0, stream>>>(hb, Wf2t, projb, nullptr,
        4096,1024,4096, 4096,4096,1024, 0,0,0,0,0,0, 1);
    ln_res<<<4096, 256, 0, stream>>>(out2_32, projb, nullptr, bf2, ln3g, ln3b, outp, nullptr);
}

// Round 14
// 871.100 us; speedup vs baseline: 2.0323x; 1.0233x over previous
//
#include <hip/hip_runtime.h>

typedef unsigned short u16;
typedef __attribute__((ext_vector_type(8))) short short8;
typedef __attribute__((ext_vector_type(4))) float f4;
typedef __attribute__((ext_vector_type(4))) unsigned short u16x4;

__device__ __forceinline__ float b2f(u16 u) {
    unsigned int x = ((unsigned int)u) << 16;
    return __builtin_bit_cast(float, x);
}
__device__ __forceinline__ u16 f2b(float f) {
    unsigned int u = __builtin_bit_cast(unsigned int, f);
    u += 0x7FFFu + ((u >> 16) & 1u);   // round-to-nearest-even
    return (u16)(u >> 16);
}

__device__ __forceinline__ void gl16(const void* g, void* l) {
    __builtin_amdgcn_global_load_lds(
        (const __attribute__((address_space(1))) void*)g,
        (__attribute__((address_space(3))) void*)l, 16, 0, 0);
}

// ---------------------------------------------------------------------------
// bf16 MFMA GEMM, global_load_lds staging + double-buffered LDS:
//   C[M,N] = A[M,K] @ Bt[N,K]^T  (+bias, +relu)
// Tile (FM*32)x(FN*32), BK=32, 4 waves (2x2).
// CBF: 0 f32-out, 1 bf16-out, 2 bf16 V^T-out,
//      3 z-switch {z=0: bf16->Cp ldc ; z=1: V^T->Cp2 ldc2},
//      4 z-switch {z<2: bf16->Cp+sCh*hh ; z=2: V^T->Cp2 ldc2}.
// EPI: 0 none, 1 +bias, 2 +bias+relu. Multi-source via batch strides.
// ---------------------------------------------------------------------------
template<int FM, int FN, int CBF, int EPI>
__global__ __launch_bounds__(256, 3)
void gemm_bt(const u16* __restrict__ Ap, const u16* __restrict__ Bp,
             void* __restrict__ Cp, void* __restrict__ Cp2, int ldc2,
             const float* __restrict__ bias,
             int M, int N, int K, int lda, int ldb, int ldc,
             long long sAh, long long sAb, long long sBh, long long sBb,
             long long sCh, long long sCb, int batchH)
{
    constexpr int BM = FM * 32;
    constexpr int BN = FN * 32;
    __shared__ __align__(16) u16 As[2][BM * 32];
    __shared__ __align__(16) u16 Bs[2][BN * 32];

    const int tid  = threadIdx.x;
    const int z    = blockIdx.z;
    const int bb   = z / batchH;
    const int hh   = z - bb * batchH;
    const int m0   = blockIdx.y * BM;
    const int n0   = blockIdx.x * BN;
    const int w    = tid >> 6;
    const int lane = tid & 63;
    const int wr   = w >> 1;
    const int wc   = w & 1;
    const int lrow = lane & 15;
    const int lk   = (lane >> 4) << 3;
    const int lrow4 = lane >> 2;
    const int lch   = lane & 3;

    const u16* Ag = Ap + sAb * bb + sAh * hh;
    const u16* Bg = Bp + sBb * bb + sBh * hh;

    f4 acc[FM][FN] = {};

    auto stage = [&](int buf, int kt) {
        const int kb = kt << 5;
        #pragma unroll
        for (int i = 0; i < BM / 64; ++i) {
            const int row0 = (w + i * 4) << 4;
            gl16(Ag + (long long)(m0 + row0 + lrow4) * lda + kb + (lch << 3),
                 &As[buf][row0 * 32]);
        }
        #pragma unroll
        for (int i = 0; i < BN / 64; ++i) {
            const int row0 = (w + i * 4) << 4;
            gl16(Bg + (long long)(n0 + row0 + lrow4) * ldb + kb + (lch << 3),
                 &Bs[buf][row0 * 32]);
        }
    };

    const int nKt = K >> 5;
    stage(0, 0);
    __syncthreads();
    int cur = 0;
    for (int kt = 0; kt < nKt; ++kt) {
        if (kt + 1 < nKt) stage(cur ^ 1, kt + 1);

        short8 af[FM], bv[FN];
        #pragma unroll
        for (int m = 0; m < FM; ++m)
            af[m] = *(const short8*)(&As[cur][(wr * FM * 16 + m * 16 + lrow) * 32 + lk]);
        #pragma unroll
        for (int n = 0; n < FN; ++n)
            bv[n] = *(const short8*)(&Bs[cur][(wc * FN * 16 + n * 16 + lrow) * 32 + lk]);
        #pragma unroll
        for (int m = 0; m < FM; ++m)
            #pragma unroll
            for (int n = 0; n < FN; ++n)
                acc[m][n] = __builtin_amdgcn_mfma_f32_16x16x32_bf16(af[m], bv[n], acc[m][n], 0, 0, 0);

        __syncthreads();
        cur ^= 1;
    }

    const int crow0 = m0 + wr * FM * 16 + ((lane >> 4) << 2);
    const int ccol0 = n0 + wc * FN * 16 + lrow;
    const bool vtpath = (CBF == 2) || (CBF == 3 && z == 1) || (CBF == 4 && z == 2);
    if (CBF == 0) {
        float* Cg = (float*)Cp + sCb * bb + sCh * hh;
        #pragma unroll
        for (int m = 0; m < FM; ++m) {
            #pragma unroll
            for (int n = 0; n < FN; ++n) {
                const int col = ccol0 + n * 16;
                float bvv = (EPI >= 1) ? bias[col] : 0.f;
                #pragma unroll
                for (int r = 0; r < 4; ++r) {
                    float vv = acc[m][n][r] + bvv;
                    if (EPI == 2) vv = fmaxf(vv, 0.f);
                    Cg[(long long)(crow0 + m * 16 + r) * ldc + col] = vv;
                }
            }
        }
    } else if (!vtpath) {
        u16* Cg = (u16*)Cp + sCb * bb + sCh * hh;
        #pragma unroll
        for (int m = 0; m < FM; ++m) {
            #pragma unroll
            for (int n = 0; n < FN; ++n) {
                const int col = ccol0 + n * 16;
                float bvv = (EPI >= 1) ? bias[col] : 0.f;
                #pragma unroll
                for (int r = 0; r < 4; ++r) {
                    float vv = acc[m][n][r] + bvv;
                    if (EPI == 2) vv = fmaxf(vv, 0.f);
                    Cg[(long long)(crow0 + m * 16 + r) * ldc + col] = f2b(vv);
                }
            }
        }
    } else {
        // V^T write: vt[(b*1024 + col)*ldv + j], b = row/ldv, j = row%ldv.
        const int ldv = (CBF == 2) ? ldc : ldc2;
        u16* Cg = (CBF == 2) ? (u16*)Cp : (u16*)Cp2;
        #pragma unroll
        for (int m = 0; m < FM; ++m) {
            const int row0 = crow0 + m * 16;
            const int b2 = row0 / ldv;
            const int j = row0 - b2 * ldv;
            #pragma unroll
            for (int n = 0; n < FN; ++n) {
                const int col = ccol0 + n * 16;
                u16x4 o;
                o.x = f2b(acc[m][n][0]); o.y = f2b(acc[m][n][1]);
                o.z = f2b(acc[m][n][2]); o.w = f2b(acc[m][n][3]);
                *(u16x4*)(Cg + ((long long)(b2 * 1024 + col)) * ldv + j) = o;
            }
        }
    }
}

// ---------------------------------------------------------------------------
// Fused attention v8: swapped-operand + wave-interleaved + XCD-swizzled grid
// + software-pipelined K gathers + setprio around MFMA clusters.
// 16 q-rows, 512 threads (8 waves), 1D grid 4096 (bijective XCD chunking).
// MODE 0: self causal (limit=t+1024), KK=2048. MODE 1: cross, KK=1024.
// ---------------------------------------------------------------------------
template<int KK, int MODE>
__global__ __launch_bounds__(512, 4)
void fattn(const u16* __restrict__ qsrc, long long qld, long long qsb,
           const float* __restrict__ rwb, const float* __restrict__ rrb,
           const u16* __restrict__ kb, const u16* __restrict__ rr,
           const u16* __restrict__ vt,
           float* __restrict__ probs, u16* __restrict__ ob, int kld)
{
    constexpr int LE = KK + 8;
    constexpr int NT = KK / 16;
    constexpr int NI = NT / 8;
    constexpr int NB = NI / 4;
    __shared__ __align__(16) u16 e[16 * LE];
    __shared__ __align__(16) u16 qws[16 * 72];
    __shared__ __align__(16) u16 qrs[17 * 72];
    __shared__ float psum[8][16];

    const int tid = threadIdx.x;
    const int bid = blockIdx.x;
    const int nid = ((bid & 7) << 9) + (bid >> 3);
    const int bh  = nid >> 6;
    const int t0  = (nid & 63) << 4;
    const int b   = bh >> 4, h = bh & 15;

    if (tid < 264) {
        int row, ch; const float* bias; u16* dst; bool act = true;
        if (tid < 128)      { row = tid >> 3;        ch = tid & 7; bias = rwb; dst = &qws[row * 72 + ch * 8]; }
        else if (tid < 256) { row = (tid - 128) >> 3; ch = tid & 7; bias = rrb; dst = &qrs[row * 72 + ch * 8]; }
        else if (MODE == 1) { row = 16;              ch = tid - 256; bias = rrb; dst = &qrs[16 * 72 + ch * 8]; }
        else act = false;
        if (act) {
            int trow = t0 + row; if (trow > 1023) trow = 1023;
            short8 qv = *(const short8*)(qsrc + b * qsb + (long long)trow * qld + h * 64 + ch * 8);
            const float* bp = bias + h * 64 + ch * 8;
            f4 b0 = *(const f4*)bp, b1 = *(const f4*)(bp + 4);
            short8 o;
            o[0] = (short)f2b((b2f((u16)qv[0]) + b0.x) * 0.125f);
            o[1] = (short)f2b((b2f((u16)qv[1]) + b0.y) * 0.125f);
            o[2] = (short)f2b((b2f((u16)qv[2]) + b0.z) * 0.125f);
            o[3] = (short)f2b((b2f((u16)qv[3]) + b0.w) * 0.125f);
            o[4] = (short)f2b((b2f((u16)qv[4]) + b1.x) * 0.125f);
            o[5] = (short)f2b((b2f((u16)qv[5]) + b1.y) * 0.125f);
            o[6] = (short)f2b((b2f((u16)qv[6]) + b1.z) * 0.125f);
            o[7] = (short)f2b((b2f((u16)qv[7]) + b1.w) * 0.125f);
            *(short8*)dst = o;
        }
    }
    __syncthreads();

    const int w = tid >> 6, lane = tid & 63;
    const int lc = lane & 15, g = lane >> 4, lk = g << 3;
    const int t = t0 + lc;

    const short8 bq0 = *(const short8*)&qws[lc * 72 + lk];
    const short8 bq1 = *(const short8*)&qws[lc * 72 + 32 + lk];
    const short8 br0 = *(const short8*)&qrs[lc * 72 + lk];
    const short8 br1 = *(const short8*)&qrs[lc * 72 + 32 + lk];
    short8 bs0 = {}, bs1 = {};
    if (MODE == 1) {
        bs0 = *(const short8*)&qrs[(lc + 1) * 72 + lk];
        bs1 = *(const short8*)&qrs[(lc + 1) * 72 + 32 + lk];
    }

    // ---- A0: BD~ pre-shifted write-only; 2-deep batched R-gathers
    #pragma unroll
    for (int Bb = 0; Bb < NI; Bb += 2) {
        short8 R0[2], R1[2];
        #pragma unroll
        for (int u = 0; u < 2; ++u) {
            const int ut = w + (Bb + u) * 8;
            const int u0 = ut << 4;
            const bool nd = (u0 + t0 + 30 >= 1023) || (MODE == 1 && u0 + t0 <= 1021);
            if (nd) {
                const u16* rg = rr + (long long)(u0 + lc) * 2048 + h * 64;
                R0[u] = *(const short8*)(rg + lk);
                R1[u] = *(const short8*)(rg + 32 + lk);
            }
        }
        #pragma unroll
        for (int u = 0; u < 2; ++u) {
            const int ut = w + (Bb + u) * 8;
            const int u0 = ut << 4;
            const bool need1 = (u0 + t0 + 30 >= 1023);
            const bool need2 = (MODE == 1) && (u0 + t0 <= 1021);
            if (need1) {
                f4 acc = {};
                acc = __builtin_amdgcn_mfma_f32_16x16x32_bf16(R0[u], br0, acc, 0, 0, 0);
                acc = __builtin_amdgcn_mfma_f32_16x16x32_bf16(R1[u], br1, acc, 0, 0, 0);
                #pragma unroll
                for (int i = 0; i < 4; ++i) {
                    const int j = u0 + 4 * g + i + t - 1023;
                    if (j >= 0) e[lc * LE + j] = f2b(acc[i]);
                }
            }
            if (MODE == 1 && need2) {
                f4 acc = {};
                acc = __builtin_amdgcn_mfma_f32_16x16x32_bf16(R0[u], bs0, acc, 0, 0, 0);
                acc = __builtin_amdgcn_mfma_f32_16x16x32_bf16(R1[u], bs1, acc, 0, 0, 0);
                #pragma unroll
                for (int i = 0; i < 4; ++i) {
                    const int j = u0 + 4 * g + i + t + 2;
                    if (j < KK) e[lc * LE + j] = f2b(acc[i]);
                }
            }
        }
    }
    __syncthreads();

    // ---- A1: AC + BD-add + exp + row-sum; pipelined 4-deep batched K-gathers
    float sum = 0.f;
    const int limit = t + 1024;
    const int jvt = (MODE == 0) ? ((t0 + 1039) >> 4) : (NT - 1);
    {
        short8 K0a[4], K0b[4], K1c[4];
        auto ldK0 = [&](short8* dst, int B2) {
            #pragma unroll
            for (int u = 0; u < 4; ++u) {
                const int jt = w + (B2 * 4 + u) * 8;
                if (MODE != 0 || jt <= jvt) {
                    const u16* kg = kb + (long long)(b * KK + (jt << 4) + lc) * kld + h * 64;
                    dst[u] = *(const short8*)(kg + lk);
                }
            }
        };
        ldK0(K0a, 0);
        #pragma unroll
        for (int B2 = 0; B2 < NB; ++B2) {
            short8* K0c = (B2 & 1) ? K0b : K0a;
            short8* K0n = (B2 & 1) ? K0a : K0b;
            #pragma unroll
            for (int u = 0; u < 4; ++u) {
                const int jt = w + (B2 * 4 + u) * 8;
                if (MODE != 0 || jt <= jvt) {
                    const u16* kg = kb + (long long)(b * KK + (jt << 4) + lc) * kld + h * 64;
                    K1c[u] = *(const short8*)(kg + 32 + lk);
                }
            }
            if (B2 + 1 < NB) ldK0(K0n, B2 + 1);
            __builtin_amdgcn_s_setprio(1);
            #pragma unroll
            for (int u = 0; u < 4; ++u) {
                const int jt = w + (B2 * 4 + u) * 8;
                const int jme = (jt << 4) + 4 * g;
                if (MODE == 0 && jt > jvt) {
                    u16x4 zz = {0, 0, 0, 0};
                    *(u16x4*)&e[lc * LE + jme] = zz;
                } else {
                    f4 acc = {};
                    acc = __builtin_amdgcn_mfma_f32_16x16x32_bf16(K0c[u], bq0, acc, 0, 0, 0);
                    acc = __builtin_amdgcn_mfma_f32_16x16x32_bf16(K1c[u], bq1, acc, 0, 0, 0);
                    u16x4 bd4 = *(const u16x4*)&e[lc * LE + jme];
                    u16x4 st;
                    #pragma unroll
                    for (int i = 0; i < 4; ++i) {
                        const int j = jme + i;
                        float bd = b2f(bd4[i]);
                        if (MODE == 1 && j == t + 1) bd = 0.f;
                        float ev = __expf(acc[i] + bd);
                        if (MODE == 0 && j > limit) ev = 0.f;
                        sum += ev;
                        st[i] = f2b(ev);
                    }
                    *(u16x4*)&e[lc * LE + jme] = st;
                }
            }
            __builtin_amdgcn_s_setprio(0);
        }
    }
    sum += __shfl_xor(sum, 16);
    sum += __shfl_xor(sum, 32);
    if (g == 0) psum[w][lc] = sum;
    __syncthreads();

    if (w >= 4) {
        const int r = (tid >> 4) & 15;
        const int q = tid & 15;
        float s = 0.f;
        #pragma unroll
        for (int w2 = 0; w2 < 8; ++w2) s += psum[w2][r];
        const float inv = 1.f / s;
        float* pr = probs + ((long long)bh * 1024 + t0 + r) * KK;
        #pragma unroll 4
        for (int i2 = 0; i2 < KK / 128; ++i2) {
            const int j0 = q * 8 + i2 * 128;
            u16x4 e0 = *(const u16x4*)&e[r * LE + j0];
            u16x4 e1 = *(const u16x4*)&e[r * LE + j0 + 4];
            f4 p0, p1;
            p0.x = b2f(e0.x) * inv; p0.y = b2f(e0.y) * inv;
            p0.z = b2f(e0.z) * inv; p0.w = b2f(e0.w) * inv;
            p1.x = b2f(e1.x) * inv; p1.y = b2f(e1.y) * inv;
            p1.z = b2f(e1.z) * inv; p1.w = b2f(e1.w) * inv;
            __builtin_nontemporal_store(p0, (f4*)(pr + j0));
            __builtin_nontemporal_store(p1, (f4*)(pr + j0 + 4));
        }
    } else {
        const int db = w << 4;
        const u16* vrow = vt + ((long long)(bh * 64 + db + lc)) * KK + lk;
        int kcend = KK / 32;
        if (MODE == 0) {
            const int ke = (t0 + 1071) >> 5;
            if (ke < kcend) kcend = ke;
        }
        f4 acc = {};
        __builtin_amdgcn_s_setprio(1);
        #pragma unroll 2
        for (int kc = 0; kc < kcend; ++kc) {
            short8 a = *(const short8*)&e[lc * LE + kc * 32 + lk];
            short8 bv = *(const short8*)(vrow + kc * 32);
            acc = __builtin_amdgcn_mfma_f32_16x16x32_bf16(a, bv, acc, 0, 0, 0);
        }
        __builtin_amdgcn_s_setprio(0);
        #pragma unroll
        for (int i = 0; i < 4; ++i) {
            const int trow = g * 4 + i;
            float s = 0.f;
            #pragma unroll
            for (int w2 = 0; w2 < 8; ++w2) s += psum[w2][trow];
            ob[((long long)(b * 1024 + t0 + trow)) * 1024 + h * 64 + db + lc] = f2b(acc[i] / s);
        }
    }
}

// ---------------------------------------------------------------------------
__global__ void prep0(const float* __restrict__ mem, const float* __restrict__ tgt,
                      const float* __restrict__ src, const float* __restrict__ pos,
                      float* __restrict__ nm, u16* __restrict__ cat,
                      u16* __restrict__ srcb, u16* __restrict__ posb)
{
    const int bid = blockIdx.x;
    const int tid = threadIdx.x;
    if (bid < 8192) {
        long long i = (long long)bid * 256 + tid;
        long long b = i >> 19;
        int rem = (int)(i & 524287);
        int r = rem >> 8, c4 = rem & 255;
        const float* sp = (r < 1024) ? (mem + ((b << 10) + r) * 1024 + c4 * 4)
                                     : (tgt + ((b << 10) + (r - 1024)) * 1024 + c4 * 4);
        f4 v = *(const f4*)sp;
        __builtin_nontemporal_store(v, (f4*)(nm + i * 4));
        u16x4 o; o.x = f2b(v.x); o.y = f2b(v.y); o.z = f2b(v.z); o.w = f2b(v.w);
        *(u16x4*)(cat + i * 4) = o;
    } else if (bid < 12288) {
        long long i = (long long)(bid - 8192) * 256 + tid;
        f4 v = *(const f4*)(src + i * 4);
        u16x4 o; o.x = f2b(v.x); o.y = f2b(v.y); o.z = f2b(v.z); o.w = f2b(v.w);
        *(u16x4*)(srcb + i * 4) = o;
    } else {
        long long i = (long long)(bid - 12288) * 256 + tid;
        f4 v = *(const f4*)(pos + i * 4);
        u16x4 o; o.x = f2b(v.x); o.y = f2b(v.y); o.z = f2b(v.z); o.w = f2b(v.w);
        *(u16x4*)(posb + i * 4) = o;
    }
}

struct TWS { const float* s; u16* d; int sld, dld; };
struct TW18 { TWS t[18]; };
__global__ void transpose_w18(TW18 p)
{
    __shared__ float tile[32][33];
    const TWS ts = p.t[blockIdx.z];
    int c0 = blockIdx.x * 32, r0 = blockIdx.y * 32;
    int tx = threadIdx.x, ty = threadIdx.y;
    tile[ty][tx] = ts.s[(long long)(r0 + ty) * ts.sld + c0 + tx];
    __syncthreads();
    ts.d[(long long)(c0 + ty) * ts.dld + r0 + tx] = f2b(tile[tx][ty]);
}

// out = LN(x + h1 + h2? + hbias?) * g + bl ; obf==nullptr -> NT final store.
__global__ __launch_bounds__(256) void ln_res(const float* __restrict__ x,
                                              const float* __restrict__ h1,
                                              const float* __restrict__ h2,
                                              const float* __restrict__ hbias,
                                              const float* __restrict__ g, const float* __restrict__ bl,
                                              float* __restrict__ o32, u16* __restrict__ obf)
{
    const long long row = blockIdx.x;
    const int tid = threadIdx.x;
    const long long base = row * 1024 + tid * 4;
    f4 xa = *(const f4*)(x + base);
    f4 ha = *(const f4*)(h1 + base);
    f4 hb = {0.f, 0.f, 0.f, 0.f};
    if (h2) hb = *(const f4*)(h2 + base);
    f4 hc = {0.f, 0.f, 0.f, 0.f};
    if (hbias) hc = *(const f4*)(hbias + tid * 4);
    float v0 = xa.x + ha.x + hb.x + hc.x, v1 = xa.y + ha.y + hb.y + hc.y;
    float v2 = xa.z + ha.z + hb.z + hc.z, v3 = xa.w + ha.w + hb.w + hc.w;
    float lsum = v0 + v1 + v2 + v3;
    float lsq = v0 * v0 + v1 * v1 + v2 * v2 + v3 * v3;
    #pragma unroll
    for (int o2 = 32; o2; o2 >>= 1) { lsum += __shfl_xor(lsum, o2); lsq += __shfl_xor(lsq, o2); }
    __shared__ float r1[4], r2[4];
    int w = tid >> 6, lane = tid & 63;
    if (lane == 0) { r1[w] = lsum; r2[w] = lsq; }
    __syncthreads();
    lsum = r1[0] + r1[1] + r1[2] + r1[3];
    lsq  = r2[0] + r2[1] + r2[2] + r2[3];
    const float mu = lsum * 0.0009765625f;
    const float var = lsq * 0.0009765625f - mu * mu;
    const float rsd = rsqrtf(var + 1e-5f);
    const int c = tid * 4;
    f4 gv = *(const f4*)(g + c);
    f4 bv = *(const f4*)(bl + c);
    f4 y;
    y.x = (v0 - mu) * rsd * gv.x + bv.x;
    y.y = (v1 - mu) * rsd * gv.y + bv.y;
    y.z = (v2 - mu) * rsd * gv.z + bv.z;
    y.w = (v3 - mu) * rsd * gv.w + bv.w;
    if (obf) {
        *(f4*)(o32 + base) = y;
        u16x4 u; u.x = f2b(y.x); u.y = f2b(y.y); u.z = f2b(y.z); u.w = f2b(y.w);
        *(u16x4*)(obf + base) = u;
    } else {
        __builtin_nontemporal_store(y, (f4*)(o32 + base));
    }
}

// ---------------------------------------------------------------------------
extern "C" void kernel_launch(void* const* d_in, const int* in_sizes, int n_in,
                              void* d_out, int out_size, void* d_ws, size_t ws_size,
                              hipStream_t stream)
{
    (void)in_sizes; (void)n_in; (void)out_size;
    const float* src  = (const float*)d_in[0];
    const float* tgt  = (const float*)d_in[1];
    const float* mem  = (const float*)d_in[2];
    const float* pos  = (const float*)d_in[3];
    const float* rwb  = (const float*)d_in[4];
    const float* rrb  = (const float*)d_in[5];
    const float* Wq1  = (const float*)d_in[6];
    const float* Wk1  = (const float*)d_in[7];
    const float* Wv1  = (const float*)d_in[8];
    const float* Wr1  = (const float*)d_in[9];
    const float* Wo1  = (const float*)d_in[10];
    const float* ln1g = (const float*)d_in[11];
    const float* ln1b = (const float*)d_in[12];
    const float* Wq2  = (const float*)d_in[13];
    const float* Wk2  = (const float*)d_in[14];
    const float* Wv2  = (const float*)d_in[15];
    const float* Wr2  = (const float*)d_in[16];
    const float* Wo2  = (const float*)d_in[17];
    const float* ln2g = (const float*)d_in[18];
    const float* ln2b = (const float*)d_in[19];
    const float* Wf1  = (const float*)d_in[20];
    const float* bf1  = (const float*)d_in[21];
    const float* Wf2  = (const float*)d_in[22];
    const float* bf2  = (const float*)d_in[23];
    const float* ln3g = (const float*)d_in[24];
    const float* ln3b = (const float*)d_in[25];

    float* outp   = (float*)d_out;            // [4,1024,1024]
    float* newmem = outp + 4194304;           // [4,2048,1024]
    float* selfP  = outp + 12582912;          // [4,16,1024,2048]
    float* interP = outp + 146800640;         // [4,16,1024,1024]

    char* ws = (char*)d_ws;
    size_t off = 0;
    auto alloc = [&](size_t bytes) -> void* {
        void* p = ws + off;
        off = (off + bytes + 255) & ~(size_t)255;
        return p;
    };
    u16*   src_bf  = (u16*)alloc(8u << 20);
    u16*   cat_bf  = (u16*)alloc(16u << 20);
    u16*   pos_bf  = (u16*)alloc(4u << 20);
    u16*   W1t    = (u16*)alloc(6u << 20);
    u16*   Wr12t  = (u16*)alloc(4u << 20);
    u16*   W2t    = (u16*)alloc(4u << 20);
    u16*   Wq2t   = (u16*)alloc(2u << 20);
    u16*   Wo1t   = (u16*)alloc(2u << 20);
    u16*   Wo2t   = (u16*)alloc(2u << 20);
    u16*   Wf1t   = (u16*)alloc(8u << 20);
    u16*   Wf2t   = (u16*)alloc(8u << 20);
    u16*   K1b    = (u16*)alloc(18u << 20);
    u16*   qb1    = (u16*)alloc(8u << 20);
    u16*   P2k    = (u16*)alloc(8u << 20);
    u16*   R12    = (u16*)alloc(8u << 20);
    u16*   qb2    = (u16*)alloc(8u << 20);
    u16*   vtb    = (u16*)alloc(16u << 20);
    u16*   ob     = (u16*)alloc(8u << 20);
    float* projb  = (float*)alloc(16u << 20);
    float* out1_32 = (float*)alloc(16u << 20);
    u16*   out1_bf = (u16*)alloc(8u << 20);
    float* out2_32 = (float*)alloc(16u << 20);
    u16*   out2_bf = (u16*)alloc(8u << 20);
    u16*   hb     = (u16*)alloc(32u << 20);
    if (off > ws_size) return;

    dim3 tb(32, 32);

    // ---- phase 0
    prep0<<<14336, 256, 0, stream>>>(mem, tgt, src, pos, newmem, cat_bf, src_bf, pos_bf);
    TW18 tw;
    tw.t[0] = {Wq1, W1t, 1024, 1024};
    tw.t[1] = {Wk1, W1t + 1048576, 1024, 1024};
    tw.t[2] = {Wv1, W1t + 2097152, 1024, 1024};
    tw.t[3] = {Wr1, Wr12t, 1024, 1024};
    tw.t[4] = {Wr2, Wr12t + 1048576, 1024, 1024};
    tw.t[5] = {Wk2, W2t, 1024, 1024};
    tw.t[6] = {Wv2, W2t + 1048576, 1024, 1024};
    tw.t[7] = {Wq2, Wq2t, 1024, 1024};
    tw.t[8] = {Wo1, Wo1t, 1024, 1024};
    tw.t[9] = {Wo2, Wo2t, 1024, 1024};
    for (int zz = 0; zz < 4; ++zz) {
        tw.t[10 + zz] = {Wf1 + zz * 1024, Wf1t + (long long)zz * 1048576, 4096, 1024};
        tw.t[14 + zz] = {Wf2 + (long long)zz * 1048576, Wf2t + zz * 1024, 1024, 4096};
    }
    transpose_w18<<<dim3(32, 32, 18), tb, 0, stream>>>(tw);

    // ---- layer 1: self relative attention (K=2048)
    // Merged K1 + V1^T: z=0 -> K1b (bf16, ld 1056); z=1 -> vtb (V^T, ld 2048)
    gemm_bt<4,4,3,0><<<dim3(8,64,2), 256, 0, stream>>>(cat_bf, W1t + 1048576, K1b, vtb, 2048,
        nullptr, 8192,1024,1024, 1024,1024,1056, 0,0, 0,1048576LL, 0,0, 1);
    gemm_bt<2,4,1,0><<<dim3(8,16,4), 256, 0, stream>>>(cat_bf + 1048576, W1t, qb1, nullptr, 0,
        nullptr, 1024,1024,1024, 1024,1024,1024, 0,2048LL*1024, 0,0, 0,1048576LL, 1);
    gemm_bt<2,4,1,0><<<dim3(16,32,1), 256, 0, stream>>>(pos_bf, Wr12t, R12, nullptr, 0,
        nullptr, 2048,2048,1024, 1024,1024,2048, 0,0,0,0,0,0, 1);
    fattn<2048,0><<<4096, 512, 0, stream>>>(qb1, 1024LL, 1048576LL,
        rwb, rrb, K1b, R12, vtb, selfP, ob, 1056);
    gemm_bt<2,4,0,0><<<dim3(8,64,1), 256, 0, stream>>>(ob, Wo1t, projb, nullptr, 0,
        nullptr, 4096,1024,1024, 1024,1024,1024, 0,0,0,0,0,0, 1);
    ln_res<<<4096, 256, 0, stream>>>(tgt, projb, nullptr, nullptr, ln1g, ln1b, out1_32, out1_bf);

    // ---- layer 2: cross relative attention (K=1024)
    {
        // Merged Q2/K2/V2^T: z=0: out1@Wq2 -> qb2; z=1: src@Wk2 -> P2k;
        // z=2: src@Wv2 -> vtb (V^T, ld 1024). batchH=2: z->(bb,hh)=(0,0),(0,1),(1,0)
        const long long dA = (long long)(src_bf - out1_bf);
        const long long dB = (long long)(W2t - Wq2t);
        const long long dB2 = (long long)((W2t + 1048576) - Wq2t);
        const long long dC = (long long)(P2k - qb2);
        gemm_bt<2,4,4,0><<<dim3(8,64,3), 256, 0, stream>>>(out1_bf, Wq2t, qb2, vtb, 1024,
            nullptr, 4096,1024,1024, 1024,1024,1024, dA,dA, dB,dB2, dC,0, 2);
    }
    fattn<1024,1><<<4096, 512, 0, stream>>>(qb2, 1024LL, 1048576LL,
        rwb, rrb, P2k, R12 + 1024LL * 2048 + 1024, vtb, interP, ob, 1024);
    gemm_bt<2,4,0,0><<<dim3(8,64,1), 256, 0, stream>>>(ob, Wo2t, projb, nullptr, 0,
        nullptr, 4096,1024,1024, 1024,1024,1024, 0,0,0,0,0,0, 1);
    ln_res<<<4096, 256, 0, stream>>>(out1_32, projb, nullptr, nullptr, ln2g, ln2b, out2_32, out2_bf);

    // ---- layer 3: FF
    gemm_bt<4,4,1,2><<<dim3(32,32,1), 256, 0, stream>>>(out2_bf, Wf1t, hb, nullptr, 0,
        bf1, 4096,4096,1024, 1024,1024,4096, 0,0,0,0,0,0, 1);
    gemm_bt<2,4,0,0><<<dim3(8,64,1), 256, 0, stream>>>(hb, Wf2t, projb, nullptr, 0,
        nullptr, 4096,1024,4096, 4096,4096,1024, 0,0,0,0,0,0, 1);
    ln_res<<<4096, 256, 0, stream>>>(out2_32, projb, nullptr, bf2, ln3g, ln3b, outp, nullptr);
}